// Round 1
// baseline (2084.908 us; speedup 1.0000x reference)
//
#include <hip/hip_runtime.h>
#include <math.h>

#define T_DIM 4096
#define D_DIM 1024
#define BS 60
#define NBLK 69            // ceil(4096/60): 68 full blocks + one of 16
#define KT 16
#define NCHUNK 4

// ---- workspace layout (floats) ----
static constexpr size_t OFF_U   = 0;                       // 4096*1024
static constexpr size_t OFF_V   = 4194304;                 // 4096*1024
static constexpr size_t OFF_Y   = 8388608;                 // 4096*1024
static constexpr size_t OFF_SB  = 12582912;                // 69*1024
static constexpr size_t OFF_S   = OFF_SB + 70656;          // 1024
static constexpr size_t OFF_EB  = OFF_S + 1024;            // 4096*64
static constexpr size_t OFF_DB  = OFF_EB + 262144;         // 4096*64
static constexpr size_t OFF_PM  = OFF_DB + 262144;         // 4*4096
static constexpr size_t OFF_PZ  = OFF_PM + 16384;
static constexpr size_t OFF_PWE = OFF_PZ + 16384;
static constexpr size_t OFF_PWD = OFF_PWE + 16384;
static constexpr size_t OFF_M   = OFF_PWD + 16384;         // 4096
static constexpr size_t OFF_Z   = OFF_M + 4096;
static constexpr size_t OFF_ENT = OFF_Z + 4096;
static constexpr size_t OFF_DEP = OFF_ENT + 4096;
static constexpr size_t OFF_WP  = OFF_DEP + 4096;          // 1024*1028 (repacked Wout)
// total = OFF_WP + 1052672 = 14,313,472 floats = 57.3 MB

// ---------------------------------------------------------------------------
// u = x / max(||x||,eps)
__global__ __launch_bounds__(256) void k_rownorm(const float* __restrict__ x, float* __restrict__ u) {
  int i = blockIdx.x, tid = threadIdx.x;
  const float* xr = x + (size_t)i * D_DIM;
  float4 v = *reinterpret_cast<const float4*>(xr + tid * 4);
  float ss = v.x*v.x + v.y*v.y + v.z*v.z + v.w*v.w;
#pragma unroll
  for (int m = 1; m < 64; m <<= 1) ss += __shfl_xor(ss, m);
  __shared__ float sb[4];
  if ((tid & 63) == 0) sb[tid >> 6] = ss;
  __syncthreads();
  float tot = sb[0] + sb[1] + sb[2] + sb[3];
  float inv = 1.0f / fmaxf(sqrtf(tot), 1e-12f);
  float4 o; o.x = v.x*inv; o.y = v.y*inv; o.z = v.z*inv; o.w = v.w*inv;
  *reinterpret_cast<float4*>(u + (size_t)i * D_DIM + tid * 4) = o;
}

// per-block column sums of u: Sb[b][c] = sum_{j in block b} u[j][c]
__global__ __launch_bounds__(256) void k_bsum(const float* __restrict__ u, float* __restrict__ Sb) {
  int b = blockIdx.x, tid = threadIdx.x;
  int j0 = b * BS;
  int w = (BS < T_DIM - j0) ? BS : (T_DIM - j0);
  int c = tid * 4;
  float4 acc = {0,0,0,0};
  for (int j = 0; j < w; ++j) {
    float4 v = *reinterpret_cast<const float4*>(u + (size_t)(j0 + j) * D_DIM + c);
    acc.x += v.x; acc.y += v.y; acc.z += v.z; acc.w += v.w;
  }
  *reinterpret_cast<float4*>(Sb + (size_t)b * D_DIM + c) = acc;
}

// global sum: S[c] = sum_b Sb[b][c]
__global__ __launch_bounds__(256) void k_gsum(const float* __restrict__ Sb, float* __restrict__ S) {
  int c = blockIdx.x * 256 + threadIdx.x;
  float s = 0.f;
  for (int b = 0; b < NBLK; ++b) s += Sb[(size_t)b * D_DIM + c];
  S[c] = s;
}

// ---------------------------------------------------------------------------
// C[M=4096][1024] = A[4096][1024(lda=1024)] @ B[1024][ldb]^T over K=1024
// FINAL adds ent[i]*B[o][1024] + dep[i]*B[o][1025]
template<bool FINAL>
__global__ __launch_bounds__(256) void k_gemm_nt(const float* __restrict__ A, const float* __restrict__ B,
    float* __restrict__ C, int ldb, const float* __restrict__ ent, const float* __restrict__ dep) {
  __shared__ __align__(16) float As[KT][68];
  __shared__ __align__(16) float Bs[KT][68];
  int tid = threadIdx.x;
  int r = tid >> 2, cq = tid & 3;
  int ty = tid >> 4, tx = tid & 15;
  int i0 = blockIdx.y * 64, j0 = blockIdx.x * 64;
  const float* Arow = A + (size_t)(i0 + r) * D_DIM;
  const float* Brow = B + (size_t)(j0 + r) * ldb;
  float acc[4][4] = {};
  for (int kt = 0; kt < D_DIM; kt += KT) {
    float4 av = *reinterpret_cast<const float4*>(Arow + kt + cq * 4);
    float4 bv = *reinterpret_cast<const float4*>(Brow + kt + cq * 4);
    __syncthreads();
    As[cq*4+0][r] = av.x; As[cq*4+1][r] = av.y; As[cq*4+2][r] = av.z; As[cq*4+3][r] = av.w;
    Bs[cq*4+0][r] = bv.x; Bs[cq*4+1][r] = bv.y; Bs[cq*4+2][r] = bv.z; Bs[cq*4+3][r] = bv.w;
    __syncthreads();
#pragma unroll
    for (int k = 0; k < KT; ++k) {
      float4 a4 = *reinterpret_cast<const float4*>(&As[k][ty * 4]);
      float4 b4 = *reinterpret_cast<const float4*>(&Bs[k][tx * 4]);
      float aa[4] = {a4.x, a4.y, a4.z, a4.w};
      float bb[4] = {b4.x, b4.y, b4.z, b4.w};
#pragma unroll
      for (int a = 0; a < 4; ++a)
#pragma unroll
        for (int b = 0; b < 4; ++b) acc[a][b] = fmaf(aa[a], bb[b], acc[a][b]);
    }
  }
  if constexpr (FINAL) {
    float w1[4], w2[4];
#pragma unroll
    for (int b = 0; b < 4; ++b) {
      w1[b] = B[(size_t)(j0 + tx*4 + b) * ldb + 1024];
      w2[b] = B[(size_t)(j0 + tx*4 + b) * ldb + 1025];
    }
#pragma unroll
    for (int a = 0; a < 4; ++a) {
      float e = ent[i0 + ty*4 + a], d = dep[i0 + ty*4 + a];
#pragma unroll
      for (int b = 0; b < 4; ++b) acc[a][b] += e * w1[b] + d * w2[b];
    }
  }
#pragma unroll
  for (int a = 0; a < 4; ++a) {
    float4 o = {acc[a][0], acc[a][1], acc[a][2], acc[a][3]};
    *reinterpret_cast<float4*>(C + (size_t)(i0 + ty*4 + a) * D_DIM + j0 + tx * 4) = o;
  }
}

// ---------------------------------------------------------------------------
// Fused streaming pass: E = Q@K^T and D = U@U^T tile-by-tile, online softmax
// stats per row (m, Z, We=sum p*e, Wd=sum p*(u_i.u_j)) over this WG's j-chunk;
// diagonal-block e,d values stored for exact later subtraction.
__global__ __launch_bounds__(256) void k_stream(const float* __restrict__ Q, const float* __restrict__ Km,
    const float* __restrict__ U, float* __restrict__ eb, float* __restrict__ db,
    float* __restrict__ pm, float* __restrict__ pZ, float* __restrict__ pWe, float* __restrict__ pWd) {
  __shared__ __align__(16) float Qs[KT][68], Ks[KT][68], Uis[KT][68], Ujs[KT][68];
  int chunk = blockIdx.x, it = blockIdx.y;
  int tid = threadIdx.x;
  int r = tid >> 2, cq = tid & 3;
  int ty = tid >> 4, tx = tid & 15;
  int i0 = it * 64;
  const float* Qrow  = Q + (size_t)(i0 + r) * D_DIM;
  const float* Uirow = U + (size_t)(i0 + r) * D_DIM;
  float m[4], Z[4], We[4], Wd[4];
#pragma unroll
  for (int a = 0; a < 4; ++a) { m[a] = -INFINITY; Z[a] = 0; We[a] = 0; Wd[a] = 0; }

  for (int jt = 0; jt < 16; ++jt) {
    int j0 = chunk * 1024 + jt * 64;
    const float* Krow  = Km + (size_t)(j0 + r) * D_DIM;
    const float* Ujrow = U  + (size_t)(j0 + r) * D_DIM;
    float E[4][4] = {}, Dv[4][4] = {};
    for (int kt = 0; kt < D_DIM; kt += KT) {
      float4 qv  = *reinterpret_cast<const float4*>(Qrow  + kt + cq * 4);
      float4 kv  = *reinterpret_cast<const float4*>(Krow  + kt + cq * 4);
      float4 uiv = *reinterpret_cast<const float4*>(Uirow + kt + cq * 4);
      float4 ujv = *reinterpret_cast<const float4*>(Ujrow + kt + cq * 4);
      __syncthreads();
      Qs [cq*4+0][r]=qv.x;  Qs [cq*4+1][r]=qv.y;  Qs [cq*4+2][r]=qv.z;  Qs [cq*4+3][r]=qv.w;
      Ks [cq*4+0][r]=kv.x;  Ks [cq*4+1][r]=kv.y;  Ks [cq*4+2][r]=kv.z;  Ks [cq*4+3][r]=kv.w;
      Uis[cq*4+0][r]=uiv.x; Uis[cq*4+1][r]=uiv.y; Uis[cq*4+2][r]=uiv.z; Uis[cq*4+3][r]=uiv.w;
      Ujs[cq*4+0][r]=ujv.x; Ujs[cq*4+1][r]=ujv.y; Ujs[cq*4+2][r]=ujv.z; Ujs[cq*4+3][r]=ujv.w;
      __syncthreads();
#pragma unroll
      for (int k = 0; k < KT; ++k) {
        float4 qa4 = *reinterpret_cast<const float4*>(&Qs [k][ty*4]);
        float4 ka4 = *reinterpret_cast<const float4*>(&Ks [k][tx*4]);
        float4 ua4 = *reinterpret_cast<const float4*>(&Uis[k][ty*4]);
        float4 ub4 = *reinterpret_cast<const float4*>(&Ujs[k][tx*4]);
        float qa[4] = {qa4.x,qa4.y,qa4.z,qa4.w};
        float ka[4] = {ka4.x,ka4.y,ka4.z,ka4.w};
        float ua[4] = {ua4.x,ua4.y,ua4.z,ua4.w};
        float ub[4] = {ub4.x,ub4.y,ub4.z,ub4.w};
#pragma unroll
        for (int a = 0; a < 4; ++a)
#pragma unroll
          for (int b = 0; b < 4; ++b) {
            E [a][b] = fmaf(qa[a], ka[b], E [a][b]);
            Dv[a][b] = fmaf(ua[a], ub[b], Dv[a][b]);
          }
      }
    }
    // diagonal-block stash + online stat update
#pragma unroll
    for (int a = 0; a < 4; ++a) {
      int gi = i0 + ty*4 + a;
      int bi = gi / BS;
#pragma unroll
      for (int b = 0; b < 4; ++b) {
        int gj = j0 + tx*4 + b;
        if (gj / BS == bi) {
          int c = gj - bi * BS;
          eb[(size_t)gi * 64 + c] = E[a][b];
          db[(size_t)gi * 64 + c] = Dv[a][b];
        }
      }
      float tmax = fmaxf(fmaxf(E[a][0], E[a][1]), fmaxf(E[a][2], E[a][3]));
      float nm = fmaxf(m[a], tmax);
      float s  = __expf(m[a] - nm);
      float p0 = __expf(E[a][0] - nm), p1 = __expf(E[a][1] - nm);
      float p2 = __expf(E[a][2] - nm), p3 = __expf(E[a][3] - nm);
      Z [a] = Z [a] * s + (p0 + p1 + p2 + p3);
      We[a] = We[a] * s + (p0*E[a][0] + p1*E[a][1] + p2*E[a][2] + p3*E[a][3]);
      Wd[a] = Wd[a] * s + (p0*Dv[a][0] + p1*Dv[a][1] + p2*Dv[a][2] + p3*Dv[a][3]);
      m[a] = nm;
    }
  }
  // reduce across the 16 tx lanes sharing the same rows (lane bits 0..3)
#pragma unroll
  for (int a = 0; a < 4; ++a) {
#pragma unroll
    for (int mk = 1; mk < 16; mk <<= 1) {
      float om = __shfl_xor(m[a], mk),  oZ  = __shfl_xor(Z [a], mk);
      float oWe = __shfl_xor(We[a], mk), oWd = __shfl_xor(Wd[a], mk);
      float nm = fmaxf(m[a], om);
      float s1 = __expf(m[a] - nm), s2 = __expf(om - nm);
      Z [a] = Z [a]*s1 + oZ *s2;
      We[a] = We[a]*s1 + oWe*s2;
      Wd[a] = Wd[a]*s1 + oWd*s2;
      m[a] = nm;
    }
  }
  if (tx == 0) {
#pragma unroll
    for (int a = 0; a < 4; ++a) {
      int gi = i0 + ty*4 + a;
      size_t idx = (size_t)chunk * T_DIM + gi;
      pm[idx] = m[a]; pZ[idx] = Z[a]; pWe[idx] = We[a]; pWd[idx] = Wd[a];
    }
  }
}

// ---------------------------------------------------------------------------
// per-row merge of chunk stats + dep_factor + raw entropy
__global__ __launch_bounds__(256) void k_merge(const float* __restrict__ pm, const float* __restrict__ pZ,
    const float* __restrict__ pWe, const float* __restrict__ pWd,
    const float* __restrict__ U, const float* __restrict__ Sg, const float* __restrict__ Sb,
    const float* __restrict__ eb, const float* __restrict__ db,
    float* __restrict__ dep, float* __restrict__ ent, float* __restrict__ mrow, float* __restrict__ zrow) {
  int i = blockIdx.x, tid = threadIdx.x;
  float m = pm[i], Z = pZ[i], We = pWe[i], Wd = pWd[i];
  for (int c = 1; c < NCHUNK; ++c) {
    float om = pm[(size_t)c*T_DIM + i], oZ = pZ[(size_t)c*T_DIM + i];
    float oWe = pWe[(size_t)c*T_DIM + i], oWd = pWd[(size_t)c*T_DIM + i];
    float nm = fmaxf(m, om);
    float s1 = __expf(m - nm), s2 = __expf(om - nm);
    Z = Z*s1 + oZ*s2; We = We*s1 + oWe*s2; Wd = Wd*s1 + oWd*s2; m = nm;
  }
  int b = i / BS, j0 = b * BS;
  int w = (BS < T_DIM - j0) ? BS : (T_DIM - j0);
  float4 uv  = *reinterpret_cast<const float4*>(U  + (size_t)i*D_DIM + tid*4);
  float4 Sv  = *reinterpret_cast<const float4*>(Sg + tid*4);
  float4 Sbv = *reinterpret_cast<const float4*>(Sb + (size_t)b*D_DIM + tid*4);
  float dS  = uv.x*Sv.x  + uv.y*Sv.y  + uv.z*Sv.z  + uv.w*Sv.w;
  float dSb = uv.x*Sbv.x + uv.y*Sbv.y + uv.z*Sbv.z + uv.w*Sbv.w;
  float pb = 0.f, pdb = 0.f;
  if (tid < w) {
    float e = eb[(size_t)i*64 + tid], d = db[(size_t)i*64 + tid];
    float p = __expf(e - m);
    pb = p; pdb = p * d;
  }
  float v0 = dS, v1 = dSb, v2 = pb, v3 = pdb;
#pragma unroll
  for (int mk = 1; mk < 64; mk <<= 1) {
    v0 += __shfl_xor(v0, mk); v1 += __shfl_xor(v1, mk);
    v2 += __shfl_xor(v2, mk); v3 += __shfl_xor(v3, mk);
  }
  __shared__ float red[4][4];
  if ((tid & 63) == 0) { int wv = tid >> 6; red[0][wv]=v0; red[1][wv]=v1; red[2][wv]=v2; red[3][wv]=v3; }
  __syncthreads();
  if (tid == 0) {
    float tdS  = red[0][0]+red[0][1]+red[0][2]+red[0][3];
    float tdSb = red[1][0]+red[1][1]+red[1][2]+red[1][3];
    float s1   = red[2][0]+red[2][1]+red[2][2]+red[2][3];
    float s2   = red[3][0]+red[3][1]+red[3][2]+red[3][3];
    float invZ = 1.0f / Z;
    float num = (1.0f - s1*invZ) - (Wd - s2)*invZ;
    float den = (float)(T_DIM - w) - (tdS - tdSb);
    dep[i] = num / den;
    ent[i] = -(We*invZ - m - logf(Z)) / logf((float)T_DIM);
    mrow[i] = m; zrow[i] = Z;
  }
}

// L1-normalize entropy over the T rows (deterministic single-WG reduce)
__global__ __launch_bounds__(256) void k_entnorm(float* __restrict__ ent) {
  int tid = threadIdx.x;
  float s = 0.f;
  for (int i = tid; i < T_DIM; i += 256) s += fabsf(ent[i]);
#pragma unroll
  for (int mk = 1; mk < 64; mk <<= 1) s += __shfl_xor(s, mk);
  __shared__ float sb[4];
  if ((tid & 63) == 0) sb[tid >> 6] = s;
  __syncthreads();
  float tot = sb[0] + sb[1] + sb[2] + sb[3];
  float inv = 1.0f / fmaxf(tot, 1e-12f);
  for (int i = tid; i < T_DIM; i += 256) ent[i] *= inv;
}

// repack Wout [1024][1026] -> [1024][1028] so float4 row loads are aligned
__global__ __launch_bounds__(256) void k_repack(const float* __restrict__ Wout, float* __restrict__ Wp) {
  int o = blockIdx.x;
  for (int k = threadIdx.x; k < 1026; k += 256)
    Wp[(size_t)o * 1028 + k] = Wout[(size_t)o * 1026 + k];
}

// diagonal-block att_win write + y = att_win @ V (block-diagonal)
__global__ __launch_bounds__(256) void k_atty(const float* __restrict__ eb, const float* __restrict__ mrow,
    const float* __restrict__ zrow, const float* __restrict__ dep, const float* __restrict__ V,
    float* __restrict__ att, float* __restrict__ Y) {
  int b = blockIdx.x;
  int j0 = b * BS;
  int w = (BS < T_DIM - j0) ? BS : (T_DIM - j0);
  __shared__ float wl[BS][BS + 1];
  int tid = threadIdx.x;
  for (int idx = tid; idx < BS * (BS + 1); idx += 256) (&wl[0][0])[idx] = 0.0f;
  __syncthreads();
  for (int idx = tid; idx < w * w; idx += 256) {
    int rr = idx / w, c = idx - rr * w;
    int gi = j0 + rr;
    float val = __expf(eb[(size_t)gi * 64 + c] - mrow[gi]) / zrow[gi] + dep[j0 + c];
    wl[rr][c] = val;
    if (blockIdx.y == 0) att[(size_t)gi * T_DIM + j0 + c] = val;
  }
  __syncthreads();
  int c = blockIdx.y * 256 + tid;
  float acc[BS];
#pragma unroll
  for (int rr = 0; rr < BS; ++rr) acc[rr] = 0.f;
  for (int j = 0; j < w; ++j) {
    float v = V[(size_t)(j0 + j) * D_DIM + c];
#pragma unroll
    for (int rr = 0; rr < BS; ++rr) acc[rr] = fmaf(wl[rr][j], v, acc[rr]);
  }
#pragma unroll
  for (int rr = 0; rr < BS; ++rr)
    if (rr < w) Y[(size_t)(j0 + rr) * D_DIM + c] = acc[rr];
}

// ---------------------------------------------------------------------------
extern "C" void kernel_launch(void* const* d_in, const int* in_sizes, int n_in,
                              void* d_out, int out_size, void* d_ws, size_t ws_size,
                              hipStream_t stream) {
  const float* x    = (const float*)d_in[0];
  const float* Wk   = (const float*)d_in[1];
  const float* Wq   = (const float*)d_in[2];
  const float* Wv   = (const float*)d_in[3];
  const float* Wout = (const float*)d_in[4];
  float* out = (float*)d_out;
  float* ws  = (float*)d_ws;

  float* U    = ws + OFF_U;
  float* V    = ws + OFF_V;
  float* Y    = ws + OFF_Y;
  float* Sb   = ws + OFF_SB;
  float* Sg   = ws + OFF_S;
  float* eb   = ws + OFF_EB;
  float* db   = ws + OFF_DB;
  float* pm   = ws + OFF_PM;
  float* pZ   = ws + OFF_PZ;
  float* pWe  = ws + OFF_PWE;
  float* pWd  = ws + OFF_PWD;
  float* mrow = ws + OFF_M;
  float* zrow = ws + OFF_Z;
  float* ent  = ws + OFF_ENT;
  float* dep  = ws + OFF_DEP;
  float* Wp   = ws + OFF_WP;

  float* yout = out;                       // [4096][1024]
  float* att  = out + (size_t)T_DIM * D_DIM;   // [4096][4096]
  // Q,K live temporarily inside the att region (zeroed later)
  float* Qm = att;
  float* Km = att + (size_t)T_DIM * D_DIM;

  k_rownorm<<<T_DIM, 256, 0, stream>>>(x, U);
  k_bsum<<<NBLK, 256, 0, stream>>>(U, Sb);
  k_gsum<<<4, 256, 0, stream>>>(Sb, Sg);

  dim3 gg(16, 64);
  k_gemm_nt<false><<<gg, 256, 0, stream>>>(x, Wq, Qm, D_DIM, nullptr, nullptr);
  k_gemm_nt<false><<<gg, 256, 0, stream>>>(x, Wk, Km, D_DIM, nullptr, nullptr);
  k_gemm_nt<false><<<gg, 256, 0, stream>>>(x, Wv, V,  D_DIM, nullptr, nullptr);

  k_stream<<<dim3(NCHUNK, 64), 256, 0, stream>>>(Qm, Km, U, eb, db, pm, pZ, pWe, pWd);
  k_merge<<<T_DIM, 256, 0, stream>>>(pm, pZ, pWe, pWd, U, Sg, Sb, eb, db, dep, ent, mrow, zrow);
  k_entnorm<<<1, 256, 0, stream>>>(ent);

  // Q,K no longer needed: zero the att output region, then fill diagonal blocks
  hipMemsetAsync(att, 0, (size_t)T_DIM * T_DIM * sizeof(float), stream);
  k_repack<<<1024, 256, 0, stream>>>(Wout, Wp);
  k_atty<<<dim3(NBLK, 4), 256, 0, stream>>>(eb, mrow, zrow, dep, V, att, Y);
  k_gemm_nt<true><<<gg, 256, 0, stream>>>(Y, Wp, yout, 1028, ent, dep);
}

// Round 2
// 864.675 us; speedup vs baseline: 2.4112x; 2.4112x over previous
//
#include <hip/hip_runtime.h>
#include <math.h>

#define T_DIM 4096
#define D_DIM 1024
#define BS 60
#define NBLK 69
#define NCHUNK 8
#define KT 16

typedef __attribute__((ext_vector_type(4))) float f32x4;
typedef __attribute__((ext_vector_type(8))) short short8;
#define MFMA(a,b,c) __builtin_amdgcn_mfma_f32_16x16x32_bf16((a),(b),(c),0,0,0)

static __device__ __forceinline__ ushort f2bf(float f) {
  unsigned x = __float_as_uint(f);
  unsigned r = x + 0x7fffu + ((x >> 16) & 1u);
  return (ushort)(r >> 16);
}
static __device__ __forceinline__ float bf2f(ushort u) {
  return __uint_as_float((unsigned)u << 16);
}

// ---------------------------------------------------------------------------
// split fp32 -> (hi, lo) bf16.  n multiple of 1024.
__global__ __launch_bounds__(256) void k_split(const float* __restrict__ A,
    ushort* __restrict__ hi, ushort* __restrict__ lo) {
  size_t i = ((size_t)blockIdx.x * 256 + threadIdx.x) * 4;
  float4 v = *reinterpret_cast<const float4*>(A + i);
  ushort4 h, l;
  h.x = f2bf(v.x); l.x = f2bf(v.x - bf2f(h.x));
  h.y = f2bf(v.y); l.y = f2bf(v.y - bf2f(h.y));
  h.z = f2bf(v.z); l.z = f2bf(v.z - bf2f(h.z));
  h.w = f2bf(v.w); l.w = f2bf(v.w - bf2f(h.w));
  *reinterpret_cast<ushort4*>(hi + i) = h;
  *reinterpret_cast<ushort4*>(lo + i) = l;
}

// u = x/||x|| -> bf16
__global__ __launch_bounds__(256) void k_rownorm(const float* __restrict__ x, ushort* __restrict__ u) {
  int i = blockIdx.x, tid = threadIdx.x;
  float4 v = *reinterpret_cast<const float4*>(x + (size_t)i * D_DIM + tid * 4);
  float ss = v.x*v.x + v.y*v.y + v.z*v.z + v.w*v.w;
#pragma unroll
  for (int m = 1; m < 64; m <<= 1) ss += __shfl_xor(ss, m);
  __shared__ float sb[4];
  if ((tid & 63) == 0) sb[tid >> 6] = ss;
  __syncthreads();
  float inv = 1.0f / fmaxf(sqrtf(sb[0] + sb[1] + sb[2] + sb[3]), 1e-12f);
  ushort4 o;
  o.x = f2bf(v.x*inv); o.y = f2bf(v.y*inv); o.z = f2bf(v.z*inv); o.w = f2bf(v.w*inv);
  *reinterpret_cast<ushort4*>(u + (size_t)i * D_DIM + tid * 4) = o;
}

__global__ __launch_bounds__(256) void k_bsum(const ushort* __restrict__ u, float* __restrict__ Sb) {
  int b = blockIdx.x, tid = threadIdx.x;
  int j0 = b * BS;
  int w = (BS < T_DIM - j0) ? BS : (T_DIM - j0);
  int c = tid * 4;
  float4 acc = {0,0,0,0};
  for (int j = 0; j < w; ++j) {
    ushort4 v = *reinterpret_cast<const ushort4*>(u + (size_t)(j0 + j) * D_DIM + c);
    acc.x += bf2f(v.x); acc.y += bf2f(v.y); acc.z += bf2f(v.z); acc.w += bf2f(v.w);
  }
  *reinterpret_cast<float4*>(Sb + (size_t)b * D_DIM + c) = acc;
}

__global__ __launch_bounds__(256) void k_gsum(const float* __restrict__ Sb, float* __restrict__ S) {
  int c = blockIdx.x * 256 + threadIdx.x;
  float s = 0.f;
  for (int b = 0; b < NBLK; ++b) s += Sb[(size_t)b * D_DIM + c];
  S[c] = s;
}

// ---------------------------------------------------------------------------
// MFMA split GEMM: C[4096][1024] = A @ B^T, A,B given as bf16 hi/lo (3-term).
// OUT==0: write hi/lo bf16 split.  OUT==1: write bf16 only.
template<int OUT>
__global__ __launch_bounds__(256,4) void k_qkv(
    const ushort* __restrict__ Ahi, const ushort* __restrict__ Alo,
    const ushort* __restrict__ Bhi, const ushort* __restrict__ Blo,
    ushort* __restrict__ Chi, ushort* __restrict__ Clo) {
  __shared__ ushort ldsB[8192];  // Whi @0, Wlo @4096 (shorts); 64 rows x 64k
  const int tid = threadIdx.x;
  const int w = tid >> 6, lane = tid & 63;
  const int wr = w >> 1, wc = w & 1;
  const int g = lane >> 4, cl = lane & 15;
  const int i0 = blockIdx.y * 64, j0 = blockIdx.x * 64;
  f32x4 acc[2][2];
#pragma unroll
  for (int a = 0; a < 2; ++a)
#pragma unroll
    for (int b = 0; b < 2; ++b) acc[a][b] = (f32x4){0.f,0.f,0.f,0.f};
  const int ar0 = i0 + wr*32 + cl;

  for (int ks = 0; ks < 16; ++ks) {
    const int k0 = ks * 64;
    short8 aH[2][2], aL[2][2];
#pragma unroll
    for (int is = 0; is < 2; ++is) {
      const size_t rb = (size_t)(ar0 + is*16) * D_DIM + k0;
#pragma unroll
      for (int h = 0; h < 2; ++h) {
        const size_t off = rb + (h*4+g)*8;
        aH[is][h] = *reinterpret_cast<const short8*>(Ahi + off);
        aL[is][h] = *reinterpret_cast<const short8*>(Alo + off);
      }
    }
    __syncthreads();
#pragma unroll
    for (int p = 0; p < 2; ++p) {
      const int s = tid + p*256;
      const int r = s >> 3, c = s & 7;
      const int loff = r*64 + (c ^ (r & 7))*8;
      const size_t goff = (size_t)(j0 + r) * D_DIM + k0 + c*8;
      *reinterpret_cast<short8*>(&ldsB[loff])        = *reinterpret_cast<const short8*>(Bhi + goff);
      *reinterpret_cast<short8*>(&ldsB[4096 + loff]) = *reinterpret_cast<const short8*>(Blo + goff);
    }
    __syncthreads();
#pragma unroll
    for (int h = 0; h < 2; ++h)
#pragma unroll
      for (int js = 0; js < 2; ++js) {
        const int br = wc*32 + js*16 + cl;
        const int lo = br*64 + ((h*4+g) ^ (br & 7))*8;
        short8 bH = *reinterpret_cast<const short8*>(&ldsB[lo]);
        short8 bL = *reinterpret_cast<const short8*>(&ldsB[4096 + lo]);
#pragma unroll
        for (int is = 0; is < 2; ++is) {
          acc[is][js] = MFMA(aH[is][h], bH, acc[is][js]);
          acc[is][js] = MFMA(aL[is][h], bH, acc[is][js]);
          acc[is][js] = MFMA(aH[is][h], bL, acc[is][js]);
        }
      }
  }
#pragma unroll
  for (int is = 0; is < 2; ++is)
#pragma unroll
    for (int js = 0; js < 2; ++js)
#pragma unroll
      for (int a = 0; a < 4; ++a) {
        int gi = i0 + wr*32 + is*16 + g*4 + a;
        int gj = j0 + wc*32 + js*16 + cl;
        float v = acc[is][js][a];
        if constexpr (OUT == 0) {
          ushort h = f2bf(v);
          Chi[(size_t)gi*D_DIM + gj] = h;
          Clo[(size_t)gi*D_DIM + gj] = f2bf(v - bf2f(h));
        } else {
          Chi[(size_t)gi*D_DIM + gj] = f2bf(v);
        }
      }
}

// ---------------------------------------------------------------------------
// Fused MFMA stream: E = Q@K^T (3-term split) and D = U@U^T (1-term),
// online softmax stats per row over this WG's 512-col chunk.
__global__ __launch_bounds__(256,2) void k_stream(
    const ushort* __restrict__ Qhi, const ushort* __restrict__ Qlo,
    const ushort* __restrict__ Khi, const ushort* __restrict__ Klo,
    const ushort* __restrict__ Uh,
    float* __restrict__ eb, float* __restrict__ db,
    float* __restrict__ pm, float* __restrict__ pZ,
    float* __restrict__ pWe, float* __restrict__ pWd) {
  __shared__ ushort ldsB[24576];   // Khi @0, Klo @8192, Uj @16384 (shorts); 128 rows x 64k
  __shared__ float stat_s[2][2][32][4];
  const int tid = threadIdx.x;
  const int chunk = blockIdx.x, it = blockIdx.y;
  const int i0 = it * 64;
  const int w = tid >> 6, lane = tid & 63;
  const int wr = w >> 1, wc = w & 1;
  const int g = lane >> 4, cl = lane & 15;
  const int ar0 = i0 + wr*32 + cl;
  const int blkLo = i0 / BS, blkHi = (i0 + 63) / BS;

  float m_[2][4], Z_[2][4], We_[2][4], Wd_[2][4];
#pragma unroll
  for (int is = 0; is < 2; ++is)
#pragma unroll
    for (int a = 0; a < 4; ++a) { m_[is][a] = -3.0e38f; Z_[is][a] = 0.f; We_[is][a] = 0.f; Wd_[is][a] = 0.f; }

  for (int jt = 0; jt < 4; ++jt) {
    const int jb = chunk*512 + jt*128;
    f32x4 accE[2][4], accD[2][4];
#pragma unroll
    for (int is = 0; is < 2; ++is)
#pragma unroll
      for (int js = 0; js < 4; ++js) { accE[is][js] = (f32x4){0.f,0.f,0.f,0.f}; accD[is][js] = (f32x4){0.f,0.f,0.f,0.f}; }

    for (int ks = 0; ks < 16; ++ks) {
      const int k0 = ks * 64;
      short8 aQh[2][2], aQl[2][2], aUh[2][2];
#pragma unroll
      for (int is = 0; is < 2; ++is) {
        const size_t rb = (size_t)(ar0 + is*16) * D_DIM + k0;
#pragma unroll
        for (int h = 0; h < 2; ++h) {
          const size_t off = rb + (h*4+g)*8;
          aQh[is][h] = *reinterpret_cast<const short8*>(Qhi + off);
          aQl[is][h] = *reinterpret_cast<const short8*>(Qlo + off);
          aUh[is][h] = *reinterpret_cast<const short8*>(Uh  + off);
        }
      }
      __syncthreads();
#pragma unroll
      for (int p = 0; p < 4; ++p) {
        const int s = tid + p*256;
        const int r = s >> 3, c = s & 7;
        const int loff = r*64 + (c ^ (r & 7))*8;
        const size_t goff = (size_t)(jb + r) * D_DIM + k0 + c*8;
        *reinterpret_cast<short8*>(&ldsB[loff])         = *reinterpret_cast<const short8*>(Khi + goff);
        *reinterpret_cast<short8*>(&ldsB[8192 + loff])  = *reinterpret_cast<const short8*>(Klo + goff);
        *reinterpret_cast<short8*>(&ldsB[16384 + loff]) = *reinterpret_cast<const short8*>(Uh + goff);
      }
      __syncthreads();
#pragma unroll
      for (int h = 0; h < 2; ++h)
#pragma unroll
        for (int js = 0; js < 4; ++js) {
          const int br = wc*64 + js*16 + cl;
          const int lo = br*64 + ((h*4+g) ^ (br & 7))*8;
          short8 bKh = *reinterpret_cast<const short8*>(&ldsB[lo]);
          short8 bKl = *reinterpret_cast<const short8*>(&ldsB[8192 + lo]);
          short8 bUh = *reinterpret_cast<const short8*>(&ldsB[16384 + lo]);
#pragma unroll
          for (int is = 0; is < 2; ++is) {
            accE[is][js] = MFMA(aQh[is][h], bKh, accE[is][js]);
            accE[is][js] = MFMA(aQl[is][h], bKh, accE[is][js]);
            accE[is][js] = MFMA(aQh[is][h], bKl, accE[is][js]);
            accD[is][js] = MFMA(aUh[is][h], bUh, accD[is][js]);
          }
        }
    }
    // diagonal-block stash (gated, wave-uniform)
    if (jb < (blkHi+1)*BS && jb + 128 > blkLo*BS) {
#pragma unroll
      for (int is = 0; is < 2; ++is)
#pragma unroll
        for (int js = 0; js < 4; ++js)
#pragma unroll
          for (int a = 0; a < 4; ++a) {
            int gi = i0 + wr*32 + is*16 + g*4 + a;
            int gj = jb + wc*64 + js*16 + cl;
            int bi = gi / BS;
            if (gj / BS == bi) {
              int c = gj - bi * BS;
              eb[(size_t)gi*64 + c] = accE[is][js][a];
              db[(size_t)gi*64 + c] = accD[is][js][a];
            }
          }
    }
    // online stats
#pragma unroll
    for (int is = 0; is < 2; ++is)
#pragma unroll
      for (int a = 0; a < 4; ++a) {
        float e0 = accE[is][0][a], e1 = accE[is][1][a], e2 = accE[is][2][a], e3 = accE[is][3][a];
        float d0 = accD[is][0][a], d1 = accD[is][1][a], d2 = accD[is][2][a], d3 = accD[is][3][a];
        float tmax = fmaxf(fmaxf(e0,e1), fmaxf(e2,e3));
#pragma unroll
        for (int mk = 1; mk < 16; mk <<= 1) tmax = fmaxf(tmax, __shfl_xor(tmax, mk));
        float nm = fmaxf(m_[is][a], tmax);
        float p0 = __expf(e0-nm), p1 = __expf(e1-nm), p2 = __expf(e2-nm), p3 = __expf(e3-nm);
        float z  = p0+p1+p2+p3;
        float we = p0*e0+p1*e1+p2*e2+p3*e3;
        float wd = p0*d0+p1*d1+p2*d2+p3*d3;
#pragma unroll
        for (int mk = 1; mk < 16; mk <<= 1) {
          z += __shfl_xor(z, mk); we += __shfl_xor(we, mk); wd += __shfl_xor(wd, mk);
        }
        float sc = __expf(m_[is][a] - nm);
        Z_[is][a]  = Z_[is][a]*sc + z;
        We_[is][a] = We_[is][a]*sc + we;
        Wd_[is][a] = Wd_[is][a]*sc + wd;
        m_[is][a]  = nm;
      }
  }
  if (cl == 0) {
#pragma unroll
    for (int is = 0; is < 2; ++is)
#pragma unroll
      for (int a = 0; a < 4; ++a) {
        int rl = is*16 + g*4 + a;
        stat_s[wr][wc][rl][0] = m_[is][a];
        stat_s[wr][wc][rl][1] = Z_[is][a];
        stat_s[wr][wc][rl][2] = We_[is][a];
        stat_s[wr][wc][rl][3] = Wd_[is][a];
      }
  }
  __syncthreads();
  if (tid < 64) {
    int wr2 = tid >> 5, rl = tid & 31;
    float m0 = stat_s[wr2][0][rl][0], Z0 = stat_s[wr2][0][rl][1], We0 = stat_s[wr2][0][rl][2], Wd0 = stat_s[wr2][0][rl][3];
    float m1 = stat_s[wr2][1][rl][0], Z1 = stat_s[wr2][1][rl][1], We1 = stat_s[wr2][1][rl][2], Wd1 = stat_s[wr2][1][rl][3];
    float nm = fmaxf(m0, m1);
    float s0 = __expf(m0 - nm), s1 = __expf(m1 - nm);
    size_t idx = (size_t)chunk * T_DIM + i0 + wr2*32 + rl;
    pm[idx]  = nm;
    pZ[idx]  = Z0*s0 + Z1*s1;
    pWe[idx] = We0*s0 + We1*s1;
    pWd[idx] = Wd0*s0 + Wd1*s1;
  }
}

// ---------------------------------------------------------------------------
__global__ __launch_bounds__(256) void k_merge(const float* __restrict__ pm, const float* __restrict__ pZ,
    const float* __restrict__ pWe, const float* __restrict__ pWd,
    const ushort* __restrict__ Uh, const float* __restrict__ Sg, const float* __restrict__ Sb,
    const float* __restrict__ eb, const float* __restrict__ db,
    float* __restrict__ dep, float* __restrict__ ent, float* __restrict__ mrow, float* __restrict__ zrow) {
  int i = blockIdx.x, tid = threadIdx.x;
  float m = pm[i], Z = pZ[i], We = pWe[i], Wd = pWd[i];
  for (int c = 1; c < NCHUNK; ++c) {
    float om = pm[(size_t)c*T_DIM + i], oZ = pZ[(size_t)c*T_DIM + i];
    float oWe = pWe[(size_t)c*T_DIM + i], oWd = pWd[(size_t)c*T_DIM + i];
    float nm = fmaxf(m, om);
    float s1 = __expf(m - nm), s2 = __expf(om - nm);
    Z = Z*s1 + oZ*s2; We = We*s1 + oWe*s2; Wd = Wd*s1 + oWd*s2; m = nm;
  }
  int b = i / BS, j0 = b * BS;
  int w = (BS < T_DIM - j0) ? BS : (T_DIM - j0);
  ushort4 uv = *reinterpret_cast<const ushort4*>(Uh + (size_t)i*D_DIM + tid*4);
  float4 Sv  = *reinterpret_cast<const float4*>(Sg + tid*4);
  float4 Sbv = *reinterpret_cast<const float4*>(Sb + (size_t)b*D_DIM + tid*4);
  float ux = bf2f(uv.x), uy = bf2f(uv.y), uz = bf2f(uv.z), uw = bf2f(uv.w);
  float dS  = ux*Sv.x  + uy*Sv.y  + uz*Sv.z  + uw*Sv.w;
  float dSb = ux*Sbv.x + uy*Sbv.y + uz*Sbv.z + uw*Sbv.w;
  float pb = 0.f, pdb = 0.f;
  if (tid < w) {
    float e = eb[(size_t)i*64 + tid], d = db[(size_t)i*64 + tid];
    float p = __expf(e - m);
    pb = p; pdb = p * d;
  }
  float v0 = dS, v1 = dSb, v2 = pb, v3 = pdb;
#pragma unroll
  for (int mk = 1; mk < 64; mk <<= 1) {
    v0 += __shfl_xor(v0, mk); v1 += __shfl_xor(v1, mk);
    v2 += __shfl_xor(v2, mk); v3 += __shfl_xor(v3, mk);
  }
  __shared__ float red[4][4];
  if ((tid & 63) == 0) { int wv = tid >> 6; red[0][wv]=v0; red[1][wv]=v1; red[2][wv]=v2; red[3][wv]=v3; }
  __syncthreads();
  if (tid == 0) {
    float tdS  = red[0][0]+red[0][1]+red[0][2]+red[0][3];
    float tdSb = red[1][0]+red[1][1]+red[1][2]+red[1][3];
    float s1   = red[2][0]+red[2][1]+red[2][2]+red[2][3];
    float s2   = red[3][0]+red[3][1]+red[3][2]+red[3][3];
    float invZ = 1.0f / Z;
    float num = (1.0f - s1*invZ) - (Wd - s2)*invZ;
    float den = (float)(T_DIM - w) - (tdS - tdSb);
    dep[i] = num / den;
    ent[i] = -(We*invZ - m - logf(Z)) / logf((float)T_DIM);
    mrow[i] = m; zrow[i] = Z;
  }
}

__global__ __launch_bounds__(256) void k_entnorm(float* __restrict__ ent) {
  int tid = threadIdx.x;
  float s = 0.f;
  for (int i = tid; i < T_DIM; i += 256) s += fabsf(ent[i]);
#pragma unroll
  for (int mk = 1; mk < 64; mk <<= 1) s += __shfl_xor(s, mk);
  __shared__ float sb[4];
  if ((tid & 63) == 0) sb[tid >> 6] = s;
  __syncthreads();
  float inv = 1.0f / fmaxf(sb[0] + sb[1] + sb[2] + sb[3], 1e-12f);
  for (int i = tid; i < T_DIM; i += 256) ent[i] *= inv;
}

__global__ __launch_bounds__(256) void k_repack(const float* __restrict__ Wout, float* __restrict__ Wp) {
  int o = blockIdx.x;
  for (int k = threadIdx.x; k < 1026; k += 256)
    Wp[(size_t)o * 1028 + k] = Wout[(size_t)o * 1026 + k];
}

// diagonal att write + y = att_win @ V (block-diagonal), V in bf16
__global__ __launch_bounds__(256) void k_atty(const float* __restrict__ eb, const float* __restrict__ mrow,
    const float* __restrict__ zrow, const float* __restrict__ dep, const ushort* __restrict__ Vb,
    float* __restrict__ att, float* __restrict__ Y) {
  int b = blockIdx.x;
  int j0 = b * BS;
  int w = (BS < T_DIM - j0) ? BS : (T_DIM - j0);
  __shared__ float wl[BS][BS + 1];
  int tid = threadIdx.x;
  for (int idx = tid; idx < BS * (BS + 1); idx += 256) (&wl[0][0])[idx] = 0.0f;
  __syncthreads();
  for (int idx = tid; idx < w * w; idx += 256) {
    int rr = idx / w, c = idx - rr * w;
    int gi = j0 + rr;
    float val = __expf(eb[(size_t)gi * 64 + c] - mrow[gi]) / zrow[gi] + dep[j0 + c];
    wl[rr][c] = val;
    if (blockIdx.y == 0) att[(size_t)gi * T_DIM + j0 + c] = val;
  }
  __syncthreads();
  int c = blockIdx.y * 256 + tid;
  float acc[BS];
#pragma unroll
  for (int rr = 0; rr < BS; ++rr) acc[rr] = 0.f;
  for (int j = 0; j < w; ++j) {
    float v = bf2f(Vb[(size_t)(j0 + j) * D_DIM + c]);
#pragma unroll
    for (int rr = 0; rr < BS; ++rr) acc[rr] = fmaf(wl[rr][j], v, acc[rr]);
  }
#pragma unroll
  for (int rr = 0; rr < BS; ++rr)
    if (rr < w) Y[(size_t)(j0 + rr) * D_DIM + c] = acc[rr];
}

// fp32 tiled GEMM for the final projection (K=1026 via repacked Wp, ldb=1028)
template<bool FINAL>
__global__ __launch_bounds__(256) void k_gemm_nt(const float* __restrict__ A, const float* __restrict__ B,
    float* __restrict__ C, int ldb, const float* __restrict__ ent, const float* __restrict__ dep) {
  __shared__ __align__(16) float As[KT][68];
  __shared__ __align__(16) float Bs[KT][68];
  int tid = threadIdx.x;
  int r = tid >> 2, cq = tid & 3;
  int ty = tid >> 4, tx = tid & 15;
  int i0 = blockIdx.y * 64, j0 = blockIdx.x * 64;
  const float* Arow = A + (size_t)(i0 + r) * D_DIM;
  const float* Brow = B + (size_t)(j0 + r) * ldb;
  float acc[4][4] = {};
  for (int kt = 0; kt < D_DIM; kt += KT) {
    float4 av = *reinterpret_cast<const float4*>(Arow + kt + cq * 4);
    float4 bv = *reinterpret_cast<const float4*>(Brow + kt + cq * 4);
    __syncthreads();
    As[cq*4+0][r] = av.x; As[cq*4+1][r] = av.y; As[cq*4+2][r] = av.z; As[cq*4+3][r] = av.w;
    Bs[cq*4+0][r] = bv.x; Bs[cq*4+1][r] = bv.y; Bs[cq*4+2][r] = bv.z; Bs[cq*4+3][r] = bv.w;
    __syncthreads();
#pragma unroll
    for (int k = 0; k < KT; ++k) {
      float4 a4 = *reinterpret_cast<const float4*>(&As[k][ty * 4]);
      float4 b4 = *reinterpret_cast<const float4*>(&Bs[k][tx * 4]);
      float aa[4] = {a4.x, a4.y, a4.z, a4.w};
      float bb[4] = {b4.x, b4.y, b4.z, b4.w};
#pragma unroll
      for (int a = 0; a < 4; ++a)
#pragma unroll
        for (int b = 0; b < 4; ++b) acc[a][b] = fmaf(aa[a], bb[b], acc[a][b]);
    }
  }
  if constexpr (FINAL) {
    float w1[4], w2[4];
#pragma unroll
    for (int b = 0; b < 4; ++b) {
      w1[b] = B[(size_t)(j0 + tx*4 + b) * ldb + 1024];
      w2[b] = B[(size_t)(j0 + tx*4 + b) * ldb + 1025];
    }
#pragma unroll
    for (int a = 0; a < 4; ++a) {
      float e = ent[i0 + ty*4 + a], d = dep[i0 + ty*4 + a];
#pragma unroll
      for (int b = 0; b < 4; ++b) acc[a][b] += e * w1[b] + d * w2[b];
    }
  }
#pragma unroll
  for (int a = 0; a < 4; ++a) {
    float4 o = {acc[a][0], acc[a][1], acc[a][2], acc[a][3]};
    *reinterpret_cast<float4*>(C + (size_t)(i0 + ty*4 + a) * D_DIM + j0 + tx * 4) = o;
  }
}

// ---------------------------------------------------------------------------
extern "C" void kernel_launch(void* const* d_in, const int* in_sizes, int n_in,
                              void* d_out, int out_size, void* d_ws, size_t ws_size,
                              hipStream_t stream) {
  const float* x    = (const float*)d_in[0];
  const float* Wk   = (const float*)d_in[1];
  const float* Wq   = (const float*)d_in[2];
  const float* Wv   = (const float*)d_in[3];
  const float* Wout = (const float*)d_in[4];
  float* out = (float*)d_out;
  char* wsb  = (char*)d_ws;

  // workspace layout (bytes)
  ushort* Uh   = (ushort*)(wsb + 0);           // 8,388,608
  ushort* Vb   = (ushort*)(wsb + 8388608);     // 8,388,608
  float*  Y    = (float*) (wsb + 16777216);    // 16,777,216
  ushort* Wqh  = (ushort*)(wsb + 33554432);    // 6 x 2,097,152 (W splits)
  ushort* Wql  = Wqh + 1048576;
  ushort* Wkh  = Wql + 1048576;
  ushort* Wkl  = Wkh + 1048576;
  ushort* Wvh  = Wkl + 1048576;
  ushort* Wvl  = Wvh + 1048576;
  float*  Wp   = (float*)(wsb + 33554432);     // aliases W splits (post-QKV)
  float*  eb   = (float*)(wsb + 46137344);
  float*  db   = (float*)(wsb + 47185920);
  float*  pm   = (float*)(wsb + 48234496);
  float*  pZ   = (float*)(wsb + 48365568);
  float*  pWe  = (float*)(wsb + 48496640);
  float*  pWd  = (float*)(wsb + 48627712);
  float*  mrow = (float*)(wsb + 48758784);
  float*  zrow = (float*)(wsb + 48775168);
  float*  ent  = (float*)(wsb + 48791552);
  float*  dep  = (float*)(wsb + 48807936);
  float*  Sb   = (float*)(wsb + 48824320);
  float*  Sg   = (float*)(wsb + 49106944);

  float* yout = out;                               // [4096][1024]
  float* att  = out + (size_t)T_DIM * D_DIM;       // [4096][4096]
  // bf16 scratch inside the (later memset) att region
  ushort* xhi = (ushort*)att;
  ushort* xlo = xhi + 4194304;
  ushort* Qhi = xlo + 4194304;
  ushort* Qlo = Qhi + 4194304;
  ushort* Khi = Qlo + 4194304;
  ushort* Klo = Khi + 4194304;

  k_split<<<4096, 256, 0, stream>>>(x, xhi, xlo);
  k_split<<<1024, 256, 0, stream>>>(Wq, Wqh, Wql);
  k_split<<<1024, 256, 0, stream>>>(Wk, Wkh, Wkl);
  k_split<<<1024, 256, 0, stream>>>(Wv, Wvh, Wvl);
  k_rownorm<<<T_DIM, 256, 0, stream>>>(x, Uh);
  k_bsum<<<NBLK, 256, 0, stream>>>(Uh, Sb);
  k_gsum<<<4, 256, 0, stream>>>(Sb, Sg);

  dim3 gq(16, 64);
  k_qkv<0><<<gq, 256, 0, stream>>>(xhi, xlo, Wqh, Wql, Qhi, Qlo);
  k_qkv<0><<<gq, 256, 0, stream>>>(xhi, xlo, Wkh, Wkl, Khi, Klo);
  k_qkv<1><<<gq, 256, 0, stream>>>(xhi, xlo, Wvh, Wvl, Vb, nullptr);

  k_stream<<<dim3(NCHUNK, 64), 256, 0, stream>>>(Qhi, Qlo, Khi, Klo, Uh, eb, db, pm, pZ, pWe, pWd);
  k_merge<<<T_DIM, 256, 0, stream>>>(pm, pZ, pWe, pWd, Uh, Sg, Sb, eb, db, dep, ent, mrow, zrow);
  k_entnorm<<<1, 256, 0, stream>>>(ent);

  hipMemsetAsync(att, 0, (size_t)T_DIM * T_DIM * sizeof(float), stream);
  k_repack<<<1024, 256, 0, stream>>>(Wout, Wp);
  k_atty<<<dim3(NBLK, 4), 256, 0, stream>>>(eb, mrow, zrow, dep, Vb, att, Y);
  k_gemm_nt<true><<<gq, 256, 0, stream>>>(Y, Wp, yout, 1028, ent, dep);
}

// Round 4
// 724.726 us; speedup vs baseline: 2.8768x; 1.1931x over previous
//
#include <hip/hip_runtime.h>
#include <math.h>

#define T_DIM 4096
#define D_DIM 1024
#define BS 60
#define NBLK 69
#define NPART 64

typedef __attribute__((ext_vector_type(4))) float f32x4;
typedef __attribute__((ext_vector_type(8))) short short8;
#define MFMA(a,b,c) __builtin_amdgcn_mfma_f32_16x16x32_bf16((a),(b),(c),0,0,0)

static __device__ __forceinline__ ushort f2bf(float f) {
  unsigned x = __float_as_uint(f);
  unsigned r = x + 0x7fffu + ((x >> 16) & 1u);
  return (ushort)(r >> 16);
}
static __device__ __forceinline__ float bf2f(ushort u) {
  return __uint_as_float((unsigned)u << 16);
}

// ---------------------------------------------------------------------------
__global__ __launch_bounds__(256) void k_split(const float* __restrict__ A,
    ushort* __restrict__ hi, ushort* __restrict__ lo) {
  size_t i = ((size_t)blockIdx.x * 256 + threadIdx.x) * 4;
  float4 v = *reinterpret_cast<const float4*>(A + i);
  ushort4 h, l;
  h.x = f2bf(v.x); l.x = f2bf(v.x - bf2f(h.x));
  h.y = f2bf(v.y); l.y = f2bf(v.y - bf2f(h.y));
  h.z = f2bf(v.z); l.z = f2bf(v.z - bf2f(h.z));
  h.w = f2bf(v.w); l.w = f2bf(v.w - bf2f(h.w));
  *reinterpret_cast<ushort4*>(hi + i) = h;
  *reinterpret_cast<ushort4*>(lo + i) = l;
}

__global__ __launch_bounds__(256) void k_rownorm(const float* __restrict__ x, ushort* __restrict__ u) {
  int i = blockIdx.x, tid = threadIdx.x;
  float4 v = *reinterpret_cast<const float4*>(x + (size_t)i * D_DIM + tid * 4);
  float ss = v.x*v.x + v.y*v.y + v.z*v.z + v.w*v.w;
#pragma unroll
  for (int m = 1; m < 64; m <<= 1) ss += __shfl_xor(ss, m);
  __shared__ float sb[4];
  if ((tid & 63) == 0) sb[tid >> 6] = ss;
  __syncthreads();
  float inv = 1.0f / fmaxf(sqrtf(sb[0] + sb[1] + sb[2] + sb[3]), 1e-12f);
  ushort4 o;
  o.x = f2bf(v.x*inv); o.y = f2bf(v.y*inv); o.z = f2bf(v.z*inv); o.w = f2bf(v.w*inv);
  *reinterpret_cast<ushort4*>(u + (size_t)i * D_DIM + tid * 4) = o;
}

__global__ __launch_bounds__(256) void k_bsum(const ushort* __restrict__ u, float* __restrict__ Sb) {
  int b = blockIdx.x, tid = threadIdx.x;
  int j0 = b * BS;
  int w = (BS < T_DIM - j0) ? BS : (T_DIM - j0);
  int c = tid * 4;
  float4 acc = {0,0,0,0};
  for (int j = 0; j < w; ++j) {
    ushort4 v = *reinterpret_cast<const ushort4*>(u + (size_t)(j0 + j) * D_DIM + c);
    acc.x += bf2f(v.x); acc.y += bf2f(v.y); acc.z += bf2f(v.z); acc.w += bf2f(v.w);
  }
  *reinterpret_cast<float4*>(Sb + (size_t)b * D_DIM + c) = acc;
}

__global__ __launch_bounds__(256) void k_gsum(const float* __restrict__ Sb, float* __restrict__ S) {
  int c = blockIdx.x * 256 + threadIdx.x;
  float s = 0.f;
  for (int b = 0; b < NBLK; ++b) s += Sb[(size_t)b * D_DIM + c];
  S[c] = s;
}

// ---------------------------------------------------------------------------
// R2-proven MFMA split GEMM: C[4096][1024] = A @ B^T (3-term).
// OUT==0: write hi/lo split.  OUT==1: write bf16 only.
template<int OUT>
__global__ __launch_bounds__(256,4) void k_qkv(
    const ushort* __restrict__ Ahi, const ushort* __restrict__ Alo,
    const ushort* __restrict__ Bhi, const ushort* __restrict__ Blo,
    ushort* __restrict__ Chi, ushort* __restrict__ Clo) {
  __shared__ ushort ldsB[8192];  // Whi @0, Wlo @4096 (shorts); 64 rows x 64k
  const int tid = threadIdx.x;
  const int w = tid >> 6, lane = tid & 63;
  const int wr = w >> 1, wc = w & 1;
  const int g = lane >> 4, cl = lane & 15;
  const int i0 = blockIdx.y * 64, j0 = blockIdx.x * 64;
  f32x4 acc[2][2];
#pragma unroll
  for (int a = 0; a < 2; ++a)
#pragma unroll
    for (int b = 0; b < 2; ++b) acc[a][b] = (f32x4){0.f,0.f,0.f,0.f};
  const int ar0 = i0 + wr*32 + cl;

  for (int ks = 0; ks < 16; ++ks) {
    const int k0 = ks * 64;
    short8 aH[2][2], aL[2][2];
#pragma unroll
    for (int is = 0; is < 2; ++is) {
      const size_t rb = (size_t)(ar0 + is*16) * D_DIM + k0;
#pragma unroll
      for (int h = 0; h < 2; ++h) {
        const size_t off = rb + (h*4+g)*8;
        aH[is][h] = *reinterpret_cast<const short8*>(Ahi + off);
        aL[is][h] = *reinterpret_cast<const short8*>(Alo + off);
      }
    }
    __syncthreads();
#pragma unroll
    for (int p = 0; p < 2; ++p) {
      const int s = tid + p*256;
      const int r = s >> 3, c = s & 7;
      const int loff = r*64 + (c ^ (r & 7))*8;
      const size_t goff = (size_t)(j0 + r) * D_DIM + k0 + c*8;
      *reinterpret_cast<short8*>(&ldsB[loff])        = *reinterpret_cast<const short8*>(Bhi + goff);
      *reinterpret_cast<short8*>(&ldsB[4096 + loff]) = *reinterpret_cast<const short8*>(Blo + goff);
    }
    __syncthreads();
#pragma unroll
    for (int h = 0; h < 2; ++h)
#pragma unroll
      for (int js = 0; js < 2; ++js) {
        const int br = wc*32 + js*16 + cl;
        const int lo = br*64 + ((h*4+g) ^ (br & 7))*8;
        short8 bH = *reinterpret_cast<const short8*>(&ldsB[lo]);
        short8 bL = *reinterpret_cast<const short8*>(&ldsB[4096 + lo]);
#pragma unroll
        for (int is = 0; is < 2; ++is) {
          acc[is][js] = MFMA(aH[is][h], bH, acc[is][js]);
          acc[is][js] = MFMA(aL[is][h], bH, acc[is][js]);
          acc[is][js] = MFMA(aH[is][h], bL, acc[is][js]);
        }
      }
  }
#pragma unroll
  for (int is = 0; is < 2; ++is)
#pragma unroll
    for (int js = 0; js < 2; ++js)
#pragma unroll
      for (int a = 0; a < 4; ++a) {
        int gi = i0 + wr*32 + is*16 + g*4 + a;
        int gj = j0 + wc*32 + js*16 + cl;
        float v = acc[is][js][a];
        if constexpr (OUT == 0) {
          ushort h = f2bf(v);
          Chi[(size_t)gi*D_DIM + gj] = h;
          Clo[(size_t)gi*D_DIM + gj] = f2bf(v - bf2f(h));
        } else {
          Chi[(size_t)gi*D_DIM + gj] = f2bf(v);
        }
      }
}

// ---------------------------------------------------------------------------
// Fused stream: E = Q@K^T (3-term) and Dv = U@U^T (1-term).
// WG tile 128i x 64j per jt (4 jt = 256-col chunk), wave 64x32, BK=32.
// Register staging + ds_write (R2-proven sync), depth-1 pipelined loads.
__global__ __launch_bounds__(256,2) void k_stream(
    const ushort* __restrict__ Qhi, const ushort* __restrict__ Qlo,
    const ushort* __restrict__ Khi, const ushort* __restrict__ Klo,
    const ushort* __restrict__ Uh,
    float* __restrict__ eb, float* __restrict__ db,
    float* __restrict__ pm, float* __restrict__ pZ,
    float* __restrict__ pWe, float* __restrict__ pWd) {
  __shared__ __align__(16) ushort lds[18432]; // Qhi@0 Qlo@4096 Ui@8192 (128x32) | Khi@12288 Klo@14336 Uj@16384 (64x32)
  __shared__ float stat_s[2][2][64][4];
  const int tid = threadIdx.x;
  const int bid = blockIdx.x;
  const int wg = (bid & 7) * 64 + (bid >> 3);   // XCD-bijective (512 % 8 == 0)
  const int it = wg >> 4, chunk = wg & 15;
  const int i0 = it * 128;
  const int w = tid >> 6, lane = tid & 63;
  const int wr = w >> 1, wc = w & 1;
  const int g = lane >> 4, cl = lane & 15;

  int adA[4], adB[2];
#pragma unroll
  for (int is = 0; is < 4; ++is) {
    int r = wr*64 + is*16 + cl;
    adA[is] = r*32 + (g ^ ((r >> 1) & 3))*8;
  }
#pragma unroll
  for (int js = 0; js < 2; ++js) {
    int r = wc*32 + js*16 + cl;
    adB[js] = r*32 + (g ^ ((r >> 1) & 3))*8;
  }

  const int ra1 = tid >> 2, ra2 = 64 + (tid >> 2), rbr = tid >> 2;
  const int sa = tid & 3;
  const int wA1 = ra1*32 + (sa ^ ((ra1 >> 1) & 3))*8;
  const int wA2 = ra2*32 + (sa ^ ((ra2 >> 1) & 3))*8;
  const int wB  = rbr*32 + (sa ^ ((rbr >> 1) & 3))*8;
  const size_t gA1 = (size_t)(i0 + ra1) * D_DIM + sa*8;
  const size_t gA2 = (size_t)(i0 + ra2) * D_DIM + sa*8;

  const int iw0 = i0 + wr*64;
  const int blkLo = iw0 / BS, blkHi = (iw0 + 63) / BS;

  for (int jt = 0; jt < 4; ++jt) {
    const int jb = chunk*256 + jt*64;
    const size_t gB = (size_t)(jb + rbr) * D_DIM + sa*8;

    f32x4 accE[4][2], accD[4][2];
#pragma unroll
    for (int is = 0; is < 4; ++is)
#pragma unroll
      for (int js = 0; js < 2; ++js) {
        accE[is][js] = (f32x4){0.f,0.f,0.f,0.f};
        accD[is][js] = (f32x4){0.f,0.f,0.f,0.f};
      }

    // prologue loads (k0 = 0)
    short8 sQh1 = *reinterpret_cast<const short8*>(Qhi + gA1);
    short8 sQh2 = *reinterpret_cast<const short8*>(Qhi + gA2);
    short8 sQl1 = *reinterpret_cast<const short8*>(Qlo + gA1);
    short8 sQl2 = *reinterpret_cast<const short8*>(Qlo + gA2);
    short8 sUi1 = *reinterpret_cast<const short8*>(Uh  + gA1);
    short8 sUi2 = *reinterpret_cast<const short8*>(Uh  + gA2);
    short8 sKh  = *reinterpret_cast<const short8*>(Khi + gB);
    short8 sKl  = *reinterpret_cast<const short8*>(Klo + gB);
    short8 sUj  = *reinterpret_cast<const short8*>(Uh  + gB);

    for (int ks = 0; ks < 32; ++ks) {
      __syncthreads();
      *reinterpret_cast<short8*>(&lds[wA1])         = sQh1;
      *reinterpret_cast<short8*>(&lds[wA2])         = sQh2;
      *reinterpret_cast<short8*>(&lds[4096 + wA1])  = sQl1;
      *reinterpret_cast<short8*>(&lds[4096 + wA2])  = sQl2;
      *reinterpret_cast<short8*>(&lds[8192 + wA1])  = sUi1;
      *reinterpret_cast<short8*>(&lds[8192 + wA2])  = sUi2;
      *reinterpret_cast<short8*>(&lds[12288 + wB])  = sKh;
      *reinterpret_cast<short8*>(&lds[14336 + wB])  = sKl;
      *reinterpret_cast<short8*>(&lds[16384 + wB])  = sUj;
      __syncthreads();
      short8 aQh[4], aQl[4], aU[4], bKh[2], bKl[2], bU[2];
#pragma unroll
      for (int is = 0; is < 4; ++is) {
        aQh[is] = *reinterpret_cast<const short8*>(&lds[adA[is]]);
        aQl[is] = *reinterpret_cast<const short8*>(&lds[4096 + adA[is]]);
        aU [is] = *reinterpret_cast<const short8*>(&lds[8192 + adA[is]]);
      }
#pragma unroll
      for (int js = 0; js < 2; ++js) {
        bKh[js] = *reinterpret_cast<const short8*>(&lds[12288 + adB[js]]);
        bKl[js] = *reinterpret_cast<const short8*>(&lds[14336 + adB[js]]);
        bU [js] = *reinterpret_cast<const short8*>(&lds[16384 + adB[js]]);
      }
      if (ks < 31) {   // issue next-K loads under the MFMA block
        const int k0 = (ks + 1) * 32;
        sQh1 = *reinterpret_cast<const short8*>(Qhi + gA1 + k0);
        sQh2 = *reinterpret_cast<const short8*>(Qhi + gA2 + k0);
        sQl1 = *reinterpret_cast<const short8*>(Qlo + gA1 + k0);
        sQl2 = *reinterpret_cast<const short8*>(Qlo + gA2 + k0);
        sUi1 = *reinterpret_cast<const short8*>(Uh  + gA1 + k0);
        sUi2 = *reinterpret_cast<const short8*>(Uh  + gA2 + k0);
        sKh  = *reinterpret_cast<const short8*>(Khi + gB + k0);
        sKl  = *reinterpret_cast<const short8*>(Klo + gB + k0);
        sUj  = *reinterpret_cast<const short8*>(Uh  + gB + k0);
      }
#pragma unroll
      for (int js = 0; js < 2; ++js)
#pragma unroll
        for (int is = 0; is < 4; ++is) {
          accE[is][js] = MFMA(aQh[is], bKh[js], accE[is][js]);
          accE[is][js] = MFMA(aQl[is], bKh[js], accE[is][js]);
          accE[is][js] = MFMA(aQh[is], bKl[js], accE[is][js]);
          accD[is][js] = MFMA(aU[is],  bU[js],  accD[is][js]);
        }
    }

    // diagonal-block stash
    const int jw0 = jb + wc*32;
    if (jw0 < (blkHi+1)*BS && jw0 + 32 > blkLo*BS) {
#pragma unroll
      for (int is = 0; is < 4; ++is)
#pragma unroll
        for (int js = 0; js < 2; ++js)
#pragma unroll
          for (int a = 0; a < 4; ++a) {
            int gi = i0 + wr*64 + is*16 + g*4 + a;
            int gj = jw0 + js*16 + cl;
            int bi = gi / BS;
            if (gj / BS == bi) {
              int c = gj - bi * BS;
              eb[(size_t)gi*64 + c] = accE[is][js][a];
              db[(size_t)gi*64 + c] = accD[is][js][a];
            }
          }
    }

    // per-jt partial softmax stats over this 64-col tile
#pragma unroll
    for (int is = 0; is < 4; ++is)
#pragma unroll
      for (int a = 0; a < 4; ++a) {
        float e0 = accE[is][0][a], e1 = accE[is][1][a];
        float d0 = accD[is][0][a], d1 = accD[is][1][a];
        float tmax = fmaxf(e0, e1);
#pragma unroll
        for (int mk = 1; mk < 16; mk <<= 1) tmax = fmaxf(tmax, __shfl_xor(tmax, mk));
        float p0 = __expf(e0 - tmax), p1 = __expf(e1 - tmax);
        float z  = p0 + p1;
        float we = p0*e0 + p1*e1;
        float wd = p0*d0 + p1*d1;
#pragma unroll
        for (int mk = 1; mk < 16; mk <<= 1) {
          z += __shfl_xor(z, mk); we += __shfl_xor(we, mk); wd += __shfl_xor(wd, mk);
        }
        if (cl == 0) {
          int rl = is*16 + g*4 + a;
          stat_s[wr][wc][rl][0] = tmax;
          stat_s[wr][wc][rl][1] = z;
          stat_s[wr][wc][rl][2] = we;
          stat_s[wr][wc][rl][3] = wd;
        }
      }
    __syncthreads();
    if (tid < 128) {
      int rl = tid & 63, wr2 = tid >> 6;
      float m0 = stat_s[wr2][0][rl][0], Z0 = stat_s[wr2][0][rl][1];
      float We0 = stat_s[wr2][0][rl][2], Wd0 = stat_s[wr2][0][rl][3];
      float m1 = stat_s[wr2][1][rl][0], Z1 = stat_s[wr2][1][rl][1];
      float We1 = stat_s[wr2][1][rl][2], Wd1 = stat_s[wr2][1][rl][3];
      float nm = fmaxf(m0, m1);
      float s0 = __expf(m0 - nm), s1 = __expf(m1 - nm);
      size_t idx = (size_t)(chunk*4 + jt) * T_DIM + i0 + wr2*64 + rl;
      pm[idx]  = nm;
      pZ[idx]  = Z0*s0 + Z1*s1;
      pWe[idx] = We0*s0 + We1*s1;
      pWd[idx] = Wd0*s0 + Wd1*s1;
    }
  }
}

// ---------------------------------------------------------------------------
__global__ __launch_bounds__(256) void k_merge(const float* __restrict__ pm, const float* __restrict__ pZ,
    const float* __restrict__ pWe, const float* __restrict__ pWd,
    const ushort* __restrict__ Uh, const float* __restrict__ Sg, const float* __restrict__ Sb,
    const float* __restrict__ eb, const float* __restrict__ db,
    float* __restrict__ dep, float* __restrict__ ent, float* __restrict__ mrow, float* __restrict__ zrow) {
  int i = blockIdx.x, tid = threadIdx.x;
  float m = pm[i], Z = pZ[i], We = pWe[i], Wd = pWd[i];
  for (int c = 1; c < NPART; ++c) {
    float om = pm[(size_t)c*T_DIM + i], oZ = pZ[(size_t)c*T_DIM + i];
    float oWe = pWe[(size_t)c*T_DIM + i], oWd = pWd[(size_t)c*T_DIM + i];
    float nm = fmaxf(m, om);
    float s1 = __expf(m - nm), s2 = __expf(om - nm);
    Z = Z*s1 + oZ*s2; We = We*s1 + oWe*s2; Wd = Wd*s1 + oWd*s2; m = nm;
  }
  int b = i / BS, j0 = b * BS;
  int w = (BS < T_DIM - j0) ? BS : (T_DIM - j0);
  ushort4 uv = *reinterpret_cast<const ushort4*>(Uh + (size_t)i*D_DIM + tid*4);
  float4 Sv  = *reinterpret_cast<const float4*>(Sg + tid*4);
  float4 Sbv = *reinterpret_cast<const float4*>(Sb + (size_t)b*D_DIM + tid*4);
  float ux = bf2f(uv.x), uy = bf2f(uv.y), uz = bf2f(uv.z), uw = bf2f(uv.w);
  float dS  = ux*Sv.x  + uy*Sv.y  + uz*Sv.z  + uw*Sv.w;
  float dSb = ux*Sbv.x + uy*Sbv.y + uz*Sbv.z + uw*Sbv.w;
  float pb = 0.f, pdb = 0.f;
  if (tid < w) {
    float e = eb[(size_t)i*64 + tid], d = db[(size_t)i*64 + tid];
    float p = __expf(e - m);
    pb = p; pdb = p * d;
  }
  float v0 = dS, v1 = dSb, v2 = pb, v3 = pdb;
#pragma unroll
  for (int mk = 1; mk < 64; mk <<= 1) {
    v0 += __shfl_xor(v0, mk); v1 += __shfl_xor(v1, mk);
    v2 += __shfl_xor(v2, mk); v3 += __shfl_xor(v3, mk);
  }
  __shared__ float red[4][4];
  if ((tid & 63) == 0) { int wv = tid >> 6; red[0][wv]=v0; red[1][wv]=v1; red[2][wv]=v2; red[3][wv]=v3; }
  __syncthreads();
  if (tid == 0) {
    float tdS  = red[0][0]+red[0][1]+red[0][2]+red[0][3];
    float tdSb = red[1][0]+red[1][1]+red[1][2]+red[1][3];
    float s1   = red[2][0]+red[2][1]+red[2][2]+red[2][3];
    float s2   = red[3][0]+red[3][1]+red[3][2]+red[3][3];
    float invZ = 1.0f / Z;
    float num = (1.0f - s1*invZ) - (Wd - s2)*invZ;
    float den = (float)(T_DIM - w) - (tdS - tdSb);
    dep[i] = num / den;
    ent[i] = -(We*invZ - m - logf(Z)) / logf((float)T_DIM);
    mrow[i] = m; zrow[i] = Z;
  }
}

__global__ __launch_bounds__(256) void k_entnorm(float* __restrict__ ent) {
  int tid = threadIdx.x;
  float s = 0.f;
  for (int i = tid; i < T_DIM; i += 256) s += fabsf(ent[i]);
#pragma unroll
  for (int mk = 1; mk < 64; mk <<= 1) s += __shfl_xor(s, mk);
  __shared__ float sb[4];
  if ((tid & 63) == 0) sb[tid >> 6] = s;
  __syncthreads();
  float inv = 1.0f / fmaxf(sb[0] + sb[1] + sb[2] + sb[3], 1e-12f);
  for (int i = tid; i < T_DIM; i += 256) ent[i] *= inv;
}

__global__ __launch_bounds__(256) void k_repack(const float* __restrict__ Wout, ushort* __restrict__ Wob) {
  int o = blockIdx.x;
  for (int k = threadIdx.x; k < 1024; k += 256)
    Wob[(size_t)o * 1024 + k] = f2bf(Wout[(size_t)o * 1026 + k]);
}

// diagonal att write + y = att_win @ V, y stored bf16
__global__ __launch_bounds__(256) void k_atty(const float* __restrict__ eb, const float* __restrict__ mrow,
    const float* __restrict__ zrow, const float* __restrict__ dep, const ushort* __restrict__ Vb,
    float* __restrict__ att, ushort* __restrict__ Ybf) {
  int b = blockIdx.x;
  int j0 = b * BS;
  int w = (BS < T_DIM - j0) ? BS : (T_DIM - j0);
  __shared__ float wl[BS][BS + 1];
  int tid = threadIdx.x;
  for (int idx = tid; idx < BS * (BS + 1); idx += 256) (&wl[0][0])[idx] = 0.0f;
  __syncthreads();
  for (int idx = tid; idx < w * w; idx += 256) {
    int rr = idx / w, c = idx - rr * w;
    int gi = j0 + rr;
    float val = __expf(eb[(size_t)gi * 64 + c] - mrow[gi]) / zrow[gi] + dep[j0 + c];
    wl[rr][c] = val;
    if (blockIdx.y == 0) att[(size_t)gi * T_DIM + j0 + c] = val;
  }
  __syncthreads();
  int c = blockIdx.y * 256 + tid;
  float acc[BS];
#pragma unroll
  for (int rr = 0; rr < BS; ++rr) acc[rr] = 0.f;
  for (int j = 0; j < w; ++j) {
    float v = bf2f(Vb[(size_t)(j0 + j) * D_DIM + c]);
#pragma unroll
    for (int rr = 0; rr < BS; ++rr) acc[rr] = fmaf(wl[rr][j], v, acc[rr]);
  }
#pragma unroll
  for (int rr = 0; rr < BS; ++rr)
    if (rr < w) Ybf[(size_t)(j0 + rr) * D_DIM + c] = f2bf(acc[rr]);
}

// ---------------------------------------------------------------------------
// Final projection: yout = Ybf @ Wob^T (1-term bf16) + ent/dep epilogue.
// R2-proven k_qkv skeleton (64x64 tile, A direct-from-global, B LDS-staged).
__global__ __launch_bounds__(256,4) void k_final(
    const ushort* __restrict__ Ybf, const ushort* __restrict__ Wob,
    const float* __restrict__ Wout, const float* __restrict__ ent,
    const float* __restrict__ dep, float* __restrict__ yout) {
  __shared__ ushort ldsB[4096];  // 64 rows x 64k
  const int tid = threadIdx.x;
  const int w = tid >> 6, lane = tid & 63;
  const int wr = w >> 1, wc = w & 1;
  const int g = lane >> 4, cl = lane & 15;
  const int i0 = blockIdx.y * 64, j0 = blockIdx.x * 64;
  f32x4 acc[2][2];
#pragma unroll
  for (int a = 0; a < 2; ++a)
#pragma unroll
    for (int b = 0; b < 2; ++b) acc[a][b] = (f32x4){0.f,0.f,0.f,0.f};
  const int ar0 = i0 + wr*32 + cl;

  for (int ks = 0; ks < 16; ++ks) {
    const int k0 = ks * 64;
    short8 aY[2][2];
#pragma unroll
    for (int is = 0; is < 2; ++is) {
      const size_t rb = (size_t)(ar0 + is*16) * D_DIM + k0;
#pragma unroll
      for (int h = 0; h < 2; ++h)
        aY[is][h] = *reinterpret_cast<const short8*>(Ybf + rb + (h*4+g)*8);
    }
    __syncthreads();
#pragma unroll
    for (int p = 0; p < 2; ++p) {
      const int s = tid + p*256;
      const int r = s >> 3, c = s & 7;
      const int loff = r*64 + (c ^ (r & 7))*8;
      *reinterpret_cast<short8*>(&ldsB[loff]) =
          *reinterpret_cast<const short8*>(Wob + (size_t)(j0 + r) * D_DIM + k0 + c*8);
    }
    __syncthreads();
#pragma unroll
    for (int h = 0; h < 2; ++h)
#pragma unroll
      for (int js = 0; js < 2; ++js) {
        const int br = wc*32 + js*16 + cl;
        short8 bW = *reinterpret_cast<const short8*>(&ldsB[br*64 + ((h*4+g) ^ (br & 7))*8]);
#pragma unroll
        for (int is = 0; is < 2; ++is)
          acc[is][js] = MFMA(aY[is][h], bW, acc[is][js]);
      }
  }
  float w1[2], w2[2];
#pragma unroll
  for (int js = 0; js < 2; ++js) {
    int gj = j0 + wc*32 + js*16 + cl;
    w1[js] = Wout[(size_t)gj * 1026 + 1024];
    w2[js] = Wout[(size_t)gj * 1026 + 1025];
  }
#pragma unroll
  for (int is = 0; is < 2; ++is)
#pragma unroll
    for (int a = 0; a < 4; ++a) {
      int gi = i0 + wr*32 + is*16 + g*4 + a;
      float e = ent[gi], d = dep[gi];
#pragma unroll
      for (int js = 0; js < 2; ++js) {
        int gj = j0 + wc*32 + js*16 + cl;
        yout[(size_t)gi * D_DIM + gj] = acc[is][js][a] + e * w1[js] + d * w2[js];
      }
    }
}

// ---------------------------------------------------------------------------
extern "C" void kernel_launch(void* const* d_in, const int* in_sizes, int n_in,
                              void* d_out, int out_size, void* d_ws, size_t ws_size,
                              hipStream_t stream) {
  const float* x    = (const float*)d_in[0];
  const float* Wk   = (const float*)d_in[1];
  const float* Wq   = (const float*)d_in[2];
  const float* Wv   = (const float*)d_in[3];
  const float* Wout = (const float*)d_in[4];
  float* out = (float*)d_out;
  char* wsb  = (char*)d_ws;

  ushort* Uh   = (ushort*)(wsb + 0);            // 8 MB
  ushort* Vb   = (ushort*)(wsb + 8388608);      // 8 MB
  ushort* Ybf  = (ushort*)(wsb + 16777216);     // 8 MB
  ushort* Wob  = (ushort*)(wsb + 25165824);     // 2 MB
  ushort* Wqh  = (ushort*)(wsb + 27262976);     // 6 x 2 MB
  ushort* Wql  = Wqh + 1048576;
  ushort* Wkh  = Wql + 1048576;
  ushort* Wkl  = Wkh + 1048576;
  ushort* Wvh  = Wkl + 1048576;
  ushort* Wvl  = Wvh + 1048576;
  float*  eb   = (float*)(wsb + 39845888);      // 1 MB
  float*  db   = (float*)(wsb + 40894464);      // 1 MB
  float*  pm   = (float*)(wsb + 41943040);      // 1 MB each (64 partials)
  float*  pZ   = (float*)(wsb + 42991616);
  float*  pWe  = (float*)(wsb + 44040192);
  float*  pWd  = (float*)(wsb + 45088768);
  float*  mrow = (float*)(wsb + 46137344);
  float*  zrow = (float*)(wsb + 46153728);
  float*  ent  = (float*)(wsb + 46170112);
  float*  dep  = (float*)(wsb + 46186496);
  float*  Sb   = (float*)(wsb + 46202880);
  float*  Sg   = (float*)(wsb + 46485504);

  float* yout = out;                               // [4096][1024]
  float* att  = out + (size_t)T_DIM * D_DIM;       // [4096][4096]
  ushort* xhi = (ushort*)att;                      // scratch in att region
  ushort* xlo = xhi + 4194304;
  ushort* Qhi = xlo + 4194304;
  ushort* Qlo = Qhi + 4194304;
  ushort* Khi = Qlo + 4194304;
  ushort* Klo = Khi + 4194304;

  k_split<<<4096, 256, 0, stream>>>(x, xhi, xlo);
  k_split<<<1024, 256, 0, stream>>>(Wq, Wqh, Wql);
  k_split<<<1024, 256, 0, stream>>>(Wk, Wkh, Wkl);
  k_split<<<1024, 256, 0, stream>>>(Wv, Wvh, Wvl);
  k_rownorm<<<T_DIM, 256, 0, stream>>>(x, Uh);
  k_bsum<<<NBLK, 256, 0, stream>>>(Uh, Sb);
  k_gsum<<<4, 256, 0, stream>>>(Sb, Sg);

  dim3 gq(16, 64);
  k_qkv<0><<<gq, 256, 0, stream>>>(xhi, xlo, Wqh, Wql, Qhi, Qlo);
  k_qkv<0><<<gq, 256, 0, stream>>>(xhi, xlo, Wkh, Wkl, Khi, Klo);
  k_qkv<1><<<gq, 256, 0, stream>>>(xhi, xlo, Wvh, Wvl, Vb, nullptr);

  k_stream<<<512, 256, 0, stream>>>(Qhi, Qlo, Khi, Klo, Uh, eb, db, pm, pZ, pWe, pWd);
  k_merge<<<T_DIM, 256, 0, stream>>>(pm, pZ, pWe, pWd, Uh, Sg, Sb, eb, db, dep, ent, mrow, zrow);
  k_entnorm<<<1, 256, 0, stream>>>(ent);

  hipMemsetAsync(att, 0, (size_t)T_DIM * T_DIM * sizeof(float), stream);
  k_repack<<<1024, 256, 0, stream>>>(Wout, Wob);
  k_atty<<<dim3(NBLK, 4), 256, 0, stream>>>(eb, mrow, zrow, dep, Vb, att, Ybf);
  k_final<<<gq, 256, 0, stream>>>(Ybf, Wob, Wout, ent, dep, yout);
}

// Round 5
// 656.852 us; speedup vs baseline: 3.1741x; 1.1033x over previous
//
#include <hip/hip_runtime.h>
#include <math.h>

#define T_DIM 4096
#define D_DIM 1024
#define BS 60
#define NBLK 69
#define NPART 64

typedef __attribute__((ext_vector_type(4))) float f32x4;
typedef __attribute__((ext_vector_type(8))) short short8;
#define MFMA(a,b,c) __builtin_amdgcn_mfma_f32_16x16x32_bf16((a),(b),(c),0,0,0)

static __device__ __forceinline__ ushort f2bf(float f) {
  unsigned x = __float_as_uint(f);
  unsigned r = x + 0x7fffu + ((x >> 16) & 1u);
  return (ushort)(r >> 16);
}
static __device__ __forceinline__ float bf2f(ushort u) {
  return __uint_as_float((unsigned)u << 16);
}

// ---------------------------------------------------------------------------
__global__ __launch_bounds__(256) void k_split(const float* __restrict__ A,
    ushort* __restrict__ hi, ushort* __restrict__ lo) {
  size_t i = ((size_t)blockIdx.x * 256 + threadIdx.x) * 4;
  float4 v = *reinterpret_cast<const float4*>(A + i);
  ushort4 h, l;
  h.x = f2bf(v.x); l.x = f2bf(v.x - bf2f(h.x));
  h.y = f2bf(v.y); l.y = f2bf(v.y - bf2f(h.y));
  h.z = f2bf(v.z); l.z = f2bf(v.z - bf2f(h.z));
  h.w = f2bf(v.w); l.w = f2bf(v.w - bf2f(h.w));
  *reinterpret_cast<ushort4*>(hi + i) = h;
  *reinterpret_cast<ushort4*>(lo + i) = l;
}

__global__ __launch_bounds__(256) void k_rownorm(const float* __restrict__ x, ushort* __restrict__ u) {
  int i = blockIdx.x, tid = threadIdx.x;
  float4 v = *reinterpret_cast<const float4*>(x + (size_t)i * D_DIM + tid * 4);
  float ss = v.x*v.x + v.y*v.y + v.z*v.z + v.w*v.w;
#pragma unroll
  for (int m = 1; m < 64; m <<= 1) ss += __shfl_xor(ss, m);
  __shared__ float sb[4];
  if ((tid & 63) == 0) sb[tid >> 6] = ss;
  __syncthreads();
  float inv = 1.0f / fmaxf(sqrtf(sb[0] + sb[1] + sb[2] + sb[3]), 1e-12f);
  ushort4 o;
  o.x = f2bf(v.x*inv); o.y = f2bf(v.y*inv); o.z = f2bf(v.z*inv); o.w = f2bf(v.w*inv);
  *reinterpret_cast<ushort4*>(u + (size_t)i * D_DIM + tid * 4) = o;
}

__global__ __launch_bounds__(256) void k_bsum(const ushort* __restrict__ u, float* __restrict__ Sb) {
  int b = blockIdx.x, tid = threadIdx.x;
  int j0 = b * BS;
  int w = (BS < T_DIM - j0) ? BS : (T_DIM - j0);
  int c = tid * 4;
  float4 acc = {0,0,0,0};
  for (int j = 0; j < w; ++j) {
    ushort4 v = *reinterpret_cast<const ushort4*>(u + (size_t)(j0 + j) * D_DIM + c);
    acc.x += bf2f(v.x); acc.y += bf2f(v.y); acc.z += bf2f(v.z); acc.w += bf2f(v.w);
  }
  *reinterpret_cast<float4*>(Sb + (size_t)b * D_DIM + c) = acc;
}

__global__ __launch_bounds__(256) void k_gsum(const float* __restrict__ Sb, float* __restrict__ S) {
  int c = blockIdx.x * 256 + threadIdx.x;
  float s = 0.f;
  for (int b = 0; b < NBLK; ++b) s += Sb[(size_t)b * D_DIM + c];
  S[c] = s;
}

// ---------------------------------------------------------------------------
// Fused Q+K MFMA GEMM (3-term split each): Q = x@Wq^T, K = x@Wk^T.
// Tile 128i x 64j, waves 64x32, BK=32, reg-staged ds_write + depth-1 prefetch.
__global__ __launch_bounds__(256,2) void k_qk(
    const ushort* __restrict__ xhi, const ushort* __restrict__ xlo,
    const ushort* __restrict__ Wqh, const ushort* __restrict__ Wql,
    const ushort* __restrict__ Wkh, const ushort* __restrict__ Wkl,
    ushort* __restrict__ Qhi, ushort* __restrict__ Qlo,
    ushort* __restrict__ Khi, ushort* __restrict__ Klo) {
  __shared__ __align__(16) ushort lds[16384]; // xh@0 xl@4096 (128x32) | Wqh@8192 Wql@10240 Wkh@12288 Wkl@14336 (64x32)
  const int tid = threadIdx.x;
  const int w = tid >> 6, lane = tid & 63;
  const int wr = w >> 1, wc = w & 1;
  const int g = lane >> 4, cl = lane & 15;
  const int i0 = blockIdx.y * 128, j0 = blockIdx.x * 64;

  int adA[4], adB[2];
#pragma unroll
  for (int is = 0; is < 4; ++is) {
    int r = wr*64 + is*16 + cl;
    adA[is] = r*32 + (g ^ ((r >> 1) & 3))*8;
  }
#pragma unroll
  for (int js = 0; js < 2; ++js) {
    int r = wc*32 + js*16 + cl;
    adB[js] = r*32 + (g ^ ((r >> 1) & 3))*8;
  }

  const int ra1 = tid >> 2, ra2 = 64 + (tid >> 2), rbr = tid >> 2;
  const int sa = tid & 3;
  const int wA1 = ra1*32 + (sa ^ ((ra1 >> 1) & 3))*8;
  const int wA2 = ra2*32 + (sa ^ ((ra2 >> 1) & 3))*8;
  const int wB  = rbr*32 + (sa ^ ((rbr >> 1) & 3))*8;
  const size_t gA1 = (size_t)(i0 + ra1) * D_DIM + sa*8;
  const size_t gA2 = (size_t)(i0 + ra2) * D_DIM + sa*8;
  const size_t gB  = (size_t)(j0 + rbr) * D_DIM + sa*8;

  f32x4 accQ[4][2], accK[4][2];
#pragma unroll
  for (int is = 0; is < 4; ++is)
#pragma unroll
    for (int js = 0; js < 2; ++js) {
      accQ[is][js] = (f32x4){0.f,0.f,0.f,0.f};
      accK[is][js] = (f32x4){0.f,0.f,0.f,0.f};
    }

  short8 sXh1 = *reinterpret_cast<const short8*>(xhi + gA1);
  short8 sXh2 = *reinterpret_cast<const short8*>(xhi + gA2);
  short8 sXl1 = *reinterpret_cast<const short8*>(xlo + gA1);
  short8 sXl2 = *reinterpret_cast<const short8*>(xlo + gA2);
  short8 sQh  = *reinterpret_cast<const short8*>(Wqh + gB);
  short8 sQl  = *reinterpret_cast<const short8*>(Wql + gB);
  short8 sKh  = *reinterpret_cast<const short8*>(Wkh + gB);
  short8 sKl  = *reinterpret_cast<const short8*>(Wkl + gB);

  for (int ks = 0; ks < 32; ++ks) {
    __syncthreads();
    *reinterpret_cast<short8*>(&lds[wA1])          = sXh1;
    *reinterpret_cast<short8*>(&lds[wA2])          = sXh2;
    *reinterpret_cast<short8*>(&lds[4096 + wA1])   = sXl1;
    *reinterpret_cast<short8*>(&lds[4096 + wA2])   = sXl2;
    *reinterpret_cast<short8*>(&lds[8192 + wB])    = sQh;
    *reinterpret_cast<short8*>(&lds[10240 + wB])   = sQl;
    *reinterpret_cast<short8*>(&lds[12288 + wB])   = sKh;
    *reinterpret_cast<short8*>(&lds[14336 + wB])   = sKl;
    __syncthreads();
    short8 aH[4], aL[4], bQh[2], bQl[2], bKh[2], bKl[2];
#pragma unroll
    for (int is = 0; is < 4; ++is) {
      aH[is] = *reinterpret_cast<const short8*>(&lds[adA[is]]);
      aL[is] = *reinterpret_cast<const short8*>(&lds[4096 + adA[is]]);
    }
#pragma unroll
    for (int js = 0; js < 2; ++js) {
      bQh[js] = *reinterpret_cast<const short8*>(&lds[8192  + adB[js]]);
      bQl[js] = *reinterpret_cast<const short8*>(&lds[10240 + adB[js]]);
      bKh[js] = *reinterpret_cast<const short8*>(&lds[12288 + adB[js]]);
      bKl[js] = *reinterpret_cast<const short8*>(&lds[14336 + adB[js]]);
    }
    if (ks < 31) {
      const int k0 = (ks + 1) * 32;
      sXh1 = *reinterpret_cast<const short8*>(xhi + gA1 + k0);
      sXh2 = *reinterpret_cast<const short8*>(xhi + gA2 + k0);
      sXl1 = *reinterpret_cast<const short8*>(xlo + gA1 + k0);
      sXl2 = *reinterpret_cast<const short8*>(xlo + gA2 + k0);
      sQh  = *reinterpret_cast<const short8*>(Wqh + gB + k0);
      sQl  = *reinterpret_cast<const short8*>(Wql + gB + k0);
      sKh  = *reinterpret_cast<const short8*>(Wkh + gB + k0);
      sKl  = *reinterpret_cast<const short8*>(Wkl + gB + k0);
    }
#pragma unroll
    for (int js = 0; js < 2; ++js)
#pragma unroll
      for (int is = 0; is < 4; ++is) {
        accQ[is][js] = MFMA(aH[is], bQh[js], accQ[is][js]);
        accQ[is][js] = MFMA(aL[is], bQh[js], accQ[is][js]);
        accQ[is][js] = MFMA(aH[is], bQl[js], accQ[is][js]);
        accK[is][js] = MFMA(aH[is], bKh[js], accK[is][js]);
        accK[is][js] = MFMA(aL[is], bKh[js], accK[is][js]);
        accK[is][js] = MFMA(aH[is], bKl[js], accK[is][js]);
      }
  }
#pragma unroll
  for (int is = 0; is < 4; ++is)
#pragma unroll
    for (int js = 0; js < 2; ++js)
#pragma unroll
      for (int a = 0; a < 4; ++a) {
        int gi = i0 + wr*64 + is*16 + g*4 + a;
        int gj = j0 + wc*32 + js*16 + cl;
        float vq = accQ[is][js][a];
        ushort hq = f2bf(vq);
        Qhi[(size_t)gi*D_DIM + gj] = hq;
        Qlo[(size_t)gi*D_DIM + gj] = f2bf(vq - bf2f(hq));
        float vk = accK[is][js][a];
        ushort hk = f2bf(vk);
        Khi[(size_t)gi*D_DIM + gj] = hk;
        Klo[(size_t)gi*D_DIM + gj] = f2bf(vk - bf2f(hk));
      }
}

// ---------------------------------------------------------------------------
// V = x@Wv^T, 1-term bf16 (R2-proven skeleton: A direct global, B LDS-staged).
__global__ __launch_bounds__(256,4) void k_v(
    const ushort* __restrict__ Ahi, const ushort* __restrict__ Bhi,
    ushort* __restrict__ C) {
  __shared__ ushort ldsB[4096];  // 64 rows x 64k
  const int tid = threadIdx.x;
  const int w = tid >> 6, lane = tid & 63;
  const int wr = w >> 1, wc = w & 1;
  const int g = lane >> 4, cl = lane & 15;
  const int i0 = blockIdx.y * 64, j0 = blockIdx.x * 64;
  f32x4 acc[2][2];
#pragma unroll
  for (int a = 0; a < 2; ++a)
#pragma unroll
    for (int b = 0; b < 2; ++b) acc[a][b] = (f32x4){0.f,0.f,0.f,0.f};
  const int ar0 = i0 + wr*32 + cl;

  for (int ks = 0; ks < 16; ++ks) {
    const int k0 = ks * 64;
    short8 aH[2][2];
#pragma unroll
    for (int is = 0; is < 2; ++is) {
      const size_t rb = (size_t)(ar0 + is*16) * D_DIM + k0;
#pragma unroll
      for (int h = 0; h < 2; ++h)
        aH[is][h] = *reinterpret_cast<const short8*>(Ahi + rb + (h*4+g)*8);
    }
    __syncthreads();
#pragma unroll
    for (int p = 0; p < 2; ++p) {
      const int s = tid + p*256;
      const int r = s >> 3, c = s & 7;
      const int loff = r*64 + (c ^ (r & 7))*8;
      *reinterpret_cast<short8*>(&ldsB[loff]) =
          *reinterpret_cast<const short8*>(Bhi + (size_t)(j0 + r) * D_DIM + k0 + c*8);
    }
    __syncthreads();
#pragma unroll
    for (int h = 0; h < 2; ++h)
#pragma unroll
      for (int js = 0; js < 2; ++js) {
        const int br = wc*32 + js*16 + cl;
        short8 bH = *reinterpret_cast<const short8*>(&ldsB[br*64 + ((h*4+g) ^ (br & 7))*8]);
#pragma unroll
        for (int is = 0; is < 2; ++is)
          acc[is][js] = MFMA(aH[is][h], bH, acc[is][js]);
      }
  }
#pragma unroll
  for (int is = 0; is < 2; ++is)
#pragma unroll
    for (int js = 0; js < 2; ++js)
#pragma unroll
      for (int a = 0; a < 4; ++a) {
        int gi = i0 + wr*32 + is*16 + g*4 + a;
        int gj = j0 + wc*32 + js*16 + cl;
        C[(size_t)gi*D_DIM + gj] = f2bf(acc[is][js][a]);
      }
}

// ---------------------------------------------------------------------------
// Fused stream: E = Q@K^T (3-term) and Dv = U@U^T (1-term).
// WG tile 128i x 64j per jt (2 jt = 128-col chunk), wave 64x32, BK=32.
// Grid 1024 -> 4 blocks/CU (LDS 40960*4 = 160KiB exactly, VGPR<=128).
__global__ __launch_bounds__(256,4) void k_stream(
    const ushort* __restrict__ Qhi, const ushort* __restrict__ Qlo,
    const ushort* __restrict__ Khi, const ushort* __restrict__ Klo,
    const ushort* __restrict__ Uh,
    float* __restrict__ eb, float* __restrict__ db,
    float* __restrict__ pm, float* __restrict__ pZ,
    float* __restrict__ pWe, float* __restrict__ pWd) {
  __shared__ __align__(16) ushort lds[18432]; // Qhi@0 Qlo@4096 Ui@8192 (128x32) | Khi@12288 Klo@14336 Uj@16384 (64x32)
  __shared__ float stat_s[2][2][64][4];
  const int tid = threadIdx.x;
  const int bid = blockIdx.x;
  const int wg = (bid & 7) * 128 + (bid >> 3);   // XCD-bijective (1024 % 8 == 0)
  const int it = wg >> 5, chunk = wg & 31;
  const int i0 = it * 128;
  const int w = tid >> 6, lane = tid & 63;
  const int wr = w >> 1, wc = w & 1;
  const int g = lane >> 4, cl = lane & 15;

  int adA[4], adB[2];
#pragma unroll
  for (int is = 0; is < 4; ++is) {
    int r = wr*64 + is*16 + cl;
    adA[is] = r*32 + (g ^ ((r >> 1) & 3))*8;
  }
#pragma unroll
  for (int js = 0; js < 2; ++js) {
    int r = wc*32 + js*16 + cl;
    adB[js] = r*32 + (g ^ ((r >> 1) & 3))*8;
  }

  const int ra1 = tid >> 2, ra2 = 64 + (tid >> 2), rbr = tid >> 2;
  const int sa = tid & 3;
  const int wA1 = ra1*32 + (sa ^ ((ra1 >> 1) & 3))*8;
  const int wA2 = ra2*32 + (sa ^ ((ra2 >> 1) & 3))*8;
  const int wB  = rbr*32 + (sa ^ ((rbr >> 1) & 3))*8;
  const size_t gA1 = (size_t)(i0 + ra1) * D_DIM + sa*8;
  const size_t gA2 = (size_t)(i0 + ra2) * D_DIM + sa*8;

  const int iw0 = i0 + wr*64;
  const int blkLo = iw0 / BS, blkHi = (iw0 + 63) / BS;

  for (int jt = 0; jt < 2; ++jt) {
    const int jb = chunk*128 + jt*64;
    const size_t gB = (size_t)(jb + rbr) * D_DIM + sa*8;

    f32x4 accE[4][2], accD[4][2];
#pragma unroll
    for (int is = 0; is < 4; ++is)
#pragma unroll
      for (int js = 0; js < 2; ++js) {
        accE[is][js] = (f32x4){0.f,0.f,0.f,0.f};
        accD[is][js] = (f32x4){0.f,0.f,0.f,0.f};
      }

    short8 sQh1 = *reinterpret_cast<const short8*>(Qhi + gA1);
    short8 sQh2 = *reinterpret_cast<const short8*>(Qhi + gA2);
    short8 sQl1 = *reinterpret_cast<const short8*>(Qlo + gA1);
    short8 sQl2 = *reinterpret_cast<const short8*>(Qlo + gA2);
    short8 sUi1 = *reinterpret_cast<const short8*>(Uh  + gA1);
    short8 sUi2 = *reinterpret_cast<const short8*>(Uh  + gA2);
    short8 sKh  = *reinterpret_cast<const short8*>(Khi + gB);
    short8 sKl  = *reinterpret_cast<const short8*>(Klo + gB);
    short8 sUj  = *reinterpret_cast<const short8*>(Uh  + gB);

    for (int ks = 0; ks < 32; ++ks) {
      __syncthreads();
      *reinterpret_cast<short8*>(&lds[wA1])         = sQh1;
      *reinterpret_cast<short8*>(&lds[wA2])         = sQh2;
      *reinterpret_cast<short8*>(&lds[4096 + wA1])  = sQl1;
      *reinterpret_cast<short8*>(&lds[4096 + wA2])  = sQl2;
      *reinterpret_cast<short8*>(&lds[8192 + wA1])  = sUi1;
      *reinterpret_cast<short8*>(&lds[8192 + wA2])  = sUi2;
      *reinterpret_cast<short8*>(&lds[12288 + wB])  = sKh;
      *reinterpret_cast<short8*>(&lds[14336 + wB])  = sKl;
      *reinterpret_cast<short8*>(&lds[16384 + wB])  = sUj;
      __syncthreads();
      short8 aQh[4], aQl[4], aU[4], bKh[2], bKl[2], bU[2];
#pragma unroll
      for (int is = 0; is < 4; ++is) {
        aQh[is] = *reinterpret_cast<const short8*>(&lds[adA[is]]);
        aQl[is] = *reinterpret_cast<const short8*>(&lds[4096 + adA[is]]);
        aU [is] = *reinterpret_cast<const short8*>(&lds[8192 + adA[is]]);
      }
#pragma unroll
      for (int js = 0; js < 2; ++js) {
        bKh[js] = *reinterpret_cast<const short8*>(&lds[12288 + adB[js]]);
        bKl[js] = *reinterpret_cast<const short8*>(&lds[14336 + adB[js]]);
        bU [js] = *reinterpret_cast<const short8*>(&lds[16384 + adB[js]]);
      }
      if (ks < 31) {   // issue next-K loads under the MFMA block
        const int k0 = (ks + 1) * 32;
        sQh1 = *reinterpret_cast<const short8*>(Qhi + gA1 + k0);
        sQh2 = *reinterpret_cast<const short8*>(Qhi + gA2 + k0);
        sQl1 = *reinterpret_cast<const short8*>(Qlo + gA1 + k0);
        sQl2 = *reinterpret_cast<const short8*>(Qlo + gA2 + k0);
        sUi1 = *reinterpret_cast<const short8*>(Uh  + gA1 + k0);
        sUi2 = *reinterpret_cast<const short8*>(Uh  + gA2 + k0);
        sKh  = *reinterpret_cast<const short8*>(Khi + gB + k0);
        sKl  = *reinterpret_cast<const short8*>(Klo + gB + k0);
        sUj  = *reinterpret_cast<const short8*>(Uh  + gB + k0);
      }
#pragma unroll
      for (int js = 0; js < 2; ++js)
#pragma unroll
        for (int is = 0; is < 4; ++is) {
          accE[is][js] = MFMA(aQh[is], bKh[js], accE[is][js]);
          accE[is][js] = MFMA(aQl[is], bKh[js], accE[is][js]);
          accE[is][js] = MFMA(aQh[is], bKl[js], accE[is][js]);
          accD[is][js] = MFMA(aU[is],  bU[js],  accD[is][js]);
        }
    }

    // diagonal-block stash
    const int jw0 = jb + wc*32;
    if (jw0 < (blkHi+1)*BS && jw0 + 32 > blkLo*BS) {
#pragma unroll
      for (int is = 0; is < 4; ++is)
#pragma unroll
        for (int js = 0; js < 2; ++js)
#pragma unroll
          for (int a = 0; a < 4; ++a) {
            int gi = i0 + wr*64 + is*16 + g*4 + a;
            int gj = jw0 + js*16 + cl;
            int bi = gi / BS;
            if (gj / BS == bi) {
              int c = gj - bi * BS;
              eb[(size_t)gi*64 + c] = accE[is][js][a];
              db[(size_t)gi*64 + c] = accD[is][js][a];
            }
          }
    }

    // per-jt partial softmax stats over this 64-col tile
#pragma unroll
    for (int is = 0; is < 4; ++is)
#pragma unroll
      for (int a = 0; a < 4; ++a) {
        float e0 = accE[is][0][a], e1 = accE[is][1][a];
        float d0 = accD[is][0][a], d1 = accD[is][1][a];
        float tmax = fmaxf(e0, e1);
#pragma unroll
        for (int mk = 1; mk < 16; mk <<= 1) tmax = fmaxf(tmax, __shfl_xor(tmax, mk));
        float p0 = __expf(e0 - tmax), p1 = __expf(e1 - tmax);
        float z  = p0 + p1;
        float we = p0*e0 + p1*e1;
        float wd = p0*d0 + p1*d1;
#pragma unroll
        for (int mk = 1; mk < 16; mk <<= 1) {
          z += __shfl_xor(z, mk); we += __shfl_xor(we, mk); wd += __shfl_xor(wd, mk);
        }
        if (cl == 0) {
          int rl = is*16 + g*4 + a;
          stat_s[wr][wc][rl][0] = tmax;
          stat_s[wr][wc][rl][1] = z;
          stat_s[wr][wc][rl][2] = we;
          stat_s[wr][wc][rl][3] = wd;
        }
      }
    __syncthreads();
    if (tid < 128) {
      int rl = tid & 63, wr2 = tid >> 6;
      float m0 = stat_s[wr2][0][rl][0], Z0 = stat_s[wr2][0][rl][1];
      float We0 = stat_s[wr2][0][rl][2], Wd0 = stat_s[wr2][0][rl][3];
      float m1 = stat_s[wr2][1][rl][0], Z1 = stat_s[wr2][1][rl][1];
      float We1 = stat_s[wr2][1][rl][2], Wd1 = stat_s[wr2][1][rl][3];
      float nm = fmaxf(m0, m1);
      float s0 = __expf(m0 - nm), s1 = __expf(m1 - nm);
      size_t idx = (size_t)(chunk*2 + jt) * T_DIM + i0 + wr2*64 + rl;
      pm[idx]  = nm;
      pZ[idx]  = Z0*s0 + Z1*s1;
      pWe[idx] = We0*s0 + We1*s1;
      pWd[idx] = Wd0*s0 + Wd1*s1;
    }
  }
}

// ---------------------------------------------------------------------------
__global__ __launch_bounds__(256) void k_merge(const float* __restrict__ pm, const float* __restrict__ pZ,
    const float* __restrict__ pWe, const float* __restrict__ pWd,
    const ushort* __restrict__ Uh, const float* __restrict__ Sg, const float* __restrict__ Sb,
    const float* __restrict__ eb, const float* __restrict__ db,
    float* __restrict__ dep, float* __restrict__ ent, float* __restrict__ mrow, float* __restrict__ zrow) {
  int i = blockIdx.x, tid = threadIdx.x;
  float m = pm[i], Z = pZ[i], We = pWe[i], Wd = pWd[i];
  for (int c = 1; c < NPART; ++c) {
    float om = pm[(size_t)c*T_DIM + i], oZ = pZ[(size_t)c*T_DIM + i];
    float oWe = pWe[(size_t)c*T_DIM + i], oWd = pWd[(size_t)c*T_DIM + i];
    float nm = fmaxf(m, om);
    float s1 = __expf(m - nm), s2 = __expf(om - nm);
    Z = Z*s1 + oZ*s2; We = We*s1 + oWe*s2; Wd = Wd*s1 + oWd*s2; m = nm;
  }
  int b = i / BS, j0 = b * BS;
  int w = (BS < T_DIM - j0) ? BS : (T_DIM - j0);
  ushort4 uv = *reinterpret_cast<const ushort4*>(Uh + (size_t)i*D_DIM + tid*4);
  float4 Sv  = *reinterpret_cast<const float4*>(Sg + tid*4);
  float4 Sbv = *reinterpret_cast<const float4*>(Sb + (size_t)b*D_DIM + tid*4);
  float ux = bf2f(uv.x), uy = bf2f(uv.y), uz = bf2f(uv.z), uw = bf2f(uv.w);
  float dS  = ux*Sv.x  + uy*Sv.y  + uz*Sv.z  + uw*Sv.w;
  float dSb = ux*Sbv.x + uy*Sbv.y + uz*Sbv.z + uw*Sbv.w;
  float pb = 0.f, pdb = 0.f;
  if (tid < w) {
    float e = eb[(size_t)i*64 + tid], d = db[(size_t)i*64 + tid];
    float p = __expf(e - m);
    pb = p; pdb = p * d;
  }
  float v0 = dS, v1 = dSb, v2 = pb, v3 = pdb;
#pragma unroll
  for (int mk = 1; mk < 64; mk <<= 1) {
    v0 += __shfl_xor(v0, mk); v1 += __shfl_xor(v1, mk);
    v2 += __shfl_xor(v2, mk); v3 += __shfl_xor(v3, mk);
  }
  __shared__ float red[4][4];
  if ((tid & 63) == 0) { int wv = tid >> 6; red[0][wv]=v0; red[1][wv]=v1; red[2][wv]=v2; red[3][wv]=v3; }
  __syncthreads();
  if (tid == 0) {
    float tdS  = red[0][0]+red[0][1]+red[0][2]+red[0][3];
    float tdSb = red[1][0]+red[1][1]+red[1][2]+red[1][3];
    float s1   = red[2][0]+red[2][1]+red[2][2]+red[2][3];
    float s2   = red[3][0]+red[3][1]+red[3][2]+red[3][3];
    float invZ = 1.0f / Z;
    float num = (1.0f - s1*invZ) - (Wd - s2)*invZ;
    float den = (float)(T_DIM - w) - (tdS - tdSb);
    dep[i] = num / den;
    ent[i] = -(We*invZ - m - logf(Z)) / logf((float)T_DIM);
    mrow[i] = m; zrow[i] = Z;
  }
}

__global__ __launch_bounds__(256) void k_entnorm(float* __restrict__ ent) {
  int tid = threadIdx.x;
  float s = 0.f;
  for (int i = tid; i < T_DIM; i += 256) s += fabsf(ent[i]);
#pragma unroll
  for (int mk = 1; mk < 64; mk <<= 1) s += __shfl_xor(s, mk);
  __shared__ float sb[4];
  if ((tid & 63) == 0) sb[tid >> 6] = s;
  __syncthreads();
  float inv = 1.0f / fmaxf(sb[0] + sb[1] + sb[2] + sb[3], 1e-12f);
  for (int i = tid; i < T_DIM; i += 256) ent[i] *= inv;
}

__global__ __launch_bounds__(256) void k_repack(const float* __restrict__ Wout, ushort* __restrict__ Wob) {
  int o = blockIdx.x;
  for (int k = threadIdx.x; k < 1024; k += 256)
    Wob[(size_t)o * 1024 + k] = f2bf(Wout[(size_t)o * 1026 + k]);
}

// diagonal att write + y = att_win @ V, y stored bf16
__global__ __launch_bounds__(256) void k_atty(const float* __restrict__ eb, const float* __restrict__ mrow,
    const float* __restrict__ zrow, const float* __restrict__ dep, const ushort* __restrict__ Vb,
    float* __restrict__ att, ushort* __restrict__ Ybf) {
  int b = blockIdx.x;
  int j0 = b * BS;
  int w = (BS < T_DIM - j0) ? BS : (T_DIM - j0);
  __shared__ float wl[BS][BS + 1];
  int tid = threadIdx.x;
  for (int idx = tid; idx < BS * (BS + 1); idx += 256) (&wl[0][0])[idx] = 0.0f;
  __syncthreads();
  for (int idx = tid; idx < w * w; idx += 256) {
    int rr = idx / w, c = idx - rr * w;
    int gi = j0 + rr;
    float val = __expf(eb[(size_t)gi * 64 + c] - mrow[gi]) / zrow[gi] + dep[j0 + c];
    wl[rr][c] = val;
    if (blockIdx.y == 0) att[(size_t)gi * T_DIM + j0 + c] = val;
  }
  __syncthreads();
  int c = blockIdx.y * 256 + tid;
  float acc[BS];
#pragma unroll
  for (int rr = 0; rr < BS; ++rr) acc[rr] = 0.f;
  for (int j = 0; j < w; ++j) {
    float v = bf2f(Vb[(size_t)(j0 + j) * D_DIM + c]);
#pragma unroll
    for (int rr = 0; rr < BS; ++rr) acc[rr] = fmaf(wl[rr][j], v, acc[rr]);
  }
#pragma unroll
  for (int rr = 0; rr < BS; ++rr)
    if (rr < w) Ybf[(size_t)(j0 + rr) * D_DIM + c] = f2bf(acc[rr]);
}

// ---------------------------------------------------------------------------
// Final projection: yout = Ybf @ Wob^T (1-term bf16) + ent/dep epilogue.
__global__ __launch_bounds__(256,4) void k_final(
    const ushort* __restrict__ Ybf, const ushort* __restrict__ Wob,
    const float* __restrict__ Wout, const float* __restrict__ ent,
    const float* __restrict__ dep, float* __restrict__ yout) {
  __shared__ ushort ldsB[4096];  // 64 rows x 64k
  const int tid = threadIdx.x;
  const int w = tid >> 6, lane = tid & 63;
  const int wr = w >> 1, wc = w & 1;
  const int g = lane >> 4, cl = lane & 15;
  const int i0 = blockIdx.y * 64, j0 = blockIdx.x * 64;
  f32x4 acc[2][2];
#pragma unroll
  for (int a = 0; a < 2; ++a)
#pragma unroll
    for (int b = 0; b < 2; ++b) acc[a][b] = (f32x4){0.f,0.f,0.f,0.f};
  const int ar0 = i0 + wr*32 + cl;

  for (int ks = 0; ks < 16; ++ks) {
    const int k0 = ks * 64;
    short8 aY[2][2];
#pragma unroll
    for (int is = 0; is < 2; ++is) {
      const size_t rb = (size_t)(ar0 + is*16) * D_DIM + k0;
#pragma unroll
      for (int h = 0; h < 2; ++h)
        aY[is][h] = *reinterpret_cast<const short8*>(Ybf + rb + (h*4+g)*8);
    }
    __syncthreads();
#pragma unroll
    for (int p = 0; p < 2; ++p) {
      const int s = tid + p*256;
      const int r = s >> 3, c = s & 7;
      const int loff = r*64 + (c ^ (r & 7))*8;
      *reinterpret_cast<short8*>(&ldsB[loff]) =
          *reinterpret_cast<const short8*>(Wob + (size_t)(j0 + r) * D_DIM + k0 + c*8);
    }
    __syncthreads();
#pragma unroll
    for (int h = 0; h < 2; ++h)
#pragma unroll
      for (int js = 0; js < 2; ++js) {
        const int br = wc*32 + js*16 + cl;
        short8 bW = *reinterpret_cast<const short8*>(&ldsB[br*64 + ((h*4+g) ^ (br & 7))*8]);
#pragma unroll
        for (int is = 0; is < 2; ++is)
          acc[is][js] = MFMA(aY[is][h], bW, acc[is][js]);
      }
  }
  float w1[2], w2[2];
#pragma unroll
  for (int js = 0; js < 2; ++js) {
    int gj = j0 + wc*32 + js*16 + cl;
    w1[js] = Wout[(size_t)gj * 1026 + 1024];
    w2[js] = Wout[(size_t)gj * 1026 + 1025];
  }
#pragma unroll
  for (int is = 0; is < 2; ++is)
#pragma unroll
    for (int a = 0; a < 4; ++a) {
      int gi = i0 + wr*32 + is*16 + g*4 + a;
      float e = ent[gi], d = dep[gi];
#pragma unroll
      for (int js = 0; js < 2; ++js) {
        int gj = j0 + wc*32 + js*16 + cl;
        yout[(size_t)gi * D_DIM + gj] = acc[is][js][a] + e * w1[js] + d * w2[js];
      }
    }
}

// ---------------------------------------------------------------------------
extern "C" void kernel_launch(void* const* d_in, const int* in_sizes, int n_in,
                              void* d_out, int out_size, void* d_ws, size_t ws_size,
                              hipStream_t stream) {
  const float* x    = (const float*)d_in[0];
  const float* Wk   = (const float*)d_in[1];
  const float* Wq   = (const float*)d_in[2];
  const float* Wv   = (const float*)d_in[3];
  const float* Wout = (const float*)d_in[4];
  float* out = (float*)d_out;
  char* wsb  = (char*)d_ws;

  ushort* Uh   = (ushort*)(wsb + 0);            // 8 MB
  ushort* Vb   = (ushort*)(wsb + 8388608);      // 8 MB
  ushort* Ybf  = (ushort*)(wsb + 16777216);     // 8 MB
  ushort* Wob  = (ushort*)(wsb + 25165824);     // 2 MB
  ushort* Wqh  = (ushort*)(wsb + 27262976);     // 6 x 2 MB
  ushort* Wql  = Wqh + 1048576;
  ushort* Wkh  = Wql + 1048576;
  ushort* Wkl  = Wkh + 1048576;
  ushort* Wvh  = Wkl + 1048576;
  ushort* Wvl  = Wvh + 1048576;
  float*  eb   = (float*)(wsb + 39845888);      // 1 MB
  float*  db   = (float*)(wsb + 40894464);      // 1 MB
  float*  pm   = (float*)(wsb + 41943040);      // 1 MB each (64 partials)
  float*  pZ   = (float*)(wsb + 42991616);
  float*  pWe  = (float*)(wsb + 44040192);
  float*  pWd  = (float*)(wsb + 45088768);
  float*  mrow = (float*)(wsb + 46137344);
  float*  zrow = (float*)(wsb + 46153728);
  float*  ent  = (float*)(wsb + 46170112);
  float*  dep  = (float*)(wsb + 46186496);
  float*  Sb   = (float*)(wsb + 46202880);
  float*  Sg   = (float*)(wsb + 46485504);

  float* yout = out;                               // [4096][1024]
  float* att  = out + (size_t)T_DIM * D_DIM;       // [4096][4096]
  ushort* xhi = (ushort*)att;                      // scratch in att region
  ushort* xlo = xhi + 4194304;
  ushort* Qhi = xlo + 4194304;
  ushort* Qlo = Qhi + 4194304;
  ushort* Khi = Qlo + 4194304;
  ushort* Klo = Khi + 4194304;

  k_split<<<4096, 256, 0, stream>>>(x, xhi, xlo);
  k_split<<<1024, 256, 0, stream>>>(Wq, Wqh, Wql);
  k_split<<<1024, 256, 0, stream>>>(Wk, Wkh, Wkl);
  k_split<<<1024, 256, 0, stream>>>(Wv, Wvh, Wvl);
  k_rownorm<<<T_DIM, 256, 0, stream>>>(x, Uh);
  k_bsum<<<NBLK, 256, 0, stream>>>(Uh, Sb);
  k_gsum<<<4, 256, 0, stream>>>(Sb, Sg);

  k_qk<<<dim3(16, 32), 256, 0, stream>>>(xhi, xlo, Wqh, Wql, Wkh, Wkl, Qhi, Qlo, Khi, Klo);
  k_v<<<dim3(16, 64), 256, 0, stream>>>(xhi, Wvh, Vb);

  k_stream<<<1024, 256, 0, stream>>>(Qhi, Qlo, Khi, Klo, Uh, eb, db, pm, pZ, pWe, pWd);
  k_merge<<<T_DIM, 256, 0, stream>>>(pm, pZ, pWe, pWd, Uh, Sg, Sb, eb, db, dep, ent, mrow, zrow);
  k_entnorm<<<1, 256, 0, stream>>>(ent);

  hipMemsetAsync(att, 0, (size_t)T_DIM * T_DIM * sizeof(float), stream);
  k_repack<<<1024, 256, 0, stream>>>(Wout, Wob);
  k_atty<<<dim3(NBLK, 4), 256, 0, stream>>>(eb, mrow, zrow, dep, Vb, att, Ybf);
  k_final<<<dim3(16, 64), 256, 0, stream>>>(Ybf, Wob, Wout, ent, dep, yout);
}

// Round 6
// 588.133 us; speedup vs baseline: 3.5450x; 1.1168x over previous
//
#include <hip/hip_runtime.h>
#include <math.h>

#define T_DIM 4096
#define D_DIM 1024
#define BS 60
#define NBLK 69
#define NPART 64

typedef __attribute__((ext_vector_type(4))) float f32x4;
typedef __attribute__((ext_vector_type(8))) short short8;
#define MFMA(a,b,c) __builtin_amdgcn_mfma_f32_16x16x32_bf16((a),(b),(c),0,0,0)

static __device__ __forceinline__ ushort f2bf(float f) {
  unsigned x = __float_as_uint(f);
  unsigned r = x + 0x7fffu + ((x >> 16) & 1u);
  return (ushort)(r >> 16);
}
static __device__ __forceinline__ float bf2f(ushort u) {
  return __uint_as_float((unsigned)u << 16);
}

// ---------------------------------------------------------------------------
__global__ __launch_bounds__(256) void k_split(const float* __restrict__ A,
    ushort* __restrict__ hi, ushort* __restrict__ lo) {
  size_t i = ((size_t)blockIdx.x * 256 + threadIdx.x) * 4;
  float4 v = *reinterpret_cast<const float4*>(A + i);
  ushort4 h, l;
  h.x = f2bf(v.x); l.x = f2bf(v.x - bf2f(h.x));
  h.y = f2bf(v.y); l.y = f2bf(v.y - bf2f(h.y));
  h.z = f2bf(v.z); l.z = f2bf(v.z - bf2f(h.z));
  h.w = f2bf(v.w); l.w = f2bf(v.w - bf2f(h.w));
  *reinterpret_cast<ushort4*>(hi + i) = h;
  *reinterpret_cast<ushort4*>(lo + i) = l;
}

__global__ __launch_bounds__(256) void k_rownorm(const float* __restrict__ x, ushort* __restrict__ u) {
  int i = blockIdx.x, tid = threadIdx.x;
  float4 v = *reinterpret_cast<const float4*>(x + (size_t)i * D_DIM + tid * 4);
  float ss = v.x*v.x + v.y*v.y + v.z*v.z + v.w*v.w;
#pragma unroll
  for (int m = 1; m < 64; m <<= 1) ss += __shfl_xor(ss, m);
  __shared__ float sb[4];
  if ((tid & 63) == 0) sb[tid >> 6] = ss;
  __syncthreads();
  float inv = 1.0f / fmaxf(sqrtf(sb[0] + sb[1] + sb[2] + sb[3]), 1e-12f);
  ushort4 o;
  o.x = f2bf(v.x*inv); o.y = f2bf(v.y*inv); o.z = f2bf(v.z*inv); o.w = f2bf(v.w*inv);
  *reinterpret_cast<ushort4*>(u + (size_t)i * D_DIM + tid * 4) = o;
}

__global__ __launch_bounds__(256) void k_bsum(const ushort* __restrict__ u, float* __restrict__ Sb) {
  int b = blockIdx.x, tid = threadIdx.x;
  int j0 = b * BS;
  int w = (BS < T_DIM - j0) ? BS : (T_DIM - j0);
  int c = tid * 4;
  float4 acc = {0,0,0,0};
  for (int j = 0; j < w; ++j) {
    ushort4 v = *reinterpret_cast<const ushort4*>(u + (size_t)(j0 + j) * D_DIM + c);
    acc.x += bf2f(v.x); acc.y += bf2f(v.y); acc.z += bf2f(v.z); acc.w += bf2f(v.w);
  }
  *reinterpret_cast<float4*>(Sb + (size_t)b * D_DIM + c) = acc;
}

__global__ __launch_bounds__(256) void k_gsum(const float* __restrict__ Sb, float* __restrict__ S) {
  int c = blockIdx.x * 256 + threadIdx.x;
  float s = 0.f;
  for (int b = 0; b < NBLK; ++b) s += Sb[(size_t)b * D_DIM + c];
  S[c] = s;
}

// ---------------------------------------------------------------------------
// Fused Q+K MFMA GEMM (3-term split each): Q = x@Wq^T, K = x@Wk^T.
__global__ __launch_bounds__(256,2) void k_qk(
    const ushort* __restrict__ xhi, const ushort* __restrict__ xlo,
    const ushort* __restrict__ Wqh, const ushort* __restrict__ Wql,
    const ushort* __restrict__ Wkh, const ushort* __restrict__ Wkl,
    ushort* __restrict__ Qhi, ushort* __restrict__ Qlo,
    ushort* __restrict__ Khi, ushort* __restrict__ Klo) {
  __shared__ __align__(16) ushort lds[16384]; // xh@0 xl@4096 (128x32) | Wqh@8192 Wql@10240 Wkh@12288 Wkl@14336 (64x32)
  const int tid = threadIdx.x;
  const int w = tid >> 6, lane = tid & 63;
  const int wr = w >> 1, wc = w & 1;
  const int g = lane >> 4, cl = lane & 15;
  const int i0 = blockIdx.y * 128, j0 = blockIdx.x * 64;

  int adA[4], adB[2];
#pragma unroll
  for (int is = 0; is < 4; ++is) {
    int r = wr*64 + is*16 + cl;
    adA[is] = r*32 + (g ^ ((r >> 1) & 3))*8;
  }
#pragma unroll
  for (int js = 0; js < 2; ++js) {
    int r = wc*32 + js*16 + cl;
    adB[js] = r*32 + (g ^ ((r >> 1) & 3))*8;
  }

  const int ra1 = tid >> 2, ra2 = 64 + (tid >> 2), rbr = tid >> 2;
  const int sa = tid & 3;
  const int wA1 = ra1*32 + (sa ^ ((ra1 >> 1) & 3))*8;
  const int wA2 = ra2*32 + (sa ^ ((ra2 >> 1) & 3))*8;
  const int wB  = rbr*32 + (sa ^ ((rbr >> 1) & 3))*8;
  const size_t gA1 = (size_t)(i0 + ra1) * D_DIM + sa*8;
  const size_t gA2 = (size_t)(i0 + ra2) * D_DIM + sa*8;
  const size_t gB  = (size_t)(j0 + rbr) * D_DIM + sa*8;

  f32x4 accQ[4][2], accK[4][2];
#pragma unroll
  for (int is = 0; is < 4; ++is)
#pragma unroll
    for (int js = 0; js < 2; ++js) {
      accQ[is][js] = (f32x4){0.f,0.f,0.f,0.f};
      accK[is][js] = (f32x4){0.f,0.f,0.f,0.f};
    }

  short8 sXh1 = *reinterpret_cast<const short8*>(xhi + gA1);
  short8 sXh2 = *reinterpret_cast<const short8*>(xhi + gA2);
  short8 sXl1 = *reinterpret_cast<const short8*>(xlo + gA1);
  short8 sXl2 = *reinterpret_cast<const short8*>(xlo + gA2);
  short8 sQh  = *reinterpret_cast<const short8*>(Wqh + gB);
  short8 sQl  = *reinterpret_cast<const short8*>(Wql + gB);
  short8 sKh  = *reinterpret_cast<const short8*>(Wkh + gB);
  short8 sKl  = *reinterpret_cast<const short8*>(Wkl + gB);

  for (int ks = 0; ks < 32; ++ks) {
    __syncthreads();
    *reinterpret_cast<short8*>(&lds[wA1])          = sXh1;
    *reinterpret_cast<short8*>(&lds[wA2])          = sXh2;
    *reinterpret_cast<short8*>(&lds[4096 + wA1])   = sXl1;
    *reinterpret_cast<short8*>(&lds[4096 + wA2])   = sXl2;
    *reinterpret_cast<short8*>(&lds[8192 + wB])    = sQh;
    *reinterpret_cast<short8*>(&lds[10240 + wB])   = sQl;
    *reinterpret_cast<short8*>(&lds[12288 + wB])   = sKh;
    *reinterpret_cast<short8*>(&lds[14336 + wB])   = sKl;
    __syncthreads();
    short8 aH[4], aL[4], bQh[2], bQl[2], bKh[2], bKl[2];
#pragma unroll
    for (int is = 0; is < 4; ++is) {
      aH[is] = *reinterpret_cast<const short8*>(&lds[adA[is]]);
      aL[is] = *reinterpret_cast<const short8*>(&lds[4096 + adA[is]]);
    }
#pragma unroll
    for (int js = 0; js < 2; ++js) {
      bQh[js] = *reinterpret_cast<const short8*>(&lds[8192  + adB[js]]);
      bQl[js] = *reinterpret_cast<const short8*>(&lds[10240 + adB[js]]);
      bKh[js] = *reinterpret_cast<const short8*>(&lds[12288 + adB[js]]);
      bKl[js] = *reinterpret_cast<const short8*>(&lds[14336 + adB[js]]);
    }
    if (ks < 31) {
      const int k0 = (ks + 1) * 32;
      sXh1 = *reinterpret_cast<const short8*>(xhi + gA1 + k0);
      sXh2 = *reinterpret_cast<const short8*>(xhi + gA2 + k0);
      sXl1 = *reinterpret_cast<const short8*>(xlo + gA1 + k0);
      sXl2 = *reinterpret_cast<const short8*>(xlo + gA2 + k0);
      sQh  = *reinterpret_cast<const short8*>(Wqh + gB + k0);
      sQl  = *reinterpret_cast<const short8*>(Wql + gB + k0);
      sKh  = *reinterpret_cast<const short8*>(Wkh + gB + k0);
      sKl  = *reinterpret_cast<const short8*>(Wkl + gB + k0);
    }
#pragma unroll
    for (int js = 0; js < 2; ++js)
#pragma unroll
      for (int is = 0; is < 4; ++is) {
        accQ[is][js] = MFMA(aH[is], bQh[js], accQ[is][js]);
        accQ[is][js] = MFMA(aL[is], bQh[js], accQ[is][js]);
        accQ[is][js] = MFMA(aH[is], bQl[js], accQ[is][js]);
        accK[is][js] = MFMA(aH[is], bKh[js], accK[is][js]);
        accK[is][js] = MFMA(aL[is], bKh[js], accK[is][js]);
        accK[is][js] = MFMA(aH[is], bKl[js], accK[is][js]);
      }
  }
#pragma unroll
  for (int is = 0; is < 4; ++is)
#pragma unroll
    for (int js = 0; js < 2; ++js)
#pragma unroll
      for (int a = 0; a < 4; ++a) {
        int gi = i0 + wr*64 + is*16 + g*4 + a;
        int gj = j0 + wc*32 + js*16 + cl;
        float vq = accQ[is][js][a];
        ushort hq = f2bf(vq);
        Qhi[(size_t)gi*D_DIM + gj] = hq;
        Qlo[(size_t)gi*D_DIM + gj] = f2bf(vq - bf2f(hq));
        float vk = accK[is][js][a];
        ushort hk = f2bf(vk);
        Khi[(size_t)gi*D_DIM + gj] = hk;
        Klo[(size_t)gi*D_DIM + gj] = f2bf(vk - bf2f(hk));
      }
}

// ---------------------------------------------------------------------------
// V = x@Wv^T, 1-term bf16 (R2-proven skeleton: A direct global, B LDS-staged).
__global__ __launch_bounds__(256,4) void k_v(
    const ushort* __restrict__ Ahi, const ushort* __restrict__ Bhi,
    ushort* __restrict__ C) {
  __shared__ ushort ldsB[4096];  // 64 rows x 64k
  const int tid = threadIdx.x;
  const int w = tid >> 6, lane = tid & 63;
  const int wr = w >> 1, wc = w & 1;
  const int g = lane >> 4, cl = lane & 15;
  const int i0 = blockIdx.y * 64, j0 = blockIdx.x * 64;
  f32x4 acc[2][2];
#pragma unroll
  for (int a = 0; a < 2; ++a)
#pragma unroll
    for (int b = 0; b < 2; ++b) acc[a][b] = (f32x4){0.f,0.f,0.f,0.f};
  const int ar0 = i0 + wr*32 + cl;

  for (int ks = 0; ks < 16; ++ks) {
    const int k0 = ks * 64;
    short8 aH[2][2];
#pragma unroll
    for (int is = 0; is < 2; ++is) {
      const size_t rb = (size_t)(ar0 + is*16) * D_DIM + k0;
#pragma unroll
      for (int h = 0; h < 2; ++h)
        aH[is][h] = *reinterpret_cast<const short8*>(Ahi + rb + (h*4+g)*8);
    }
    __syncthreads();
#pragma unroll
    for (int p = 0; p < 2; ++p) {
      const int s = tid + p*256;
      const int r = s >> 3, c = s & 7;
      const int loff = r*64 + (c ^ (r & 7))*8;
      *reinterpret_cast<short8*>(&ldsB[loff]) =
          *reinterpret_cast<const short8*>(Bhi + (size_t)(j0 + r) * D_DIM + k0 + c*8);
    }
    __syncthreads();
#pragma unroll
    for (int h = 0; h < 2; ++h)
#pragma unroll
      for (int js = 0; js < 2; ++js) {
        const int br = wc*32 + js*16 + cl;
        short8 bH = *reinterpret_cast<const short8*>(&ldsB[br*64 + ((h*4+g) ^ (br & 7))*8]);
#pragma unroll
        for (int is = 0; is < 2; ++is)
          acc[is][js] = MFMA(aH[is][h], bH, acc[is][js]);
      }
  }
#pragma unroll
  for (int is = 0; is < 2; ++is)
#pragma unroll
    for (int js = 0; js < 2; ++js)
#pragma unroll
      for (int a = 0; a < 4; ++a) {
        int gi = i0 + wr*32 + is*16 + g*4 + a;
        int gj = j0 + wc*32 + js*16 + cl;
        C[(size_t)gi*D_DIM + gj] = f2bf(acc[is][js][a]);
      }
}

// ---------------------------------------------------------------------------
// Fused stream: E = Q@K^T (3-term) and Dv = U@U^T (1-term).
// WG tile 128i x 64j per jt (2 jt = 128-col chunk), wave 64x32, BK=32.
// Grid 1024; launch_bounds (256,2) -> compiler ~128 VGPR -> 4 blocks/CU
// (LDS 40960*4 = 160KiB exactly).  NOTE: (256,4) forced 64 VGPR + scratch
// spills (R5: WRITE_SIZE 9.4->155MB) -- do not re-tighten.
__global__ __launch_bounds__(256,2) void k_stream(
    const ushort* __restrict__ Qhi, const ushort* __restrict__ Qlo,
    const ushort* __restrict__ Khi, const ushort* __restrict__ Klo,
    const ushort* __restrict__ Uh,
    float* __restrict__ eb, float* __restrict__ db,
    float* __restrict__ pm, float* __restrict__ pZ,
    float* __restrict__ pWe, float* __restrict__ pWd) {
  __shared__ __align__(16) ushort lds[18432]; // Qhi@0 Qlo@4096 Ui@8192 (128x32) | Khi@12288 Klo@14336 Uj@16384 (64x32)
  __shared__ float stat_s[2][2][64][4];
  const int tid = threadIdx.x;
  const int bid = blockIdx.x;
  const int wg = (bid & 7) * 128 + (bid >> 3);   // XCD-bijective (1024 % 8 == 0)
  const int it = wg >> 5, chunk = wg & 31;
  const int i0 = it * 128;
  const int w = tid >> 6, lane = tid & 63;
  const int wr = w >> 1, wc = w & 1;
  const int g = lane >> 4, cl = lane & 15;

  int adA[4], adB[2];
#pragma unroll
  for (int is = 0; is < 4; ++is) {
    int r = wr*64 + is*16 + cl;
    adA[is] = r*32 + (g ^ ((r >> 1) & 3))*8;
  }
#pragma unroll
  for (int js = 0; js < 2; ++js) {
    int r = wc*32 + js*16 + cl;
    adB[js] = r*32 + (g ^ ((r >> 1) & 3))*8;
  }

  const int ra1 = tid >> 2, ra2 = 64 + (tid >> 2), rbr = tid >> 2;
  const int sa = tid & 3;
  const int wA1 = ra1*32 + (sa ^ ((ra1 >> 1) & 3))*8;
  const int wA2 = ra2*32 + (sa ^ ((ra2 >> 1) & 3))*8;
  const int wB  = rbr*32 + (sa ^ ((rbr >> 1) & 3))*8;
  const size_t gA1 = (size_t)(i0 + ra1) * D_DIM + sa*8;
  const size_t gA2 = (size_t)(i0 + ra2) * D_DIM + sa*8;

  const int iw0 = i0 + wr*64;
  const int blkLo = iw0 / BS, blkHi = (iw0 + 63) / BS;

  for (int jt = 0; jt < 2; ++jt) {
    const int jb = chunk*128 + jt*64;
    const size_t gB = (size_t)(jb + rbr) * D_DIM + sa*8;

    f32x4 accE[4][2], accD[4][2];
#pragma unroll
    for (int is = 0; is < 4; ++is)
#pragma unroll
      for (int js = 0; js < 2; ++js) {
        accE[is][js] = (f32x4){0.f,0.f,0.f,0.f};
        accD[is][js] = (f32x4){0.f,0.f,0.f,0.f};
      }

    short8 sQh1 = *reinterpret_cast<const short8*>(Qhi + gA1);
    short8 sQh2 = *reinterpret_cast<const short8*>(Qhi + gA2);
    short8 sQl1 = *reinterpret_cast<const short8*>(Qlo + gA1);
    short8 sQl2 = *reinterpret_cast<const short8*>(Qlo + gA2);
    short8 sUi1 = *reinterpret_cast<const short8*>(Uh  + gA1);
    short8 sUi2 = *reinterpret_cast<const short8*>(Uh  + gA2);
    short8 sKh  = *reinterpret_cast<const short8*>(Khi + gB);
    short8 sKl  = *reinterpret_cast<const short8*>(Klo + gB);
    short8 sUj  = *reinterpret_cast<const short8*>(Uh  + gB);

    for (int ks = 0; ks < 32; ++ks) {
      __syncthreads();
      *reinterpret_cast<short8*>(&lds[wA1])         = sQh1;
      *reinterpret_cast<short8*>(&lds[wA2])         = sQh2;
      *reinterpret_cast<short8*>(&lds[4096 + wA1])  = sQl1;
      *reinterpret_cast<short8*>(&lds[4096 + wA2])  = sQl2;
      *reinterpret_cast<short8*>(&lds[8192 + wA1])  = sUi1;
      *reinterpret_cast<short8*>(&lds[8192 + wA2])  = sUi2;
      *reinterpret_cast<short8*>(&lds[12288 + wB])  = sKh;
      *reinterpret_cast<short8*>(&lds[14336 + wB])  = sKl;
      *reinterpret_cast<short8*>(&lds[16384 + wB])  = sUj;
      __syncthreads();
      short8 aQh[4], aQl[4], aU[4], bKh[2], bKl[2], bU[2];
#pragma unroll
      for (int is = 0; is < 4; ++is) {
        aQh[is] = *reinterpret_cast<const short8*>(&lds[adA[is]]);
        aQl[is] = *reinterpret_cast<const short8*>(&lds[4096 + adA[is]]);
        aU [is] = *reinterpret_cast<const short8*>(&lds[8192 + adA[is]]);
      }
#pragma unroll
      for (int js = 0; js < 2; ++js) {
        bKh[js] = *reinterpret_cast<const short8*>(&lds[12288 + adB[js]]);
        bKl[js] = *reinterpret_cast<const short8*>(&lds[14336 + adB[js]]);
        bU [js] = *reinterpret_cast<const short8*>(&lds[16384 + adB[js]]);
      }
      if (ks < 31) {   // issue next-K loads under the MFMA block
        const int k0 = (ks + 1) * 32;
        sQh1 = *reinterpret_cast<const short8*>(Qhi + gA1 + k0);
        sQh2 = *reinterpret_cast<const short8*>(Qhi + gA2 + k0);
        sQl1 = *reinterpret_cast<const short8*>(Qlo + gA1 + k0);
        sQl2 = *reinterpret_cast<const short8*>(Qlo + gA2 + k0);
        sUi1 = *reinterpret_cast<const short8*>(Uh  + gA1 + k0);
        sUi2 = *reinterpret_cast<const short8*>(Uh  + gA2 + k0);
        sKh  = *reinterpret_cast<const short8*>(Khi + gB + k0);
        sKl  = *reinterpret_cast<const short8*>(Klo + gB + k0);
        sUj  = *reinterpret_cast<const short8*>(Uh  + gB + k0);
      }
#pragma unroll
      for (int js = 0; js < 2; ++js)
#pragma unroll
        for (int is = 0; is < 4; ++is) {
          accE[is][js] = MFMA(aQh[is], bKh[js], accE[is][js]);
          accE[is][js] = MFMA(aQl[is], bKh[js], accE[is][js]);
          accE[is][js] = MFMA(aQh[is], bKl[js], accE[is][js]);
          accD[is][js] = MFMA(aU[is],  bU[js],  accD[is][js]);
        }
    }

    // diagonal-block stash
    const int jw0 = jb + wc*32;
    if (jw0 < (blkHi+1)*BS && jw0 + 32 > blkLo*BS) {
#pragma unroll
      for (int is = 0; is < 4; ++is)
#pragma unroll
        for (int js = 0; js < 2; ++js)
#pragma unroll
          for (int a = 0; a < 4; ++a) {
            int gi = i0 + wr*64 + is*16 + g*4 + a;
            int gj = jw0 + js*16 + cl;
            int bi = gi / BS;
            if (gj / BS == bi) {
              int c = gj - bi * BS;
              eb[(size_t)gi*64 + c] = accE[is][js][a];
              db[(size_t)gi*64 + c] = accD[is][js][a];
            }
          }
    }

    // per-jt partial softmax stats over this 64-col tile
#pragma unroll
    for (int is = 0; is < 4; ++is)
#pragma unroll
      for (int a = 0; a < 4; ++a) {
        float e0 = accE[is][0][a], e1 = accE[is][1][a];
        float d0 = accD[is][0][a], d1 = accD[is][1][a];
        float tmax = fmaxf(e0, e1);
#pragma unroll
        for (int mk = 1; mk < 16; mk <<= 1) tmax = fmaxf(tmax, __shfl_xor(tmax, mk));
        float p0 = __expf(e0 - tmax), p1 = __expf(e1 - tmax);
        float z  = p0 + p1;
        float we = p0*e0 + p1*e1;
        float wd = p0*d0 + p1*d1;
#pragma unroll
        for (int mk = 1; mk < 16; mk <<= 1) {
          z += __shfl_xor(z, mk); we += __shfl_xor(we, mk); wd += __shfl_xor(wd, mk);
        }
        if (cl == 0) {
          int rl = is*16 + g*4 + a;
          stat_s[wr][wc][rl][0] = tmax;
          stat_s[wr][wc][rl][1] = z;
          stat_s[wr][wc][rl][2] = we;
          stat_s[wr][wc][rl][3] = wd;
        }
      }
    __syncthreads();
    if (tid < 128) {
      int rl = tid & 63, wr2 = tid >> 6;
      float m0 = stat_s[wr2][0][rl][0], Z0 = stat_s[wr2][0][rl][1];
      float We0 = stat_s[wr2][0][rl][2], Wd0 = stat_s[wr2][0][rl][3];
      float m1 = stat_s[wr2][1][rl][0], Z1 = stat_s[wr2][1][rl][1];
      float We1 = stat_s[wr2][1][rl][2], Wd1 = stat_s[wr2][1][rl][3];
      float nm = fmaxf(m0, m1);
      float s0 = __expf(m0 - nm), s1 = __expf(m1 - nm);
      size_t idx = (size_t)(chunk*2 + jt) * T_DIM + i0 + wr2*64 + rl;
      pm[idx]  = nm;
      pZ[idx]  = Z0*s0 + Z1*s1;
      pWe[idx] = We0*s0 + We1*s1;
      pWd[idx] = Wd0*s0 + Wd1*s1;
    }
  }
}

// ---------------------------------------------------------------------------
__global__ __launch_bounds__(256) void k_merge(const float* __restrict__ pm, const float* __restrict__ pZ,
    const float* __restrict__ pWe, const float* __restrict__ pWd,
    const ushort* __restrict__ Uh, const float* __restrict__ Sg, const float* __restrict__ Sb,
    const float* __restrict__ eb, const float* __restrict__ db,
    float* __restrict__ dep, float* __restrict__ ent, float* __restrict__ mrow, float* __restrict__ zrow) {
  int i = blockIdx.x, tid = threadIdx.x;
  float m = pm[i], Z = pZ[i], We = pWe[i], Wd = pWd[i];
  for (int c = 1; c < NPART; ++c) {
    float om = pm[(size_t)c*T_DIM + i], oZ = pZ[(size_t)c*T_DIM + i];
    float oWe = pWe[(size_t)c*T_DIM + i], oWd = pWd[(size_t)c*T_DIM + i];
    float nm = fmaxf(m, om);
    float s1 = __expf(m - nm), s2 = __expf(om - nm);
    Z = Z*s1 + oZ*s2; We = We*s1 + oWe*s2; Wd = Wd*s1 + oWd*s2; m = nm;
  }
  int b = i / BS, j0 = b * BS;
  int w = (BS < T_DIM - j0) ? BS : (T_DIM - j0);
  ushort4 uv = *reinterpret_cast<const ushort4*>(Uh + (size_t)i*D_DIM + tid*4);
  float4 Sv  = *reinterpret_cast<const float4*>(Sg + tid*4);
  float4 Sbv = *reinterpret_cast<const float4*>(Sb + (size_t)b*D_DIM + tid*4);
  float ux = bf2f(uv.x), uy = bf2f(uv.y), uz = bf2f(uv.z), uw = bf2f(uv.w);
  float dS  = ux*Sv.x  + uy*Sv.y  + uz*Sv.z  + uw*Sv.w;
  float dSb = ux*Sbv.x + uy*Sbv.y + uz*Sbv.z + uw*Sbv.w;
  float pb = 0.f, pdb = 0.f;
  if (tid < w) {
    float e = eb[(size_t)i*64 + tid], d = db[(size_t)i*64 + tid];
    float p = __expf(e - m);
    pb = p; pdb = p * d;
  }
  float v0 = dS, v1 = dSb, v2 = pb, v3 = pdb;
#pragma unroll
  for (int mk = 1; mk < 64; mk <<= 1) {
    v0 += __shfl_xor(v0, mk); v1 += __shfl_xor(v1, mk);
    v2 += __shfl_xor(v2, mk); v3 += __shfl_xor(v3, mk);
  }
  __shared__ float red[4][4];
  if ((tid & 63) == 0) { int wv = tid >> 6; red[0][wv]=v0; red[1][wv]=v1; red[2][wv]=v2; red[3][wv]=v3; }
  __syncthreads();
  if (tid == 0) {
    float tdS  = red[0][0]+red[0][1]+red[0][2]+red[0][3];
    float tdSb = red[1][0]+red[1][1]+red[1][2]+red[1][3];
    float s1   = red[2][0]+red[2][1]+red[2][2]+red[2][3];
    float s2   = red[3][0]+red[3][1]+red[3][2]+red[3][3];
    float invZ = 1.0f / Z;
    float num = (1.0f - s1*invZ) - (Wd - s2)*invZ;
    float den = (float)(T_DIM - w) - (tdS - tdSb);
    dep[i] = num / den;
    ent[i] = -(We*invZ - m - logf(Z)) / logf((float)T_DIM);
    mrow[i] = m; zrow[i] = Z;
  }
}

__global__ __launch_bounds__(256) void k_entnorm(float* __restrict__ ent) {
  int tid = threadIdx.x;
  float s = 0.f;
  for (int i = tid; i < T_DIM; i += 256) s += fabsf(ent[i]);
#pragma unroll
  for (int mk = 1; mk < 64; mk <<= 1) s += __shfl_xor(s, mk);
  __shared__ float sb[4];
  if ((tid & 63) == 0) sb[tid >> 6] = s;
  __syncthreads();
  float inv = 1.0f / fmaxf(sb[0] + sb[1] + sb[2] + sb[3], 1e-12f);
  for (int i = tid; i < T_DIM; i += 256) ent[i] *= inv;
}

__global__ __launch_bounds__(256) void k_repack(const float* __restrict__ Wout, ushort* __restrict__ Wob) {
  int o = blockIdx.x;
  for (int k = threadIdx.x; k < 1024; k += 256)
    Wob[(size_t)o * 1024 + k] = f2bf(Wout[(size_t)o * 1026 + k]);
}

// diagonal att write + y = att_win @ V, y stored bf16
__global__ __launch_bounds__(256) void k_atty(const float* __restrict__ eb, const float* __restrict__ mrow,
    const float* __restrict__ zrow, const float* __restrict__ dep, const ushort* __restrict__ Vb,
    float* __restrict__ att, ushort* __restrict__ Ybf) {
  int b = blockIdx.x;
  int j0 = b * BS;
  int w = (BS < T_DIM - j0) ? BS : (T_DIM - j0);
  __shared__ float wl[BS][BS + 1];
  int tid = threadIdx.x;
  for (int idx = tid; idx < BS * (BS + 1); idx += 256) (&wl[0][0])[idx] = 0.0f;
  __syncthreads();
  for (int idx = tid; idx < w * w; idx += 256) {
    int rr = idx / w, c = idx - rr * w;
    int gi = j0 + rr;
    float val = __expf(eb[(size_t)gi * 64 + c] - mrow[gi]) / zrow[gi] + dep[j0 + c];
    wl[rr][c] = val;
    if (blockIdx.y == 0) att[(size_t)gi * T_DIM + j0 + c] = val;
  }
  __syncthreads();
  int c = blockIdx.y * 256 + tid;
  float acc[BS];
#pragma unroll
  for (int rr = 0; rr < BS; ++rr) acc[rr] = 0.f;
  for (int j = 0; j < w; ++j) {
    float v = bf2f(Vb[(size_t)(j0 + j) * D_DIM + c]);
#pragma unroll
    for (int rr = 0; rr < BS; ++rr) acc[rr] = fmaf(wl[rr][j], v, acc[rr]);
  }
#pragma unroll
  for (int rr = 0; rr < BS; ++rr)
    if (rr < w) Ybf[(size_t)(j0 + rr) * D_DIM + c] = f2bf(acc[rr]);
}

// ---------------------------------------------------------------------------
// Final projection: yout = Ybf @ Wob^T (1-term bf16) + ent/dep epilogue.
__global__ __launch_bounds__(256,4) void k_final(
    const ushort* __restrict__ Ybf, const ushort* __restrict__ Wob,
    const float* __restrict__ Wout, const float* __restrict__ ent,
    const float* __restrict__ dep, float* __restrict__ yout) {
  __shared__ ushort ldsB[4096];  // 64 rows x 64k
  const int tid = threadIdx.x;
  const int w = tid >> 6, lane = tid & 63;
  const int wr = w >> 1, wc = w & 1;
  const int g = lane >> 4, cl = lane & 15;
  const int i0 = blockIdx.y * 64, j0 = blockIdx.x * 64;
  f32x4 acc[2][2];
#pragma unroll
  for (int a = 0; a < 2; ++a)
#pragma unroll
    for (int b = 0; b < 2; ++b) acc[a][b] = (f32x4){0.f,0.f,0.f,0.f};
  const int ar0 = i0 + wr*32 + cl;

  for (int ks = 0; ks < 16; ++ks) {
    const int k0 = ks * 64;
    short8 aY[2][2];
#pragma unroll
    for (int is = 0; is < 2; ++is) {
      const size_t rb = (size_t)(ar0 + is*16) * D_DIM + k0;
#pragma unroll
      for (int h = 0; h < 2; ++h)
        aY[is][h] = *reinterpret_cast<const short8*>(Ybf + rb + (h*4+g)*8);
    }
    __syncthreads();
#pragma unroll
    for (int p = 0; p < 2; ++p) {
      const int s = tid + p*256;
      const int r = s >> 3, c = s & 7;
      const int loff = r*64 + (c ^ (r & 7))*8;
      *reinterpret_cast<short8*>(&ldsB[loff]) =
          *reinterpret_cast<const short8*>(Wob + (size_t)(j0 + r) * D_DIM + k0 + c*8);
    }
    __syncthreads();
#pragma unroll
    for (int h = 0; h < 2; ++h)
#pragma unroll
      for (int js = 0; js < 2; ++js) {
        const int br = wc*32 + js*16 + cl;
        short8 bW = *reinterpret_cast<const short8*>(&ldsB[br*64 + ((h*4+g) ^ (br & 7))*8]);
#pragma unroll
        for (int is = 0; is < 2; ++is)
          acc[is][js] = MFMA(aY[is][h], bW, acc[is][js]);
      }
  }
  float w1[2], w2[2];
#pragma unroll
  for (int js = 0; js < 2; ++js) {
    int gj = j0 + wc*32 + js*16 + cl;
    w1[js] = Wout[(size_t)gj * 1026 + 1024];
    w2[js] = Wout[(size_t)gj * 1026 + 1025];
  }
#pragma unroll
  for (int is = 0; is < 2; ++is)
#pragma unroll
    for (int a = 0; a < 4; ++a) {
      int gi = i0 + wr*32 + is*16 + g*4 + a;
      float e = ent[gi], d = dep[gi];
#pragma unroll
      for (int js = 0; js < 2; ++js) {
        int gj = j0 + wc*32 + js*16 + cl;
        yout[(size_t)gi * D_DIM + gj] = acc[is][js][a] + e * w1[js] + d * w2[js];
      }
    }
}

// ---------------------------------------------------------------------------
extern "C" void kernel_launch(void* const* d_in, const int* in_sizes, int n_in,
                              void* d_out, int out_size, void* d_ws, size_t ws_size,
                              hipStream_t stream) {
  const float* x    = (const float*)d_in[0];
  const float* Wk   = (const float*)d_in[1];
  const float* Wq   = (const float*)d_in[2];
  const float* Wv   = (const float*)d_in[3];
  const float* Wout = (const float*)d_in[4];
  float* out = (float*)d_out;
  char* wsb  = (char*)d_ws;

  ushort* Uh   = (ushort*)(wsb + 0);            // 8 MB
  ushort* Vb   = (ushort*)(wsb + 8388608);      // 8 MB
  ushort* Ybf  = (ushort*)(wsb + 16777216);     // 8 MB
  ushort* Wob  = (ushort*)(wsb + 25165824);     // 2 MB
  ushort* Wqh  = (ushort*)(wsb + 27262976);     // 6 x 2 MB
  ushort* Wql  = Wqh + 1048576;
  ushort* Wkh  = Wql + 1048576;
  ushort* Wkl  = Wkh + 1048576;
  ushort* Wvh  = Wkl + 1048576;
  ushort* Wvl  = Wvh + 1048576;
  float*  eb   = (float*)(wsb + 39845888);      // 1 MB
  float*  db   = (float*)(wsb + 40894464);      // 1 MB
  float*  pm   = (float*)(wsb + 41943040);      // 1 MB each (64 partials)
  float*  pZ   = (float*)(wsb + 42991616);
  float*  pWe  = (float*)(wsb + 44040192);
  float*  pWd  = (float*)(wsb + 45088768);
  float*  mrow = (float*)(wsb + 46137344);
  float*  zrow = (float*)(wsb + 46153728);
  float*  ent  = (float*)(wsb + 46170112);
  float*  dep  = (float*)(wsb + 46186496);
  float*  Sb   = (float*)(wsb + 46202880);
  float*  Sg   = (float*)(wsb + 46485504);

  float* yout = out;                               // [4096][1024]
  float* att  = out + (size_t)T_DIM * D_DIM;       // [4096][4096]
  ushort* xhi = (ushort*)att;                      // scratch in att region
  ushort* xlo = xhi + 4194304;
  ushort* Qhi = xlo + 4194304;
  ushort* Qlo = Qhi + 4194304;
  ushort* Khi = Qlo + 4194304;
  ushort* Klo = Khi + 4194304;

  k_split<<<4096, 256, 0, stream>>>(x, xhi, xlo);
  k_split<<<1024, 256, 0, stream>>>(Wq, Wqh, Wql);
  k_split<<<1024, 256, 0, stream>>>(Wk, Wkh, Wkl);
  k_split<<<1024, 256, 0, stream>>>(Wv, Wvh, Wvl);
  k_rownorm<<<T_DIM, 256, 0, stream>>>(x, Uh);
  k_bsum<<<NBLK, 256, 0, stream>>>(Uh, Sb);
  k_gsum<<<4, 256, 0, stream>>>(Sb, Sg);

  k_qk<<<dim3(16, 32), 256, 0, stream>>>(xhi, xlo, Wqh, Wql, Wkh, Wkl, Qhi, Qlo, Khi, Klo);
  k_v<<<dim3(16, 64), 256, 0, stream>>>(xhi, Wvh, Vb);

  k_stream<<<1024, 256, 0, stream>>>(Qhi, Qlo, Khi, Klo, Uh, eb, db, pm, pZ, pWe, pWd);
  k_merge<<<T_DIM, 256, 0, stream>>>(pm, pZ, pWe, pWd, Uh, Sg, Sb, eb, db, dep, ent, mrow, zrow);
  k_entnorm<<<1, 256, 0, stream>>>(ent);

  hipMemsetAsync(att, 0, (size_t)T_DIM * T_DIM * sizeof(float), stream);
  k_repack<<<1024, 256, 0, stream>>>(Wout, Wob);
  k_atty<<<dim3(NBLK, 4), 256, 0, stream>>>(eb, mrow, zrow, dep, Vb, att, Ybf);
  k_final<<<dim3(16, 64), 256, 0, stream>>>(Ybf, Wob, Wout, ent, dep, yout);
}

// Round 7
// 583.015 us; speedup vs baseline: 3.5761x; 1.0088x over previous
//
#include <hip/hip_runtime.h>
#include <math.h>

#define T_DIM 4096
#define D_DIM 1024
#define BS 60
#define NBLK 69
#define NPART 64

typedef __attribute__((ext_vector_type(4))) float f32x4;
typedef __attribute__((ext_vector_type(8))) short short8;
#define MFMA(a,b,c) __builtin_amdgcn_mfma_f32_16x16x32_bf16((a),(b),(c),0,0,0)

static __device__ __forceinline__ ushort f2bf(float f) {
  unsigned x = __float_as_uint(f);
  unsigned r = x + 0x7fffu + ((x >> 16) & 1u);
  return (ushort)(r >> 16);
}
static __device__ __forceinline__ float bf2f(ushort u) {
  return __uint_as_float((unsigned)u << 16);
}

// ---------------------------------------------------------------------------
__global__ __launch_bounds__(256) void k_split(const float* __restrict__ A,
    ushort* __restrict__ hi, ushort* __restrict__ lo) {
  size_t i = ((size_t)blockIdx.x * 256 + threadIdx.x) * 4;
  float4 v = *reinterpret_cast<const float4*>(A + i);
  ushort4 h, l;
  h.x = f2bf(v.x); l.x = f2bf(v.x - bf2f(h.x));
  h.y = f2bf(v.y); l.y = f2bf(v.y - bf2f(h.y));
  h.z = f2bf(v.z); l.z = f2bf(v.z - bf2f(h.z));
  h.w = f2bf(v.w); l.w = f2bf(v.w - bf2f(h.w));
  *reinterpret_cast<ushort4*>(hi + i) = h;
  *reinterpret_cast<ushort4*>(lo + i) = l;
}

__global__ __launch_bounds__(256) void k_rownorm(const float* __restrict__ x, ushort* __restrict__ u) {
  int i = blockIdx.x, tid = threadIdx.x;
  float4 v = *reinterpret_cast<const float4*>(x + (size_t)i * D_DIM + tid * 4);
  float ss = v.x*v.x + v.y*v.y + v.z*v.z + v.w*v.w;
#pragma unroll
  for (int m = 1; m < 64; m <<= 1) ss += __shfl_xor(ss, m);
  __shared__ float sb[4];
  if ((tid & 63) == 0) sb[tid >> 6] = ss;
  __syncthreads();
  float inv = 1.0f / fmaxf(sqrtf(sb[0] + sb[1] + sb[2] + sb[3]), 1e-12f);
  ushort4 o;
  o.x = f2bf(v.x*inv); o.y = f2bf(v.y*inv); o.z = f2bf(v.z*inv); o.w = f2bf(v.w*inv);
  *reinterpret_cast<ushort4*>(u + (size_t)i * D_DIM + tid * 4) = o;
}

__global__ __launch_bounds__(256) void k_bsum(const ushort* __restrict__ u, float* __restrict__ Sb) {
  int b = blockIdx.x, tid = threadIdx.x;
  int j0 = b * BS;
  int w = (BS < T_DIM - j0) ? BS : (T_DIM - j0);
  int c = tid * 4;
  float4 acc = {0,0,0,0};
  for (int j = 0; j < w; ++j) {
    ushort4 v = *reinterpret_cast<const ushort4*>(u + (size_t)(j0 + j) * D_DIM + c);
    acc.x += bf2f(v.x); acc.y += bf2f(v.y); acc.z += bf2f(v.z); acc.w += bf2f(v.w);
  }
  *reinterpret_cast<float4*>(Sb + (size_t)b * D_DIM + c) = acc;
}

__global__ __launch_bounds__(256) void k_gsum(const float* __restrict__ Sb, float* __restrict__ S) {
  int c = blockIdx.x * 256 + threadIdx.x;
  float s = 0.f;
  for (int b = 0; b < NBLK; ++b) s += Sb[(size_t)b * D_DIM + c];
  S[c] = s;
}

// ---------------------------------------------------------------------------
// Fused Q+K MFMA GEMM (3-term split each).  Double-buffered LDS, ONE barrier
// per K-step: write buf[ks&1] -> barrier -> read frags -> prefetch -> MFMA.
__global__ __launch_bounds__(256,2) void k_qk(
    const ushort* __restrict__ xhi, const ushort* __restrict__ xlo,
    const ushort* __restrict__ Wqh, const ushort* __restrict__ Wql,
    const ushort* __restrict__ Wkh, const ushort* __restrict__ Wkl,
    ushort* __restrict__ Qhi, ushort* __restrict__ Qlo,
    ushort* __restrict__ Khi, ushort* __restrict__ Klo) {
  __shared__ __align__(16) ushort lds[32768]; // 2 x 16384: xh@0 xl@4096 | Wqh@8192 Wql@10240 Wkh@12288 Wkl@14336
  const int tid = threadIdx.x;
  const int w = tid >> 6, lane = tid & 63;
  const int wr = w >> 1, wc = w & 1;
  const int g = lane >> 4, cl = lane & 15;
  const int i0 = blockIdx.y * 128, j0 = blockIdx.x * 64;

  int adA[4], adB[2];
#pragma unroll
  for (int is = 0; is < 4; ++is) {
    int r = wr*64 + is*16 + cl;
    adA[is] = r*32 + (g ^ ((r >> 1) & 3))*8;
  }
#pragma unroll
  for (int js = 0; js < 2; ++js) {
    int r = wc*32 + js*16 + cl;
    adB[js] = r*32 + (g ^ ((r >> 1) & 3))*8;
  }

  const int ra1 = tid >> 2, ra2 = 64 + (tid >> 2), rbr = tid >> 2;
  const int sa = tid & 3;
  const int wA1 = ra1*32 + (sa ^ ((ra1 >> 1) & 3))*8;
  const int wA2 = ra2*32 + (sa ^ ((ra2 >> 1) & 3))*8;
  const int wB  = rbr*32 + (sa ^ ((rbr >> 1) & 3))*8;
  const size_t gA1 = (size_t)(i0 + ra1) * D_DIM + sa*8;
  const size_t gA2 = (size_t)(i0 + ra2) * D_DIM + sa*8;
  const size_t gB  = (size_t)(j0 + rbr) * D_DIM + sa*8;

  f32x4 accQ[4][2], accK[4][2];
#pragma unroll
  for (int is = 0; is < 4; ++is)
#pragma unroll
    for (int js = 0; js < 2; ++js) {
      accQ[is][js] = (f32x4){0.f,0.f,0.f,0.f};
      accK[is][js] = (f32x4){0.f,0.f,0.f,0.f};
    }

  short8 sXh1 = *reinterpret_cast<const short8*>(xhi + gA1);
  short8 sXh2 = *reinterpret_cast<const short8*>(xhi + gA2);
  short8 sXl1 = *reinterpret_cast<const short8*>(xlo + gA1);
  short8 sXl2 = *reinterpret_cast<const short8*>(xlo + gA2);
  short8 sQh  = *reinterpret_cast<const short8*>(Wqh + gB);
  short8 sQl  = *reinterpret_cast<const short8*>(Wql + gB);
  short8 sKh  = *reinterpret_cast<const short8*>(Wkh + gB);
  short8 sKl  = *reinterpret_cast<const short8*>(Wkl + gB);

  for (int ks = 0; ks < 32; ++ks) {
    const int bofs = (ks & 1) * 16384;
    *reinterpret_cast<short8*>(&lds[bofs + wA1])          = sXh1;
    *reinterpret_cast<short8*>(&lds[bofs + wA2])          = sXh2;
    *reinterpret_cast<short8*>(&lds[bofs + 4096 + wA1])   = sXl1;
    *reinterpret_cast<short8*>(&lds[bofs + 4096 + wA2])   = sXl2;
    *reinterpret_cast<short8*>(&lds[bofs + 8192 + wB])    = sQh;
    *reinterpret_cast<short8*>(&lds[bofs + 10240 + wB])   = sQl;
    *reinterpret_cast<short8*>(&lds[bofs + 12288 + wB])   = sKh;
    *reinterpret_cast<short8*>(&lds[bofs + 14336 + wB])   = sKl;
    __syncthreads();
    short8 aH[4], aL[4], bQh[2], bQl[2], bKh[2], bKl[2];
#pragma unroll
    for (int is = 0; is < 4; ++is) {
      aH[is] = *reinterpret_cast<const short8*>(&lds[bofs + adA[is]]);
      aL[is] = *reinterpret_cast<const short8*>(&lds[bofs + 4096 + adA[is]]);
    }
#pragma unroll
    for (int js = 0; js < 2; ++js) {
      bQh[js] = *reinterpret_cast<const short8*>(&lds[bofs + 8192  + adB[js]]);
      bQl[js] = *reinterpret_cast<const short8*>(&lds[bofs + 10240 + adB[js]]);
      bKh[js] = *reinterpret_cast<const short8*>(&lds[bofs + 12288 + adB[js]]);
      bKl[js] = *reinterpret_cast<const short8*>(&lds[bofs + 14336 + adB[js]]);
    }
    if (ks < 31) {
      const int k0 = (ks + 1) * 32;
      sXh1 = *reinterpret_cast<const short8*>(xhi + gA1 + k0);
      sXh2 = *reinterpret_cast<const short8*>(xhi + gA2 + k0);
      sXl1 = *reinterpret_cast<const short8*>(xlo + gA1 + k0);
      sXl2 = *reinterpret_cast<const short8*>(xlo + gA2 + k0);
      sQh  = *reinterpret_cast<const short8*>(Wqh + gB + k0);
      sQl  = *reinterpret_cast<const short8*>(Wql + gB + k0);
      sKh  = *reinterpret_cast<const short8*>(Wkh + gB + k0);
      sKl  = *reinterpret_cast<const short8*>(Wkl + gB + k0);
    }
#pragma unroll
    for (int js = 0; js < 2; ++js)
#pragma unroll
      for (int is = 0; is < 4; ++is) {
        accQ[is][js] = MFMA(aH[is], bQh[js], accQ[is][js]);
        accQ[is][js] = MFMA(aL[is], bQh[js], accQ[is][js]);
        accQ[is][js] = MFMA(aH[is], bQl[js], accQ[is][js]);
        accK[is][js] = MFMA(aH[is], bKh[js], accK[is][js]);
        accK[is][js] = MFMA(aL[is], bKh[js], accK[is][js]);
        accK[is][js] = MFMA(aH[is], bKl[js], accK[is][js]);
      }
  }
#pragma unroll
  for (int is = 0; is < 4; ++is)
#pragma unroll
    for (int js = 0; js < 2; ++js)
#pragma unroll
      for (int a = 0; a < 4; ++a) {
        int gi = i0 + wr*64 + is*16 + g*4 + a;
        int gj = j0 + wc*32 + js*16 + cl;
        float vq = accQ[is][js][a];
        ushort hq = f2bf(vq);
        Qhi[(size_t)gi*D_DIM + gj] = hq;
        Qlo[(size_t)gi*D_DIM + gj] = f2bf(vq - bf2f(hq));
        float vk = accK[is][js][a];
        ushort hk = f2bf(vk);
        Khi[(size_t)gi*D_DIM + gj] = hk;
        Klo[(size_t)gi*D_DIM + gj] = f2bf(vk - bf2f(hk));
      }
}

// ---------------------------------------------------------------------------
// V = x@Wv^T, 1-term bf16.  A-frags + B-stage prefetched, dbuf B, 1 barrier.
__global__ __launch_bounds__(256,4) void k_v(
    const ushort* __restrict__ Ahi, const ushort* __restrict__ Bhi,
    ushort* __restrict__ C) {
  __shared__ ushort ldsB[8192];  // 2 x 4096
  const int tid = threadIdx.x;
  const int w = tid >> 6, lane = tid & 63;
  const int wr = w >> 1, wc = w & 1;
  const int g = lane >> 4, cl = lane & 15;
  const int i0 = blockIdx.y * 64, j0 = blockIdx.x * 64;
  f32x4 acc[2][2];
#pragma unroll
  for (int a = 0; a < 2; ++a)
#pragma unroll
    for (int b = 0; b < 2; ++b) acc[a][b] = (f32x4){0.f,0.f,0.f,0.f};
  const int ar0 = i0 + wr*32 + cl;

  const int r1 = tid >> 3, c1 = tid & 7;
  const int r2 = (tid + 256) >> 3, c2 = (tid + 256) & 7;
  const int lo1 = r1*64 + (c1 ^ (r1 & 7))*8;
  const int lo2 = r2*64 + (c2 ^ (r2 & 7))*8;
  const size_t gB1 = (size_t)(j0 + r1) * D_DIM + c1*8;
  const size_t gB2 = (size_t)(j0 + r2) * D_DIM + c2*8;

  short8 sB1 = *reinterpret_cast<const short8*>(Bhi + gB1);
  short8 sB2 = *reinterpret_cast<const short8*>(Bhi + gB2);
  short8 aH[2][2];
#pragma unroll
  for (int is = 0; is < 2; ++is)
#pragma unroll
    for (int h = 0; h < 2; ++h)
      aH[is][h] = *reinterpret_cast<const short8*>(Ahi + (size_t)(ar0 + is*16) * D_DIM + (h*4+g)*8);

  for (int ks = 0; ks < 16; ++ks) {
    const int bofs = (ks & 1) * 4096;
    *reinterpret_cast<short8*>(&ldsB[bofs + lo1]) = sB1;
    *reinterpret_cast<short8*>(&ldsB[bofs + lo2]) = sB2;
    __syncthreads();
    short8 aC[2][2];
#pragma unroll
    for (int is = 0; is < 2; ++is)
#pragma unroll
      for (int h = 0; h < 2; ++h) aC[is][h] = aH[is][h];
    if (ks < 15) {
      const int k0 = (ks + 1) * 64;
      sB1 = *reinterpret_cast<const short8*>(Bhi + gB1 + k0);
      sB2 = *reinterpret_cast<const short8*>(Bhi + gB2 + k0);
#pragma unroll
      for (int is = 0; is < 2; ++is)
#pragma unroll
        for (int h = 0; h < 2; ++h)
          aH[is][h] = *reinterpret_cast<const short8*>(Ahi + (size_t)(ar0 + is*16) * D_DIM + k0 + (h*4+g)*8);
    }
#pragma unroll
    for (int h = 0; h < 2; ++h)
#pragma unroll
      for (int js = 0; js < 2; ++js) {
        const int br = wc*32 + js*16 + cl;
        short8 bH = *reinterpret_cast<const short8*>(&ldsB[bofs + br*64 + ((h*4+g) ^ (br & 7))*8]);
#pragma unroll
        for (int is = 0; is < 2; ++is)
          acc[is][js] = MFMA(aC[is][h], bH, acc[is][js]);
      }
  }
#pragma unroll
  for (int is = 0; is < 2; ++is)
#pragma unroll
    for (int js = 0; js < 2; ++js)
#pragma unroll
      for (int a = 0; a < 4; ++a) {
        int gi = i0 + wr*32 + is*16 + g*4 + a;
        int gj = j0 + wc*32 + js*16 + cl;
        C[(size_t)gi*D_DIM + gj] = f2bf(acc[is][js][a]);
      }
}

// ---------------------------------------------------------------------------
// Fused stream: E = Q@K^T (3-term) and Dv = U@U^T (1-term).
// Double-buffered LDS, ONE barrier per K-step.  launch_bounds (256,2):
// (256,4) forced 64 VGPR + scratch spills (R5) -- do not re-tighten.
__global__ __launch_bounds__(256,2) void k_stream(
    const ushort* __restrict__ Qhi, const ushort* __restrict__ Qlo,
    const ushort* __restrict__ Khi, const ushort* __restrict__ Klo,
    const ushort* __restrict__ Uh,
    float* __restrict__ eb, float* __restrict__ db,
    float* __restrict__ pm, float* __restrict__ pZ,
    float* __restrict__ pWe, float* __restrict__ pWd) {
  __shared__ __align__(16) ushort lds[36864]; // 2 x 18432: Qhi@0 Qlo@4096 Ui@8192 | Khi@12288 Klo@14336 Uj@16384
  __shared__ float stat_s[2][2][64][4];
  const int tid = threadIdx.x;
  const int bid = blockIdx.x;
  const int wg = (bid & 7) * 128 + (bid >> 3);   // XCD-bijective (1024 % 8 == 0)
  const int it = wg >> 5, chunk = wg & 31;
  const int i0 = it * 128;
  const int w = tid >> 6, lane = tid & 63;
  const int wr = w >> 1, wc = w & 1;
  const int g = lane >> 4, cl = lane & 15;

  int adA[4], adB[2];
#pragma unroll
  for (int is = 0; is < 4; ++is) {
    int r = wr*64 + is*16 + cl;
    adA[is] = r*32 + (g ^ ((r >> 1) & 3))*8;
  }
#pragma unroll
  for (int js = 0; js < 2; ++js) {
    int r = wc*32 + js*16 + cl;
    adB[js] = r*32 + (g ^ ((r >> 1) & 3))*8;
  }

  const int ra1 = tid >> 2, ra2 = 64 + (tid >> 2), rbr = tid >> 2;
  const int sa = tid & 3;
  const int wA1 = ra1*32 + (sa ^ ((ra1 >> 1) & 3))*8;
  const int wA2 = ra2*32 + (sa ^ ((ra2 >> 1) & 3))*8;
  const int wB  = rbr*32 + (sa ^ ((rbr >> 1) & 3))*8;
  const size_t gA1 = (size_t)(i0 + ra1) * D_DIM + sa*8;
  const size_t gA2 = (size_t)(i0 + ra2) * D_DIM + sa*8;

  const int iw0 = i0 + wr*64;
  const int blkLo = iw0 / BS, blkHi = (iw0 + 63) / BS;

  for (int jt = 0; jt < 2; ++jt) {
    const int jb = chunk*128 + jt*64;
    const size_t gB = (size_t)(jb + rbr) * D_DIM + sa*8;

    f32x4 accE[4][2], accD[4][2];
#pragma unroll
    for (int is = 0; is < 4; ++is)
#pragma unroll
      for (int js = 0; js < 2; ++js) {
        accE[is][js] = (f32x4){0.f,0.f,0.f,0.f};
        accD[is][js] = (f32x4){0.f,0.f,0.f,0.f};
      }

    short8 sQh1 = *reinterpret_cast<const short8*>(Qhi + gA1);
    short8 sQh2 = *reinterpret_cast<const short8*>(Qhi + gA2);
    short8 sQl1 = *reinterpret_cast<const short8*>(Qlo + gA1);
    short8 sQl2 = *reinterpret_cast<const short8*>(Qlo + gA2);
    short8 sUi1 = *reinterpret_cast<const short8*>(Uh  + gA1);
    short8 sUi2 = *reinterpret_cast<const short8*>(Uh  + gA2);
    short8 sKh  = *reinterpret_cast<const short8*>(Khi + gB);
    short8 sKl  = *reinterpret_cast<const short8*>(Klo + gB);
    short8 sUj  = *reinterpret_cast<const short8*>(Uh  + gB);

    for (int ks = 0; ks < 32; ++ks) {
      const int bofs = (ks & 1) * 18432;
      *reinterpret_cast<short8*>(&lds[bofs + wA1])         = sQh1;
      *reinterpret_cast<short8*>(&lds[bofs + wA2])         = sQh2;
      *reinterpret_cast<short8*>(&lds[bofs + 4096 + wA1])  = sQl1;
      *reinterpret_cast<short8*>(&lds[bofs + 4096 + wA2])  = sQl2;
      *reinterpret_cast<short8*>(&lds[bofs + 8192 + wA1])  = sUi1;
      *reinterpret_cast<short8*>(&lds[bofs + 8192 + wA2])  = sUi2;
      *reinterpret_cast<short8*>(&lds[bofs + 12288 + wB])  = sKh;
      *reinterpret_cast<short8*>(&lds[bofs + 14336 + wB])  = sKl;
      *reinterpret_cast<short8*>(&lds[bofs + 16384 + wB])  = sUj;
      __syncthreads();
      short8 aQh[4], aQl[4], aU[4], bKh[2], bKl[2], bU[2];
#pragma unroll
      for (int is = 0; is < 4; ++is) {
        aQh[is] = *reinterpret_cast<const short8*>(&lds[bofs + adA[is]]);
        aQl[is] = *reinterpret_cast<const short8*>(&lds[bofs + 4096 + adA[is]]);
        aU [is] = *reinterpret_cast<const short8*>(&lds[bofs + 8192 + adA[is]]);
      }
#pragma unroll
      for (int js = 0; js < 2; ++js) {
        bKh[js] = *reinterpret_cast<const short8*>(&lds[bofs + 12288 + adB[js]]);
        bKl[js] = *reinterpret_cast<const short8*>(&lds[bofs + 14336 + adB[js]]);
        bU [js] = *reinterpret_cast<const short8*>(&lds[bofs + 16384 + adB[js]]);
      }
      if (ks < 31) {   // issue next-K loads under the MFMA block
        const int k0 = (ks + 1) * 32;
        sQh1 = *reinterpret_cast<const short8*>(Qhi + gA1 + k0);
        sQh2 = *reinterpret_cast<const short8*>(Qhi + gA2 + k0);
        sQl1 = *reinterpret_cast<const short8*>(Qlo + gA1 + k0);
        sQl2 = *reinterpret_cast<const short8*>(Qlo + gA2 + k0);
        sUi1 = *reinterpret_cast<const short8*>(Uh  + gA1 + k0);
        sUi2 = *reinterpret_cast<const short8*>(Uh  + gA2 + k0);
        sKh  = *reinterpret_cast<const short8*>(Khi + gB + k0);
        sKl  = *reinterpret_cast<const short8*>(Klo + gB + k0);
        sUj  = *reinterpret_cast<const short8*>(Uh  + gB + k0);
      }
#pragma unroll
      for (int js = 0; js < 2; ++js)
#pragma unroll
        for (int is = 0; is < 4; ++is) {
          accE[is][js] = MFMA(aQh[is], bKh[js], accE[is][js]);
          accE[is][js] = MFMA(aQl[is], bKh[js], accE[is][js]);
          accE[is][js] = MFMA(aQh[is], bKl[js], accE[is][js]);
          accD[is][js] = MFMA(aU[is],  bU[js],  accD[is][js]);
        }
    }

    // diagonal-block stash
    const int jw0 = jb + wc*32;
    if (jw0 < (blkHi+1)*BS && jw0 + 32 > blkLo*BS) {
#pragma unroll
      for (int is = 0; is < 4; ++is)
#pragma unroll
        for (int js = 0; js < 2; ++js)
#pragma unroll
          for (int a = 0; a < 4; ++a) {
            int gi = i0 + wr*64 + is*16 + g*4 + a;
            int gj = jw0 + js*16 + cl;
            int bi = gi / BS;
            if (gj / BS == bi) {
              int c = gj - bi * BS;
              eb[(size_t)gi*64 + c] = accE[is][js][a];
              db[(size_t)gi*64 + c] = accD[is][js][a];
            }
          }
    }

    // per-jt partial softmax stats over this 64-col tile
#pragma unroll
    for (int is = 0; is < 4; ++is)
#pragma unroll
      for (int a = 0; a < 4; ++a) {
        float e0 = accE[is][0][a], e1 = accE[is][1][a];
        float d0 = accD[is][0][a], d1 = accD[is][1][a];
        float tmax = fmaxf(e0, e1);
#pragma unroll
        for (int mk = 1; mk < 16; mk <<= 1) tmax = fmaxf(tmax, __shfl_xor(tmax, mk));
        float p0 = __expf(e0 - tmax), p1 = __expf(e1 - tmax);
        float z  = p0 + p1;
        float we = p0*e0 + p1*e1;
        float wd = p0*d0 + p1*d1;
#pragma unroll
        for (int mk = 1; mk < 16; mk <<= 1) {
          z += __shfl_xor(z, mk); we += __shfl_xor(we, mk); wd += __shfl_xor(wd, mk);
        }
        if (cl == 0) {
          int rl = is*16 + g*4 + a;
          stat_s[wr][wc][rl][0] = tmax;
          stat_s[wr][wc][rl][1] = z;
          stat_s[wr][wc][rl][2] = we;
          stat_s[wr][wc][rl][3] = wd;
        }
      }
    __syncthreads();
    if (tid < 128) {
      int rl = tid & 63, wr2 = tid >> 6;
      float m0 = stat_s[wr2][0][rl][0], Z0 = stat_s[wr2][0][rl][1];
      float We0 = stat_s[wr2][0][rl][2], Wd0 = stat_s[wr2][0][rl][3];
      float m1 = stat_s[wr2][1][rl][0], Z1 = stat_s[wr2][1][rl][1];
      float We1 = stat_s[wr2][1][rl][2], Wd1 = stat_s[wr2][1][rl][3];
      float nm = fmaxf(m0, m1);
      float s0 = __expf(m0 - nm), s1 = __expf(m1 - nm);
      size_t idx = (size_t)(chunk*2 + jt) * T_DIM + i0 + wr2*64 + rl;
      pm[idx]  = nm;
      pZ[idx]  = Z0*s0 + Z1*s1;
      pWe[idx] = We0*s0 + We1*s1;
      pWd[idx] = Wd0*s0 + Wd1*s1;
    }
    __syncthreads();   // protect stat_s + LDS buf reuse across jt
  }
}

// ---------------------------------------------------------------------------
__global__ __launch_bounds__(256) void k_merge(const float* __restrict__ pm, const float* __restrict__ pZ,
    const float* __restrict__ pWe, const float* __restrict__ pWd,
    const ushort* __restrict__ Uh, const float* __restrict__ Sg, const float* __restrict__ Sb,
    const float* __restrict__ eb, const float* __restrict__ db,
    float* __restrict__ dep, float* __restrict__ ent, float* __restrict__ mrow, float* __restrict__ zrow) {
  int i = blockIdx.x, tid = threadIdx.x;
  float m = pm[i], Z = pZ[i], We = pWe[i], Wd = pWd[i];
  for (int c = 1; c < NPART; ++c) {
    float om = pm[(size_t)c*T_DIM + i], oZ = pZ[(size_t)c*T_DIM + i];
    float oWe = pWe[(size_t)c*T_DIM + i], oWd = pWd[(size_t)c*T_DIM + i];
    float nm = fmaxf(m, om);
    float s1 = __expf(m - nm), s2 = __expf(om - nm);
    Z = Z*s1 + oZ*s2; We = We*s1 + oWe*s2; Wd = Wd*s1 + oWd*s2; m = nm;
  }
  int b = i / BS, j0 = b * BS;
  int w = (BS < T_DIM - j0) ? BS : (T_DIM - j0);
  ushort4 uv = *reinterpret_cast<const ushort4*>(Uh + (size_t)i*D_DIM + tid*4);
  float4 Sv  = *reinterpret_cast<const float4*>(Sg + tid*4);
  float4 Sbv = *reinterpret_cast<const float4*>(Sb + (size_t)b*D_DIM + tid*4);
  float ux = bf2f(uv.x), uy = bf2f(uv.y), uz = bf2f(uv.z), uw = bf2f(uv.w);
  float dS  = ux*Sv.x  + uy*Sv.y  + uz*Sv.z  + uw*Sv.w;
  float dSb = ux*Sbv.x + uy*Sbv.y + uz*Sbv.z + uw*Sbv.w;
  float pb = 0.f, pdb = 0.f;
  if (tid < w) {
    float e = eb[(size_t)i*64 + tid], d = db[(size_t)i*64 + tid];
    float p = __expf(e - m);
    pb = p; pdb = p * d;
  }
  float v0 = dS, v1 = dSb, v2 = pb, v3 = pdb;
#pragma unroll
  for (int mk = 1; mk < 64; mk <<= 1) {
    v0 += __shfl_xor(v0, mk); v1 += __shfl_xor(v1, mk);
    v2 += __shfl_xor(v2, mk); v3 += __shfl_xor(v3, mk);
  }
  __shared__ float red[4][4];
  if ((tid & 63) == 0) { int wv = tid >> 6; red[0][wv]=v0; red[1][wv]=v1; red[2][wv]=v2; red[3][wv]=v3; }
  __syncthreads();
  if (tid == 0) {
    float tdS  = red[0][0]+red[0][1]+red[0][2]+red[0][3];
    float tdSb = red[1][0]+red[1][1]+red[1][2]+red[1][3];
    float s1   = red[2][0]+red[2][1]+red[2][2]+red[2][3];
    float s2   = red[3][0]+red[3][1]+red[3][2]+red[3][3];
    float invZ = 1.0f / Z;
    float num = (1.0f - s1*invZ) - (Wd - s2)*invZ;
    float den = (float)(T_DIM - w) - (tdS - tdSb);
    dep[i] = num / den;
    ent[i] = -(We*invZ - m - logf(Z)) / logf((float)T_DIM);
    mrow[i] = m; zrow[i] = Z;
  }
}

__global__ __launch_bounds__(256) void k_entnorm(float* __restrict__ ent) {
  int tid = threadIdx.x;
  float s = 0.f;
  for (int i = tid; i < T_DIM; i += 256) s += fabsf(ent[i]);
#pragma unroll
  for (int mk = 1; mk < 64; mk <<= 1) s += __shfl_xor(s, mk);
  __shared__ float sb[4];
  if ((tid & 63) == 0) sb[tid >> 6] = s;
  __syncthreads();
  float inv = 1.0f / fmaxf(sb[0] + sb[1] + sb[2] + sb[3], 1e-12f);
  for (int i = tid; i < T_DIM; i += 256) ent[i] *= inv;
}

__global__ __launch_bounds__(256) void k_repack(const float* __restrict__ Wout, ushort* __restrict__ Wob) {
  int o = blockIdx.x;
  for (int k = threadIdx.x; k < 1024; k += 256)
    Wob[(size_t)o * 1024 + k] = f2bf(Wout[(size_t)o * 1026 + k]);
}

// diagonal att write + y = att_win @ V, y stored bf16
__global__ __launch_bounds__(256) void k_atty(const float* __restrict__ eb, const float* __restrict__ mrow,
    const float* __restrict__ zrow, const float* __restrict__ dep, const ushort* __restrict__ Vb,
    float* __restrict__ att, ushort* __restrict__ Ybf) {
  int b = blockIdx.x;
  int j0 = b * BS;
  int w = (BS < T_DIM - j0) ? BS : (T_DIM - j0);
  __shared__ float wl[BS][BS + 1];
  int tid = threadIdx.x;
  for (int idx = tid; idx < BS * (BS + 1); idx += 256) (&wl[0][0])[idx] = 0.0f;
  __syncthreads();
  for (int idx = tid; idx < w * w; idx += 256) {
    int rr = idx / w, c = idx - rr * w;
    int gi = j0 + rr;
    float val = __expf(eb[(size_t)gi * 64 + c] - mrow[gi]) / zrow[gi] + dep[j0 + c];
    wl[rr][c] = val;
    if (blockIdx.y == 0) att[(size_t)gi * T_DIM + j0 + c] = val;
  }
  __syncthreads();
  int c = blockIdx.y * 256 + tid;
  float acc[BS];
#pragma unroll
  for (int rr = 0; rr < BS; ++rr) acc[rr] = 0.f;
  for (int j = 0; j < w; ++j) {
    float v = bf2f(Vb[(size_t)(j0 + j) * D_DIM + c]);
#pragma unroll
    for (int rr = 0; rr < BS; ++rr) acc[rr] = fmaf(wl[rr][j], v, acc[rr]);
  }
#pragma unroll
  for (int rr = 0; rr < BS; ++rr)
    if (rr < w) Ybf[(size_t)(j0 + rr) * D_DIM + c] = f2bf(acc[rr]);
}

// ---------------------------------------------------------------------------
// Final projection: yout = Ybf @ Wob^T (1-term bf16) + ent/dep epilogue.
// A-frags + B-stage prefetched, dbuf B, 1 barrier per step.
__global__ __launch_bounds__(256,4) void k_final(
    const ushort* __restrict__ Ybf, const ushort* __restrict__ Wob,
    const float* __restrict__ Wout, const float* __restrict__ ent,
    const float* __restrict__ dep, float* __restrict__ yout) {
  __shared__ ushort ldsB[8192];  // 2 x 4096
  const int tid = threadIdx.x;
  const int w = tid >> 6, lane = tid & 63;
  const int wr = w >> 1, wc = w & 1;
  const int g = lane >> 4, cl = lane & 15;
  const int i0 = blockIdx.y * 64, j0 = blockIdx.x * 64;
  f32x4 acc[2][2];
#pragma unroll
  for (int a = 0; a < 2; ++a)
#pragma unroll
    for (int b = 0; b < 2; ++b) acc[a][b] = (f32x4){0.f,0.f,0.f,0.f};
  const int ar0 = i0 + wr*32 + cl;

  const int r1 = tid >> 3, c1 = tid & 7;
  const int r2 = (tid + 256) >> 3, c2 = (tid + 256) & 7;
  const int lo1 = r1*64 + (c1 ^ (r1 & 7))*8;
  const int lo2 = r2*64 + (c2 ^ (r2 & 7))*8;
  const size_t gB1 = (size_t)(j0 + r1) * D_DIM + c1*8;
  const size_t gB2 = (size_t)(j0 + r2) * D_DIM + c2*8;

  short8 sB1 = *reinterpret_cast<const short8*>(Wob + gB1);
  short8 sB2 = *reinterpret_cast<const short8*>(Wob + gB2);
  short8 aY[2][2];
#pragma unroll
  for (int is = 0; is < 2; ++is)
#pragma unroll
    for (int h = 0; h < 2; ++h)
      aY[is][h] = *reinterpret_cast<const short8*>(Ybf + (size_t)(ar0 + is*16) * D_DIM + (h*4+g)*8);

  for (int ks = 0; ks < 16; ++ks) {
    const int bofs = (ks & 1) * 4096;
    *reinterpret_cast<short8*>(&ldsB[bofs + lo1]) = sB1;
    *reinterpret_cast<short8*>(&ldsB[bofs + lo2]) = sB2;
    __syncthreads();
    short8 aC[2][2];
#pragma unroll
    for (int is = 0; is < 2; ++is)
#pragma unroll
      for (int h = 0; h < 2; ++h) aC[is][h] = aY[is][h];
    if (ks < 15) {
      const int k0 = (ks + 1) * 64;
      sB1 = *reinterpret_cast<const short8*>(Wob + gB1 + k0);
      sB2 = *reinterpret_cast<const short8*>(Wob + gB2 + k0);
#pragma unroll
      for (int is = 0; is < 2; ++is)
#pragma unroll
        for (int h = 0; h < 2; ++h)
          aY[is][h] = *reinterpret_cast<const short8*>(Ybf + (size_t)(ar0 + is*16) * D_DIM + k0 + (h*4+g)*8);
    }
#pragma unroll
    for (int h = 0; h < 2; ++h)
#pragma unroll
      for (int js = 0; js < 2; ++js) {
        const int br = wc*32 + js*16 + cl;
        short8 bW = *reinterpret_cast<const short8*>(&ldsB[bofs + br*64 + ((h*4+g) ^ (br & 7))*8]);
#pragma unroll
        for (int is = 0; is < 2; ++is)
          acc[is][js] = MFMA(aC[is][h], bW, acc[is][js]);
      }
  }
  float w1[2], w2[2];
#pragma unroll
  for (int js = 0; js < 2; ++js) {
    int gj = j0 + wc*32 + js*16 + cl;
    w1[js] = Wout[(size_t)gj * 1026 + 1024];
    w2[js] = Wout[(size_t)gj * 1026 + 1025];
  }
#pragma unroll
  for (int is = 0; is < 2; ++is)
#pragma unroll
    for (int a = 0; a < 4; ++a) {
      int gi = i0 + wr*32 + is*16 + g*4 + a;
      float e = ent[gi], d = dep[gi];
#pragma unroll
      for (int js = 0; js < 2; ++js) {
        int gj = j0 + wc*32 + js*16 + cl;
        yout[(size_t)gi * D_DIM + gj] = acc[is][js][a] + e * w1[js] + d * w2[js];
      }
    }
}

// ---------------------------------------------------------------------------
extern "C" void kernel_launch(void* const* d_in, const int* in_sizes, int n_in,
                              void* d_out, int out_size, void* d_ws, size_t ws_size,
                              hipStream_t stream) {
  const float* x    = (const float*)d_in[0];
  const float* Wk   = (const float*)d_in[1];
  const float* Wq   = (const float*)d_in[2];
  const float* Wv   = (const float*)d_in[3];
  const float* Wout = (const float*)d_in[4];
  float* out = (float*)d_out;
  char* wsb  = (char*)d_ws;

  ushort* Uh   = (ushort*)(wsb + 0);            // 8 MB
  ushort* Vb   = (ushort*)(wsb + 8388608);      // 8 MB
  ushort* Ybf  = (ushort*)(wsb + 16777216);     // 8 MB
  ushort* Wob  = (ushort*)(wsb + 25165824);     // 2 MB
  ushort* Wqh  = (ushort*)(wsb + 27262976);     // 6 x 2 MB
  ushort* Wql  = Wqh + 1048576;
  ushort* Wkh  = Wql + 1048576;
  ushort* Wkl  = Wkh + 1048576;
  ushort* Wvh  = Wkl + 1048576;
  ushort* Wvl  = Wvh + 1048576;
  float*  eb   = (float*)(wsb + 39845888);      // 1 MB
  float*  db   = (float*)(wsb + 40894464);      // 1 MB
  float*  pm   = (float*)(wsb + 41943040);      // 1 MB each (64 partials)
  float*  pZ   = (float*)(wsb + 42991616);
  float*  pWe  = (float*)(wsb + 44040192);
  float*  pWd  = (float*)(wsb + 45088768);
  float*  mrow = (float*)(wsb + 46137344);
  float*  zrow = (float*)(wsb + 46153728);
  float*  ent  = (float*)(wsb + 46170112);
  float*  dep  = (float*)(wsb + 46186496);
  float*  Sb   = (float*)(wsb + 46202880);
  float*  Sg   = (float*)(wsb + 46485504);

  float* yout = out;                               // [4096][1024]
  float* att  = out + (size_t)T_DIM * D_DIM;       // [4096][4096]
  ushort* xhi = (ushort*)att;                      // scratch in att region
  ushort* xlo = xhi + 4194304;
  ushort* Qhi = xlo + 4194304;
  ushort* Qlo = Qhi + 4194304;
  ushort* Khi = Qlo + 4194304;
  ushort* Klo = Khi + 4194304;

  k_split<<<4096, 256, 0, stream>>>(x, xhi, xlo);
  k_split<<<1024, 256, 0, stream>>>(Wq, Wqh, Wql);
  k_split<<<1024, 256, 0, stream>>>(Wk, Wkh, Wkl);
  k_split<<<1024, 256, 0, stream>>>(Wv, Wvh, Wvl);
  k_rownorm<<<T_DIM, 256, 0, stream>>>(x, Uh);
  k_bsum<<<NBLK, 256, 0, stream>>>(Uh, Sb);
  k_gsum<<<4, 256, 0, stream>>>(Sb, Sg);

  k_qk<<<dim3(16, 32), 256, 0, stream>>>(xhi, xlo, Wqh, Wql, Wkh, Wkl, Qhi, Qlo, Khi, Klo);
  k_v<<<dim3(16, 64), 256, 0, stream>>>(xhi, Wvh, Vb);

  k_stream<<<1024, 256, 0, stream>>>(Qhi, Qlo, Khi, Klo, Uh, eb, db, pm, pZ, pWe, pWd);
  k_merge<<<T_DIM, 256, 0, stream>>>(pm, pZ, pWe, pWd, Uh, Sg, Sb, eb, db, dep, ent, mrow, zrow);
  k_entnorm<<<1, 256, 0, stream>>>(ent);

  hipMemsetAsync(att, 0, (size_t)T_DIM * T_DIM * sizeof(float), stream);
  k_repack<<<1024, 256, 0, stream>>>(Wout, Wob);
  k_atty<<<dim3(NBLK, 4), 256, 0, stream>>>(eb, mrow, zrow, dep, Vb, att, Ybf);
  k_final<<<dim3(16, 64), 256, 0, stream>>>(Ybf, Wob, Wout, ent, dep, yout);
}

// Round 8
// 402.031 us; speedup vs baseline: 5.1859x; 1.4502x over previous
//
#include <hip/hip_runtime.h>
#include <math.h>

#define T_DIM 4096
#define D_DIM 1024
#define BS 60
#define NBLK 69
#define NPART 32

typedef __attribute__((ext_vector_type(4))) float f32x4;
typedef __attribute__((ext_vector_type(8))) short short8;
#define MFMA(a,b,c) __builtin_amdgcn_mfma_f32_16x16x32_bf16((a),(b),(c),0,0,0)

static __device__ __forceinline__ ushort f2bf(float f) {
  unsigned x = __float_as_uint(f);
  unsigned r = x + 0x7fffu + ((x >> 16) & 1u);
  return (ushort)(r >> 16);
}
static __device__ __forceinline__ float bf2f(ushort u) {
  return __uint_as_float((unsigned)u << 16);
}

// ---------------------------------------------------------------------------
// x row: hi/lo split + L2-normalized bf16, one pass.
__global__ __launch_bounds__(256) void k_prep(const float* __restrict__ x,
    ushort* __restrict__ xhi, ushort* __restrict__ xlo, ushort* __restrict__ u) {
  int i = blockIdx.x, tid = threadIdx.x;
  size_t off = (size_t)i * D_DIM + tid * 4;
  float4 v = *reinterpret_cast<const float4*>(x + off);
  float ss = v.x*v.x + v.y*v.y + v.z*v.z + v.w*v.w;
#pragma unroll
  for (int m = 1; m < 64; m <<= 1) ss += __shfl_xor(ss, m);
  __shared__ float sb[4];
  if ((tid & 63) == 0) sb[tid >> 6] = ss;
  __syncthreads();
  float inv = 1.0f / fmaxf(sqrtf(sb[0] + sb[1] + sb[2] + sb[3]), 1e-12f);
  ushort4 h, l, un;
  h.x = f2bf(v.x); l.x = f2bf(v.x - bf2f(h.x)); un.x = f2bf(v.x*inv);
  h.y = f2bf(v.y); l.y = f2bf(v.y - bf2f(h.y)); un.y = f2bf(v.y*inv);
  h.z = f2bf(v.z); l.z = f2bf(v.z - bf2f(h.z)); un.z = f2bf(v.z*inv);
  h.w = f2bf(v.w); l.w = f2bf(v.w - bf2f(h.w)); un.w = f2bf(v.w*inv);
  *reinterpret_cast<ushort4*>(xhi + off) = h;
  *reinterpret_cast<ushort4*>(xlo + off) = l;
  *reinterpret_cast<ushort4*>(u + off) = un;
}

// W splits: y=0 Wq(hi+lo), y=1 Wk(hi+lo), y=2 Wv(hi only)
__global__ __launch_bounds__(256) void k_wsplit(
    const float* __restrict__ Wq, const float* __restrict__ Wk, const float* __restrict__ Wv,
    ushort* __restrict__ Wqh, ushort* __restrict__ Wql,
    ushort* __restrict__ Wkh, ushort* __restrict__ Wkl, ushort* __restrict__ Wvh) {
  int y = blockIdx.y;
  const float* A = (y == 0) ? Wq : (y == 1) ? Wk : Wv;
  ushort* hi = (y == 0) ? Wqh : (y == 1) ? Wkh : Wvh;
  ushort* lo = (y == 0) ? Wql : Wkl;
  size_t i = ((size_t)blockIdx.x * 256 + threadIdx.x) * 4;
  float4 v = *reinterpret_cast<const float4*>(A + i);
  ushort4 h;
  h.x = f2bf(v.x); h.y = f2bf(v.y); h.z = f2bf(v.z); h.w = f2bf(v.w);
  *reinterpret_cast<ushort4*>(hi + i) = h;
  if (y < 2) {
    ushort4 l;
    l.x = f2bf(v.x - bf2f(h.x)); l.y = f2bf(v.y - bf2f(h.y));
    l.z = f2bf(v.z - bf2f(h.z)); l.w = f2bf(v.w - bf2f(h.w));
    *reinterpret_cast<ushort4*>(lo + i) = l;
  }
}

__global__ __launch_bounds__(256) void k_bsum(const ushort* __restrict__ u, float* __restrict__ Sb) {
  int b = blockIdx.x, tid = threadIdx.x;
  int j0 = b * BS;
  int w = (BS < T_DIM - j0) ? BS : (T_DIM - j0);
  int c = tid * 4;
  float4 acc = {0,0,0,0};
  for (int j = 0; j < w; ++j) {
    ushort4 v = *reinterpret_cast<const ushort4*>(u + (size_t)(j0 + j) * D_DIM + c);
    acc.x += bf2f(v.x); acc.y += bf2f(v.y); acc.z += bf2f(v.z); acc.w += bf2f(v.w);
  }
  *reinterpret_cast<float4*>(Sb + (size_t)b * D_DIM + c) = acc;
}

__global__ __launch_bounds__(256) void k_gsum(const float* __restrict__ Sb, float* __restrict__ S) {
  int c = blockIdx.x * 256 + threadIdx.x;
  float s = 0.f;
  for (int b = 0; b < NBLK; ++b) s += Sb[(size_t)b * D_DIM + c];
  S[c] = s;
}

// ---------------------------------------------------------------------------
// Fused QKV GEMM: Q,K 3-term split; V 1-term.  Tile 128i x 64j, dbuf 1-barrier.
__global__ __launch_bounds__(256,2) void k_qkv(
    const ushort* __restrict__ xhi, const ushort* __restrict__ xlo,
    const ushort* __restrict__ Wqh, const ushort* __restrict__ Wql,
    const ushort* __restrict__ Wkh, const ushort* __restrict__ Wkl,
    const ushort* __restrict__ Wvh,
    ushort* __restrict__ Qhi, ushort* __restrict__ Qlo,
    ushort* __restrict__ Khi, ushort* __restrict__ Klo,
    ushort* __restrict__ Vb) {
  __shared__ __align__(16) ushort lds[36864]; // dbuf 18432: xh@0 xl@4096 | Wqh@8192 Wql@10240 Wkh@12288 Wkl@14336 Wvh@16384
  const int tid = threadIdx.x;
  const int w = tid >> 6, lane = tid & 63;
  const int wr = w >> 1, wc = w & 1;
  const int g = lane >> 4, cl = lane & 15;
  const int i0 = blockIdx.y * 128, j0 = blockIdx.x * 64;

  int adA[4], adB[2];
#pragma unroll
  for (int is = 0; is < 4; ++is) {
    int r = wr*64 + is*16 + cl;
    adA[is] = r*32 + (g ^ ((r >> 1) & 3))*8;
  }
#pragma unroll
  for (int js = 0; js < 2; ++js) {
    int r = wc*32 + js*16 + cl;
    adB[js] = r*32 + (g ^ ((r >> 1) & 3))*8;
  }
  const int ra1 = tid >> 2, ra2 = 64 + (tid >> 2), rbr = tid >> 2;
  const int sa = tid & 3;
  const int wA1 = ra1*32 + (sa ^ ((ra1 >> 1) & 3))*8;
  const int wA2 = ra2*32 + (sa ^ ((ra2 >> 1) & 3))*8;
  const int wB  = rbr*32 + (sa ^ ((rbr >> 1) & 3))*8;
  const size_t gA1 = (size_t)(i0 + ra1) * D_DIM + sa*8;
  const size_t gA2 = (size_t)(i0 + ra2) * D_DIM + sa*8;
  const size_t gB  = (size_t)(j0 + rbr) * D_DIM + sa*8;

  f32x4 accQ[4][2], accK[4][2], accV[4][2];
#pragma unroll
  for (int is = 0; is < 4; ++is)
#pragma unroll
    for (int js = 0; js < 2; ++js) {
      accQ[is][js] = (f32x4){0.f,0.f,0.f,0.f};
      accK[is][js] = (f32x4){0.f,0.f,0.f,0.f};
      accV[is][js] = (f32x4){0.f,0.f,0.f,0.f};
    }

  short8 sXh1 = *reinterpret_cast<const short8*>(xhi + gA1);
  short8 sXh2 = *reinterpret_cast<const short8*>(xhi + gA2);
  short8 sXl1 = *reinterpret_cast<const short8*>(xlo + gA1);
  short8 sXl2 = *reinterpret_cast<const short8*>(xlo + gA2);
  short8 sQh  = *reinterpret_cast<const short8*>(Wqh + gB);
  short8 sQl  = *reinterpret_cast<const short8*>(Wql + gB);
  short8 sKh  = *reinterpret_cast<const short8*>(Wkh + gB);
  short8 sKl  = *reinterpret_cast<const short8*>(Wkl + gB);
  short8 sVh  = *reinterpret_cast<const short8*>(Wvh + gB);

  for (int ks = 0; ks < 32; ++ks) {
    const int bofs = (ks & 1) * 18432;
    *reinterpret_cast<short8*>(&lds[bofs + wA1])          = sXh1;
    *reinterpret_cast<short8*>(&lds[bofs + wA2])          = sXh2;
    *reinterpret_cast<short8*>(&lds[bofs + 4096 + wA1])   = sXl1;
    *reinterpret_cast<short8*>(&lds[bofs + 4096 + wA2])   = sXl2;
    *reinterpret_cast<short8*>(&lds[bofs + 8192 + wB])    = sQh;
    *reinterpret_cast<short8*>(&lds[bofs + 10240 + wB])   = sQl;
    *reinterpret_cast<short8*>(&lds[bofs + 12288 + wB])   = sKh;
    *reinterpret_cast<short8*>(&lds[bofs + 14336 + wB])   = sKl;
    *reinterpret_cast<short8*>(&lds[bofs + 16384 + wB])   = sVh;
    __syncthreads();
    short8 aH[4], aL[4], bQh[2], bQl[2], bKh[2], bKl[2], bVh[2];
#pragma unroll
    for (int is = 0; is < 4; ++is) {
      aH[is] = *reinterpret_cast<const short8*>(&lds[bofs + adA[is]]);
      aL[is] = *reinterpret_cast<const short8*>(&lds[bofs + 4096 + adA[is]]);
    }
#pragma unroll
    for (int js = 0; js < 2; ++js) {
      bQh[js] = *reinterpret_cast<const short8*>(&lds[bofs + 8192  + adB[js]]);
      bQl[js] = *reinterpret_cast<const short8*>(&lds[bofs + 10240 + adB[js]]);
      bKh[js] = *reinterpret_cast<const short8*>(&lds[bofs + 12288 + adB[js]]);
      bKl[js] = *reinterpret_cast<const short8*>(&lds[bofs + 14336 + adB[js]]);
      bVh[js] = *reinterpret_cast<const short8*>(&lds[bofs + 16384 + adB[js]]);
    }
    if (ks < 31) {
      const int k0 = (ks + 1) * 32;
      sXh1 = *reinterpret_cast<const short8*>(xhi + gA1 + k0);
      sXh2 = *reinterpret_cast<const short8*>(xhi + gA2 + k0);
      sXl1 = *reinterpret_cast<const short8*>(xlo + gA1 + k0);
      sXl2 = *reinterpret_cast<const short8*>(xlo + gA2 + k0);
      sQh  = *reinterpret_cast<const short8*>(Wqh + gB + k0);
      sQl  = *reinterpret_cast<const short8*>(Wql + gB + k0);
      sKh  = *reinterpret_cast<const short8*>(Wkh + gB + k0);
      sKl  = *reinterpret_cast<const short8*>(Wkl + gB + k0);
      sVh  = *reinterpret_cast<const short8*>(Wvh + gB + k0);
    }
#pragma unroll
    for (int js = 0; js < 2; ++js)
#pragma unroll
      for (int is = 0; is < 4; ++is) {
        accQ[is][js] = MFMA(aH[is], bQh[js], accQ[is][js]);
        accQ[is][js] = MFMA(aL[is], bQh[js], accQ[is][js]);
        accQ[is][js] = MFMA(aH[is], bQl[js], accQ[is][js]);
        accK[is][js] = MFMA(aH[is], bKh[js], accK[is][js]);
        accK[is][js] = MFMA(aL[is], bKh[js], accK[is][js]);
        accK[is][js] = MFMA(aH[is], bKl[js], accK[is][js]);
        accV[is][js] = MFMA(aH[is], bVh[js], accV[is][js]);
      }
  }
#pragma unroll
  for (int is = 0; is < 4; ++is)
#pragma unroll
    for (int js = 0; js < 2; ++js)
#pragma unroll
      for (int a = 0; a < 4; ++a) {
        int gi = i0 + wr*64 + is*16 + g*4 + a;
        int gj = j0 + wc*32 + js*16 + cl;
        size_t o = (size_t)gi*D_DIM + gj;
        float vq = accQ[is][js][a];
        ushort hq = f2bf(vq);
        Qhi[o] = hq; Qlo[o] = f2bf(vq - bf2f(hq));
        float vk = accK[is][js][a];
        ushort hk = f2bf(vk);
        Khi[o] = hk; Klo[o] = f2bf(vk - bf2f(hk));
        Vb[o] = f2bf(accV[is][js][a]);
      }
}

// ---------------------------------------------------------------------------
// E = Q@K^T (3-term) -> fp32 in att region + per-chunk row-max partials.
// Tile 128x128, wave 64x64, dbuf 1-barrier, reg-staged.
__global__ __launch_bounds__(256,2) void k_E(
    const ushort* __restrict__ Qhi, const ushort* __restrict__ Qlo,
    const ushort* __restrict__ Khi, const ushort* __restrict__ Klo,
    float* __restrict__ E, float* __restrict__ pm) {
  __shared__ __align__(16) ushort lds[32768]; // dbuf 16384: Qhi@0 Qlo@4096 Khi@8192 Klo@12288 (each 128x32)
  __shared__ float stat_s[2][2][64];
  const int tid = threadIdx.x;
  const int bid = blockIdx.x;
  const int wg = (bid & 7) * 128 + (bid >> 3);   // XCD-bijective (1024 % 8 == 0)
  const int it = wg >> 5, chunk = wg & 31;
  const int i0 = it * 128, jb = chunk * 128;
  const int w = tid >> 6, lane = tid & 63;
  const int wr = w >> 1, wc = w & 1;
  const int g = lane >> 4, cl = lane & 15;

  int adA[4], adB[4];
#pragma unroll
  for (int is = 0; is < 4; ++is) {
    int r = wr*64 + is*16 + cl;
    adA[is] = r*32 + (g ^ ((r >> 1) & 3))*8;
  }
#pragma unroll
  for (int js = 0; js < 4; ++js) {
    int r = wc*64 + js*16 + cl;
    adB[js] = r*32 + (g ^ ((r >> 1) & 3))*8;
  }
  const int ra1 = tid >> 2, ra2 = 64 + (tid >> 2);
  const int sa = tid & 3;
  const int wA1 = ra1*32 + (sa ^ ((ra1 >> 1) & 3))*8;
  const int wA2 = ra2*32 + (sa ^ ((ra2 >> 1) & 3))*8;
  const size_t gA1 = (size_t)(i0 + ra1) * D_DIM + sa*8;
  const size_t gA2 = (size_t)(i0 + ra2) * D_DIM + sa*8;
  const size_t gB1 = (size_t)(jb + ra1) * D_DIM + sa*8;
  const size_t gB2 = (size_t)(jb + ra2) * D_DIM + sa*8;

  f32x4 acc[4][4];
#pragma unroll
  for (int is = 0; is < 4; ++is)
#pragma unroll
    for (int js = 0; js < 4; ++js) acc[is][js] = (f32x4){0.f,0.f,0.f,0.f};

  short8 sQ1 = *reinterpret_cast<const short8*>(Qhi + gA1);
  short8 sQ2 = *reinterpret_cast<const short8*>(Qhi + gA2);
  short8 sq1 = *reinterpret_cast<const short8*>(Qlo + gA1);
  short8 sq2 = *reinterpret_cast<const short8*>(Qlo + gA2);
  short8 sK1 = *reinterpret_cast<const short8*>(Khi + gB1);
  short8 sK2 = *reinterpret_cast<const short8*>(Khi + gB2);
  short8 sk1 = *reinterpret_cast<const short8*>(Klo + gB1);
  short8 sk2 = *reinterpret_cast<const short8*>(Klo + gB2);

  for (int ks = 0; ks < 32; ++ks) {
    const int bofs = (ks & 1) * 16384;
    *reinterpret_cast<short8*>(&lds[bofs + wA1])          = sQ1;
    *reinterpret_cast<short8*>(&lds[bofs + wA2])          = sQ2;
    *reinterpret_cast<short8*>(&lds[bofs + 4096 + wA1])   = sq1;
    *reinterpret_cast<short8*>(&lds[bofs + 4096 + wA2])   = sq2;
    *reinterpret_cast<short8*>(&lds[bofs + 8192 + wA1])   = sK1;
    *reinterpret_cast<short8*>(&lds[bofs + 8192 + wA2])   = sK2;
    *reinterpret_cast<short8*>(&lds[bofs + 12288 + wA1])  = sk1;
    *reinterpret_cast<short8*>(&lds[bofs + 12288 + wA2])  = sk2;
    __syncthreads();
    short8 aQh[4], aQl[4], bKh[4], bKl[4];
#pragma unroll
    for (int is = 0; is < 4; ++is) {
      aQh[is] = *reinterpret_cast<const short8*>(&lds[bofs + adA[is]]);
      aQl[is] = *reinterpret_cast<const short8*>(&lds[bofs + 4096 + adA[is]]);
    }
#pragma unroll
    for (int js = 0; js < 4; ++js) {
      bKh[js] = *reinterpret_cast<const short8*>(&lds[bofs + 8192 + adB[js]]);
      bKl[js] = *reinterpret_cast<const short8*>(&lds[bofs + 12288 + adB[js]]);
    }
    if (ks < 31) {
      const int k0 = (ks + 1) * 32;
      sQ1 = *reinterpret_cast<const short8*>(Qhi + gA1 + k0);
      sQ2 = *reinterpret_cast<const short8*>(Qhi + gA2 + k0);
      sq1 = *reinterpret_cast<const short8*>(Qlo + gA1 + k0);
      sq2 = *reinterpret_cast<const short8*>(Qlo + gA2 + k0);
      sK1 = *reinterpret_cast<const short8*>(Khi + gB1 + k0);
      sK2 = *reinterpret_cast<const short8*>(Khi + gB2 + k0);
      sk1 = *reinterpret_cast<const short8*>(Klo + gB1 + k0);
      sk2 = *reinterpret_cast<const short8*>(Klo + gB2 + k0);
    }
#pragma unroll
    for (int js = 0; js < 4; ++js)
#pragma unroll
      for (int is = 0; is < 4; ++is) {
        acc[is][js] = MFMA(aQh[is], bKh[js], acc[is][js]);
        acc[is][js] = MFMA(aQl[is], bKh[js], acc[is][js]);
        acc[is][js] = MFMA(aQh[is], bKl[js], acc[is][js]);
      }
  }
  // store E + row-max partials
#pragma unroll
  for (int is = 0; is < 4; ++is)
#pragma unroll
    for (int a = 0; a < 4; ++a) {
      int gi = i0 + wr*64 + is*16 + g*4 + a;
      float mx = -3.0e38f;
#pragma unroll
      for (int js = 0; js < 4; ++js) {
        float e = acc[is][js][a];
        E[(size_t)gi*T_DIM + jb + wc*64 + js*16 + cl] = e;
        mx = fmaxf(mx, e);
      }
#pragma unroll
      for (int mk = 1; mk < 16; mk <<= 1) mx = fmaxf(mx, __shfl_xor(mx, mk));
      if (cl == 0) stat_s[wr][wc][is*16 + g*4 + a] = mx;
    }
  __syncthreads();
  if (tid < 128) {
    int rl = tid & 63, wr2 = tid >> 6;
    pm[(size_t)chunk*T_DIM + i0 + wr2*64 + rl] =
        fmaxf(stat_s[wr2][0][rl], stat_s[wr2][1][rl]);
  }
}

// row max over 32 partials
__global__ __launch_bounds__(256) void k_rowmax(const float* __restrict__ pm, float* __restrict__ mrow) {
  int i = blockIdx.x * 256 + threadIdx.x;
  float m = -3.0e38f;
  for (int c = 0; c < NPART; ++c) m = fmaxf(m, pm[(size_t)c*T_DIM + i]);
  mrow[i] = m;
}

// ---------------------------------------------------------------------------
// D = U@U^T (1-term) + p=exp(e-m_final) stats (plain-sum partials) + diag stash.
__global__ __launch_bounds__(256,2) void k_D(
    const ushort* __restrict__ Uh, const float* __restrict__ E,
    const float* __restrict__ mrow,
    float* __restrict__ eb, float* __restrict__ db,
    float* __restrict__ pZ, float* __restrict__ pWe, float* __restrict__ pWd) {
  __shared__ __align__(16) ushort lds[16384]; // dbuf 8192: Ui@0 Uj@4096 (each 128x32)
  __shared__ float stat_s[2][2][64][3];
  const int tid = threadIdx.x;
  const int bid = blockIdx.x;
  const int wg = (bid & 7) * 128 + (bid >> 3);
  const int it = wg >> 5, chunk = wg & 31;
  const int i0 = it * 128, jb = chunk * 128;
  const int w = tid >> 6, lane = tid & 63;
  const int wr = w >> 1, wc = w & 1;
  const int g = lane >> 4, cl = lane & 15;

  int adA[4], adB[4];
#pragma unroll
  for (int is = 0; is < 4; ++is) {
    int r = wr*64 + is*16 + cl;
    adA[is] = r*32 + (g ^ ((r >> 1) & 3))*8;
  }
#pragma unroll
  for (int js = 0; js < 4; ++js) {
    int r = wc*64 + js*16 + cl;
    adB[js] = r*32 + (g ^ ((r >> 1) & 3))*8;
  }
  const int ra1 = tid >> 2, ra2 = 64 + (tid >> 2);
  const int sa = tid & 3;
  const int wA1 = ra1*32 + (sa ^ ((ra1 >> 1) & 3))*8;
  const int wA2 = ra2*32 + (sa ^ ((ra2 >> 1) & 3))*8;
  const size_t gA1 = (size_t)(i0 + ra1) * D_DIM + sa*8;
  const size_t gA2 = (size_t)(i0 + ra2) * D_DIM + sa*8;
  const size_t gB1 = (size_t)(jb + ra1) * D_DIM + sa*8;
  const size_t gB2 = (size_t)(jb + ra2) * D_DIM + sa*8;

  f32x4 acc[4][4];
#pragma unroll
  for (int is = 0; is < 4; ++is)
#pragma unroll
    for (int js = 0; js < 4; ++js) acc[is][js] = (f32x4){0.f,0.f,0.f,0.f};

  short8 sU1 = *reinterpret_cast<const short8*>(Uh + gA1);
  short8 sU2 = *reinterpret_cast<const short8*>(Uh + gA2);
  short8 sV1 = *reinterpret_cast<const short8*>(Uh + gB1);
  short8 sV2 = *reinterpret_cast<const short8*>(Uh + gB2);

  for (int ks = 0; ks < 32; ++ks) {
    const int bofs = (ks & 1) * 8192;
    *reinterpret_cast<short8*>(&lds[bofs + wA1])        = sU1;
    *reinterpret_cast<short8*>(&lds[bofs + wA2])        = sU2;
    *reinterpret_cast<short8*>(&lds[bofs + 4096 + wA1]) = sV1;
    *reinterpret_cast<short8*>(&lds[bofs + 4096 + wA2]) = sV2;
    __syncthreads();
    short8 aU[4], bU[4];
#pragma unroll
    for (int is = 0; is < 4; ++is)
      aU[is] = *reinterpret_cast<const short8*>(&lds[bofs + adA[is]]);
#pragma unroll
    for (int js = 0; js < 4; ++js)
      bU[js] = *reinterpret_cast<const short8*>(&lds[bofs + 4096 + adB[js]]);
    if (ks < 31) {
      const int k0 = (ks + 1) * 32;
      sU1 = *reinterpret_cast<const short8*>(Uh + gA1 + k0);
      sU2 = *reinterpret_cast<const short8*>(Uh + gA2 + k0);
      sV1 = *reinterpret_cast<const short8*>(Uh + gB1 + k0);
      sV2 = *reinterpret_cast<const short8*>(Uh + gB2 + k0);
    }
#pragma unroll
    for (int js = 0; js < 4; ++js)
#pragma unroll
      for (int is = 0; is < 4; ++is)
        acc[is][js] = MFMA(aU[is], bU[js], acc[is][js]);
  }

  // epilogue: p = exp(e - m), plain-sum partials + diag stash
  const int iw0 = i0 + wr*64;
  const int blkLo = iw0 / BS, blkHi = (iw0 + 63) / BS;
  const int jw0 = jb + wc*64;
  const bool doDiag = (jw0 < (blkHi+1)*BS) && (jw0 + 64 > blkLo*BS);

#pragma unroll
  for (int is = 0; is < 4; ++is)
#pragma unroll
    for (int a = 0; a < 4; ++a) {
      int gi = i0 + wr*64 + is*16 + g*4 + a;
      int bi = gi / BS;
      float m = mrow[gi];
      float z = 0.f, we = 0.f, wd = 0.f;
#pragma unroll
      for (int js = 0; js < 4; ++js) {
        int gj = jb + wc*64 + js*16 + cl;
        float e = E[(size_t)gi*T_DIM + gj];
        float d = acc[is][js][a];
        float p = __expf(e - m);
        z += p; we += p*e; wd += p*d;
        if (doDiag && gj / BS == bi) {
          int c = gj - bi * BS;
          eb[(size_t)gi*64 + c] = e;
          db[(size_t)gi*64 + c] = d;
        }
      }
#pragma unroll
      for (int mk = 1; mk < 16; mk <<= 1) {
        z += __shfl_xor(z, mk); we += __shfl_xor(we, mk); wd += __shfl_xor(wd, mk);
      }
      if (cl == 0) {
        int rl = is*16 + g*4 + a;
        stat_s[wr][wc][rl][0] = z;
        stat_s[wr][wc][rl][1] = we;
        stat_s[wr][wc][rl][2] = wd;
      }
    }
  __syncthreads();
  if (tid < 128) {
    int rl = tid & 63, wr2 = tid >> 6;
    size_t idx = (size_t)chunk*T_DIM + i0 + wr2*64 + rl;
    pZ[idx]  = stat_s[wr2][0][rl][0] + stat_s[wr2][1][rl][0];
    pWe[idx] = stat_s[wr2][0][rl][1] + stat_s[wr2][1][rl][1];
    pWd[idx] = stat_s[wr2][0][rl][2] + stat_s[wr2][1][rl][2];
  }
}

// ---------------------------------------------------------------------------
__global__ __launch_bounds__(256) void k_merge(const float* __restrict__ pZ,
    const float* __restrict__ pWe, const float* __restrict__ pWd,
    const float* __restrict__ mrow,
    const ushort* __restrict__ Uh, const float* __restrict__ Sg, const float* __restrict__ Sb,
    const float* __restrict__ eb, const float* __restrict__ db,
    float* __restrict__ dep, float* __restrict__ ent, float* __restrict__ zrow) {
  int i = blockIdx.x, tid = threadIdx.x;
  float m = mrow[i];
  float Z = 0.f, We = 0.f, Wd = 0.f;
  for (int c = 0; c < NPART; ++c) {
    Z  += pZ [(size_t)c*T_DIM + i];
    We += pWe[(size_t)c*T_DIM + i];
    Wd += pWd[(size_t)c*T_DIM + i];
  }
  int b = i / BS, j0 = b * BS;
  int w = (BS < T_DIM - j0) ? BS : (T_DIM - j0);
  ushort4 uv = *reinterpret_cast<const ushort4*>(Uh + (size_t)i*D_DIM + tid*4);
  float4 Sv  = *reinterpret_cast<const float4*>(Sg + tid*4);
  float4 Sbv = *reinterpret_cast<const float4*>(Sb + (size_t)b*D_DIM + tid*4);
  float ux = bf2f(uv.x), uy = bf2f(uv.y), uz = bf2f(uv.z), uw = bf2f(uv.w);
  float dS  = ux*Sv.x  + uy*Sv.y  + uz*Sv.z  + uw*Sv.w;
  float dSb = ux*Sbv.x + uy*Sbv.y + uz*Sbv.z + uw*Sbv.w;
  float pb = 0.f, pdb = 0.f;
  if (tid < w) {
    float e = eb[(size_t)i*64 + tid], d = db[(size_t)i*64 + tid];
    float p = __expf(e - m);
    pb = p; pdb = p * d;
  }
  float v0 = dS, v1 = dSb, v2 = pb, v3 = pdb;
#pragma unroll
  for (int mk = 1; mk < 64; mk <<= 1) {
    v0 += __shfl_xor(v0, mk); v1 += __shfl_xor(v1, mk);
    v2 += __shfl_xor(v2, mk); v3 += __shfl_xor(v3, mk);
  }
  __shared__ float red[4][4];
  if ((tid & 63) == 0) { int wv = tid >> 6; red[0][wv]=v0; red[1][wv]=v1; red[2][wv]=v2; red[3][wv]=v3; }
  __syncthreads();
  if (tid == 0) {
    float tdS  = red[0][0]+red[0][1]+red[0][2]+red[0][3];
    float tdSb = red[1][0]+red[1][1]+red[1][2]+red[1][3];
    float s1   = red[2][0]+red[2][1]+red[2][2]+red[2][3];
    float s2   = red[3][0]+red[3][1]+red[3][2]+red[3][3];
    float invZ = 1.0f / Z;
    float num = (1.0f - s1*invZ) - (Wd - s2)*invZ;
    float den = (float)(T_DIM - w) - (tdS - tdSb);
    dep[i] = num / den;
    ent[i] = -(We*invZ - m - logf(Z)) / logf((float)T_DIM);
    zrow[i] = Z;
  }
}

__global__ __launch_bounds__(256) void k_entnorm(float* __restrict__ ent) {
  int tid = threadIdx.x;
  float s = 0.f;
  for (int i = tid; i < T_DIM; i += 256) s += fabsf(ent[i]);
#pragma unroll
  for (int mk = 1; mk < 64; mk <<= 1) s += __shfl_xor(s, mk);
  __shared__ float sb[4];
  if ((tid & 63) == 0) sb[tid >> 6] = s;
  __syncthreads();
  float inv = 1.0f / fmaxf(sb[0] + sb[1] + sb[2] + sb[3], 1e-12f);
  for (int i = tid; i < T_DIM; i += 256) ent[i] *= inv;
}

__global__ __launch_bounds__(256) void k_repack(const float* __restrict__ Wout, ushort* __restrict__ Wob) {
  int o = blockIdx.x;
  for (int k = threadIdx.x; k < 1024; k += 256)
    Wob[(size_t)o * 1024 + k] = f2bf(Wout[(size_t)o * 1026 + k]);
}

// full att strip write (zeros + diag block) + y = att_win @ V (bf16 out)
__global__ __launch_bounds__(256) void k_atty(const float* __restrict__ eb, const float* __restrict__ mrow,
    const float* __restrict__ zrow, const float* __restrict__ dep, const ushort* __restrict__ Vb,
    float* __restrict__ att, ushort* __restrict__ Ybf) {
  int b = blockIdx.x;
  int j0 = b * BS;
  int w = (BS < T_DIM - j0) ? BS : (T_DIM - j0);
  __shared__ float wl[BS][BS + 1];
  int tid = threadIdx.x;
  for (int idx = tid; idx < BS * (BS + 1); idx += 256) (&wl[0][0])[idx] = 0.0f;
  __syncthreads();
  for (int idx = tid; idx < w * w; idx += 256) {
    int rr = idx / w, c = idx - rr * w;
    int gi = j0 + rr;
    wl[rr][c] = __expf(eb[(size_t)gi * 64 + c] - mrow[gi]) / zrow[gi] + dep[j0 + c];
  }
  __syncthreads();
  // att rows [j0, j0+w) x cols [cbase, cbase+1024): zeros except diag block
  const int cbase = blockIdx.y * 1024;
  const int c0 = cbase + tid * 4;
  for (int rr = 0; rr < w; ++rr) {
    float4 o = {0.f, 0.f, 0.f, 0.f};
    if (c0 + 3 >= j0 && c0 < j0 + w) {
#pragma unroll
      for (int e = 0; e < 4; ++e) {
        int c = c0 + e;
        if (c >= j0 && c < j0 + w) (&o.x)[e] = wl[rr][c - j0];
      }
    }
    *reinterpret_cast<float4*>(att + (size_t)(j0 + rr) * T_DIM + c0) = o;
  }
  // y product over this 256-col slice of V
  int c = blockIdx.y * 256 + tid;
  float acc[BS];
#pragma unroll
  for (int rr = 0; rr < BS; ++rr) acc[rr] = 0.f;
  for (int j = 0; j < w; ++j) {
    float v = bf2f(Vb[(size_t)(j0 + j) * D_DIM + c]);
#pragma unroll
    for (int rr = 0; rr < BS; ++rr) acc[rr] = fmaf(wl[rr][j], v, acc[rr]);
  }
#pragma unroll
  for (int rr = 0; rr < BS; ++rr)
    if (rr < w) Ybf[(size_t)(j0 + rr) * D_DIM + c] = f2bf(acc[rr]);
}

// ---------------------------------------------------------------------------
// Final projection: yout = Ybf @ Wob^T (1-term bf16) + ent/dep epilogue.
__global__ __launch_bounds__(256,4) void k_final(
    const ushort* __restrict__ Ybf, const ushort* __restrict__ Wob,
    const float* __restrict__ Wout, const float* __restrict__ ent,
    const float* __restrict__ dep, float* __restrict__ yout) {
  __shared__ ushort ldsB[8192];  // 2 x 4096
  const int tid = threadIdx.x;
  const int w = tid >> 6, lane = tid & 63;
  const int wr = w >> 1, wc = w & 1;
  const int g = lane >> 4, cl = lane & 15;
  const int i0 = blockIdx.y * 64, j0 = blockIdx.x * 64;
  f32x4 acc[2][2];
#pragma unroll
  for (int a = 0; a < 2; ++a)
#pragma unroll
    for (int b = 0; b < 2; ++b) acc[a][b] = (f32x4){0.f,0.f,0.f,0.f};
  const int ar0 = i0 + wr*32 + cl;

  const int r1 = tid >> 3, c1 = tid & 7;
  const int r2 = (tid + 256) >> 3, c2 = (tid + 256) & 7;
  const int lo1 = r1*64 + (c1 ^ (r1 & 7))*8;
  const int lo2 = r2*64 + (c2 ^ (r2 & 7))*8;
  const size_t gB1 = (size_t)(j0 + r1) * D_DIM + c1*8;
  const size_t gB2 = (size_t)(j0 + r2) * D_DIM + c2*8;

  short8 sB1 = *reinterpret_cast<const short8*>(Wob + gB1);
  short8 sB2 = *reinterpret_cast<const short8*>(Wob + gB2);
  short8 aY[2][2];
#pragma unroll
  for (int is = 0; is < 2; ++is)
#pragma unroll
    for (int h = 0; h < 2; ++h)
      aY[is][h] = *reinterpret_cast<const short8*>(Ybf + (size_t)(ar0 + is*16) * D_DIM + (h*4+g)*8);

  for (int ks = 0; ks < 16; ++ks) {
    const int bofs = (ks & 1) * 4096;
    *reinterpret_cast<short8*>(&ldsB[bofs + lo1]) = sB1;
    *reinterpret_cast<short8*>(&ldsB[bofs + lo2]) = sB2;
    __syncthreads();
    short8 aC[2][2];
#pragma unroll
    for (int is = 0; is < 2; ++is)
#pragma unroll
      for (int h = 0; h < 2; ++h) aC[is][h] = aY[is][h];
    if (ks < 15) {
      const int k0 = (ks + 1) * 64;
      sB1 = *reinterpret_cast<const short8*>(Wob + gB1 + k0);
      sB2 = *reinterpret_cast<const short8*>(Wob + gB2 + k0);
#pragma unroll
      for (int is = 0; is < 2; ++is)
#pragma unroll
        for (int h = 0; h < 2; ++h)
          aY[is][h] = *reinterpret_cast<const short8*>(Ybf + (size_t)(ar0 + is*16) * D_DIM + k0 + (h*4+g)*8);
    }
#pragma unroll
    for (int h = 0; h < 2; ++h)
#pragma unroll
      for (int js = 0; js < 2; ++js) {
        const int br = wc*32 + js*16 + cl;
        short8 bW = *reinterpret_cast<const short8*>(&ldsB[bofs + br*64 + ((h*4+g) ^ (br & 7))*8]);
#pragma unroll
        for (int is = 0; is < 2; ++is)
          acc[is][js] = MFMA(aC[is][h], bW, acc[is][js]);
      }
  }
  float w1[2], w2[2];
#pragma unroll
  for (int js = 0; js < 2; ++js) {
    int gj = j0 + wc*32 + js*16 + cl;
    w1[js] = Wout[(size_t)gj * 1026 + 1024];
    w2[js] = Wout[(size_t)gj * 1026 + 1025];
  }
#pragma unroll
  for (int is = 0; is < 2; ++is)
#pragma unroll
    for (int a = 0; a < 4; ++a) {
      int gi = i0 + wr*32 + is*16 + g*4 + a;
      float e = ent[gi], d = dep[gi];
#pragma unroll
      for (int js = 0; js < 2; ++js) {
        int gj = j0 + wc*32 + js*16 + cl;
        yout[(size_t)gi * D_DIM + gj] = acc[is][js][a] + e * w1[js] + d * w2[js];
      }
    }
}

// ---------------------------------------------------------------------------
extern "C" void kernel_launch(void* const* d_in, const int* in_sizes, int n_in,
                              void* d_out, int out_size, void* d_ws, size_t ws_size,
                              hipStream_t stream) {
  const float* x    = (const float*)d_in[0];
  const float* Wk   = (const float*)d_in[1];
  const float* Wq   = (const float*)d_in[2];
  const float* Wv   = (const float*)d_in[3];
  const float* Wout = (const float*)d_in[4];
  float* out = (float*)d_out;
  char* wsb  = (char*)d_ws;

  // ws layout (58.1 MB)
  ushort* Uh   = (ushort*)(wsb + 0);            // 8 MB
  ushort* Vb   = (ushort*)(wsb + 8388608);      // 8 MB
  ushort* Wqh  = (ushort*)(wsb + 16777216);     // 5 x 2 MB (splits)
  ushort* Wql  = (ushort*)(wsb + 18874368);
  ushort* Wkh  = (ushort*)(wsb + 20971520);
  ushort* Wkl  = (ushort*)(wsb + 23068672);
  ushort* Wvh  = (ushort*)(wsb + 25165824);
  ushort* Ybf  = (ushort*)(wsb + 16777216);     // alias Wqh..Wkl (dead after k_qkv)
  ushort* Wob  = (ushort*)(wsb + 25165824);     // alias Wvh (dead after k_qkv)
  ushort* Khi  = (ushort*)(wsb + 27262976);     // 8 MB
  ushort* Klo  = (ushort*)(wsb + 35651584);     // 8 MB
  ushort* xhi  = (ushort*)(wsb + 44040192);     // 8 MB
  ushort* xlo  = (ushort*)(wsb + 52428800);     // 8 MB
  // xzone aliases (valid after k_qkv)
  float*  eb   = (float*)(wsb + 44040192);      // 1 MB
  float*  db   = (float*)(wsb + 45088768);      // 1 MB
  float*  pZ   = (float*)(wsb + 46137344);      // 0.5 MB each
  float*  pWe  = (float*)(wsb + 46661632);
  float*  pWd  = (float*)(wsb + 47185920);
  float*  pm   = (float*)(wsb + 47710208);
  float*  Sb   = (float*)(wsb + 48234496);      // 283 KB
  float*  Sg   = (float*)(wsb + 48525312);      // 4 KB
  float*  mrow = (float*)(wsb + 60817408);      // 16 KB each
  float*  zrow = (float*)(wsb + 60833792);
  float*  ent  = (float*)(wsb + 60850176);
  float*  dep  = (float*)(wsb + 60866560);

  float* yout = out;                               // [4096][1024]
  float* att  = out + (size_t)T_DIM * D_DIM;       // [4096][4096] = E scratch then final att
  ushort* Qhi = (ushort*)yout;                     // Q splits live in yout until k_E done
  ushort* Qlo = Qhi + 4194304;
  float*  E   = att;

  k_prep<<<T_DIM, 256, 0, stream>>>(x, xhi, xlo, Uh);
  k_wsplit<<<dim3(1024, 3), 256, 0, stream>>>(Wq, Wk, Wv, Wqh, Wql, Wkh, Wkl, Wvh);
  k_qkv<<<dim3(16, 32), 256, 0, stream>>>(xhi, xlo, Wqh, Wql, Wkh, Wkl, Wvh,
                                          Qhi, Qlo, Khi, Klo, Vb);
  k_bsum<<<NBLK, 256, 0, stream>>>(Uh, Sb);     // after k_qkv: Sb lives in x-zone
  k_gsum<<<4, 256, 0, stream>>>(Sb, Sg);

  k_E<<<1024, 256, 0, stream>>>(Qhi, Qlo, Khi, Klo, E, pm);
  k_rowmax<<<16, 256, 0, stream>>>(pm, mrow);
  k_D<<<1024, 256, 0, stream>>>(Uh, E, mrow, eb, db, pZ, pWe, pWd);
  k_merge<<<T_DIM, 256, 0, stream>>>(pZ, pWe, pWd, mrow, Uh, Sg, Sb, eb, db, dep, ent, zrow);
  k_entnorm<<<1, 256, 0, stream>>>(ent);

  k_repack<<<1024, 256, 0, stream>>>(Wout, Wob);
  k_atty<<<dim3(NBLK, 4), 256, 0, stream>>>(eb, mrow, zrow, dep, Vb, att, Ybf);
  k_final<<<dim3(16, 64), 256, 0, stream>>>(Ybf, Wob, Wout, ent, dep, yout);
}